// Round 1
// baseline (1384.364 us; speedup 1.0000x reference)
//
#include <hip/hip_runtime.h>
#include <cstddef>

// Shapes (compile-time constants from the reference)
// B=16, M=128, L=512, HID=256, H=4, DH=64, LAYERS=2
#define Bsz 16
#define Msz 128
#define Lsz 512
#define HIDs 256
#define Hh 4
#define DHs 64

// ---------------------------------------------------------------------------
// Generic GEMM: Y[NR,OUT] = act(X[NR,K] @ W[OUT,K]^T + bias[OUT] + add[NR,OUT])
// act: 0=none, 1=ELU, 2=GELU(exact)
// 64x64 output tile per block, 256 threads, 4x4 micro-tile per thread, BK=16.
// Requires NR%64==0, OUT%64==0, K%16==0 (true for all call sites).
// ---------------------------------------------------------------------------
__global__ __launch_bounds__(256) void gemm_kernel(
    const float* __restrict__ X, const float* __restrict__ W,
    const float* __restrict__ bias, const float* __restrict__ add,
    float* __restrict__ Y, int NR, int K, int OUT, int act)
{
    __shared__ float Xs[16][68];   // [kk][row] pad->16B-aligned rows, 2-way max
    __shared__ float Ws[16][68];   // [kk][col]
    const int nbx = OUT >> 6;
    const int bx = blockIdx.x % nbx;
    const int by = blockIdx.x / nbx;
    const int r0 = by << 6, o0 = bx << 6;
    const int tid = threadIdx.x;
    const int tx = tid & 15, ty = tid >> 4;

    float acc[4][4] = {{0.f,0.f,0.f,0.f},{0.f,0.f,0.f,0.f},
                       {0.f,0.f,0.f,0.f},{0.f,0.f,0.f,0.f}};

    for (int k0 = 0; k0 < K; k0 += 16) {
        #pragma unroll
        for (int i = 0; i < 4; i++) {
            int idx = (i << 8) + tid;
            int kk = idx & 15, rr = idx >> 4;
            Xs[kk][rr] = X[(size_t)(r0 + rr) * K + (k0 + kk)];
            Ws[kk][rr] = W[(size_t)(o0 + rr) * K + (k0 + kk)];
        }
        __syncthreads();
        #pragma unroll
        for (int kk = 0; kk < 16; kk++) {
            float a[4], b[4];
            *(float4*)a = *(const float4*)&Xs[kk][ty << 2];
            *(float4*)b = *(const float4*)&Ws[kk][tx << 2];
            #pragma unroll
            for (int i = 0; i < 4; i++)
                #pragma unroll
                for (int j = 0; j < 4; j++)
                    acc[i][j] = fmaf(a[i], b[j], acc[i][j]);
        }
        __syncthreads();
    }

    #pragma unroll
    for (int i = 0; i < 4; i++) {
        int r = r0 + (ty << 2) + i;
        #pragma unroll
        for (int j = 0; j < 4; j++) {
            int o = o0 + (tx << 2) + j;
            float v = acc[i][j] + bias[o];
            if (add) v += add[(size_t)r * OUT + o];
            if (act == 1)      v = (v > 0.f) ? v : (__expf(v) - 1.f);
            else if (act == 2) v = 0.5f * v * (1.f + erff(v * 0.70710678118654752f));
            Y[(size_t)r * OUT + o] = v;
        }
    }
}

// ---------------------------------------------------------------------------
// TN tokenizer: temp[b,n,s*DH+d] = sum_m (e^s / sum_d e^s) * ct_e[b,m,s*DH+d]
// where e = exp(-alpha[d] * (ct_t[b,m]-ts_t[b,n])^2), alpha = softplus(kp).
// One block per (b,n); wave w handles scale s=w; lane d within wave.
// ---------------------------------------------------------------------------
__global__ __launch_bounds__(256) void tokenizer_kernel(
    const float* __restrict__ ct_t, const float* __restrict__ ts_t,
    const float* __restrict__ ct_e, const float* __restrict__ kp,
    float* __restrict__ temp)
{
    const int bid = blockIdx.x;
    const int n = bid & (Lsz - 1);
    const int b = bid >> 9;           // / 512
    const int t = threadIdx.x;
    const int s = t >> 6;             // scale = wave id
    const int d = t & 63;

    float p = kp[d];
    float alpha = fmaxf(p, 0.f) + log1pf(__expf(-fabsf(p)));  // stable softplus
    const float tsn = ts_t[b * Lsz + n];

    __shared__ float cts[Msz];
    if (t < Msz) cts[t] = ct_t[b * Msz + t];
    __syncthreads();

    float acc = 0.f;
    for (int m = 0; m < Msz; m++) {
        float diff = cts[m] - tsn;
        float nrm = diff * diff;
        float e = __expf(-alpha * nrm);
        float pw;
        if (s == 0) pw = 1.f;
        else if (s == 1) pw = e;
        else if (s == 2) pw = e * e;
        else pw = e * e * e;
        float ssum = pw;
        #pragma unroll
        for (int o = 32; o >= 1; o >>= 1) ssum += __shfl_xor(ssum, o, 64);
        acc += (pw / ssum) * ct_e[(size_t)(b * Msz + m) * HIDs + t];
    }
    temp[(size_t)(b * Lsz + n) * HIDs + t] = acc;
}

// ---------------------------------------------------------------------------
// Attention: per block = (b, h, 16-row q-tile). qkv row layout [768]:
// q at +0, k at +256, v at +512, head h occupies cols h*64..h*64+63.
// Scores/softmax in LDS; K/V streamed through LDS in 64-key chunks.
// ---------------------------------------------------------------------------
__global__ __launch_bounds__(256) void attn_kernel(
    const float* __restrict__ qkv, float* __restrict__ O)
{
    const int bid = blockIdx.x;            // 16*4*32 = 2048
    const int qt = bid & 31;
    const int h  = (bid >> 5) & 3;
    const int b  = bid >> 7;
    const int q0 = qt * 16;
    const int t  = threadIdx.x;

    __shared__ float Qs[16][65];
    __shared__ float S[16][513];
    __shared__ float KV[64][65];

    const float* base = qkv + (size_t)b * Lsz * 768;

    #pragma unroll
    for (int i = 0; i < 4; i++) {
        int idx = (i << 8) + t;
        int qi = idx >> 6, d = idx & 63;
        Qs[qi][d] = base[(size_t)(q0 + qi) * 768 + h * 64 + d];
    }
    __syncthreads();

    const int qi = t >> 4;
    const int kbase = (t & 15) << 2;

    // ---- scores ----
    for (int c = 0; c < 8; c++) {
        #pragma unroll
        for (int i = 0; i < 16; i++) {
            int idx = (i << 8) + t;
            int ki = idx >> 6, d = idx & 63;
            KV[ki][d] = base[(size_t)(c * 64 + ki) * 768 + 256 + h * 64 + d];
        }
        __syncthreads();
        float a0 = 0.f, a1 = 0.f, a2 = 0.f, a3 = 0.f;
        #pragma unroll
        for (int dd = 0; dd < 64; dd++) {
            float q = Qs[qi][dd];
            a0 = fmaf(q, KV[kbase + 0][dd], a0);
            a1 = fmaf(q, KV[kbase + 1][dd], a1);
            a2 = fmaf(q, KV[kbase + 2][dd], a2);
            a3 = fmaf(q, KV[kbase + 3][dd], a3);
        }
        S[qi][c * 64 + kbase + 0] = a0 * 0.125f;
        S[qi][c * 64 + kbase + 1] = a1 * 0.125f;
        S[qi][c * 64 + kbase + 2] = a2 * 0.125f;
        S[qi][c * 64 + kbase + 3] = a3 * 0.125f;
        __syncthreads();
    }

    // ---- softmax over 512 keys, one 16-lane group per row ----
    const int lane16 = t & 15;
    float mx = -1e30f;
    for (int k = lane16; k < Lsz; k += 16) mx = fmaxf(mx, S[qi][k]);
    #pragma unroll
    for (int o = 8; o >= 1; o >>= 1) mx = fmaxf(mx, __shfl_xor(mx, o, 16));
    float sum = 0.f;
    for (int k = lane16; k < Lsz; k += 16) {
        float e = __expf(S[qi][k] - mx);
        S[qi][k] = e;
        sum += e;
    }
    #pragma unroll
    for (int o = 8; o >= 1; o >>= 1) sum += __shfl_xor(sum, o, 16);
    const float inv = 1.f / sum;

    // ---- O = P @ V ----
    const int dbase = (t & 15) << 2;
    float o0 = 0.f, o1 = 0.f, o2 = 0.f, o3 = 0.f;
    for (int c = 0; c < 8; c++) {
        __syncthreads();
        #pragma unroll
        for (int i = 0; i < 16; i++) {
            int idx = (i << 8) + t;
            int li = idx >> 6, d = idx & 63;
            KV[li][d] = base[(size_t)(c * 64 + li) * 768 + 512 + h * 64 + d];
        }
        __syncthreads();
        #pragma unroll 8
        for (int l = 0; l < 64; l++) {
            float pv = S[qi][c * 64 + l];
            o0 = fmaf(pv, KV[l][dbase + 0], o0);
            o1 = fmaf(pv, KV[l][dbase + 1], o1);
            o2 = fmaf(pv, KV[l][dbase + 2], o2);
            o3 = fmaf(pv, KV[l][dbase + 3], o3);
        }
    }
    float* op = O + (size_t)(b * Lsz + q0 + qi) * HIDs + h * 64 + dbase;
    op[0] = o0 * inv; op[1] = o1 * inv; op[2] = o2 * inv; op[3] = o3 * inv;
}

// ---------------------------------------------------------------------------
// LayerNorm over last dim (256): X[row,:] = (Y-mu)/sqrt(var+eps)*g + b
// One block (256 threads) per row.
// ---------------------------------------------------------------------------
__global__ __launch_bounds__(256) void ln_kernel(
    const float* __restrict__ Y, const float* __restrict__ g,
    const float* __restrict__ b, float* __restrict__ X)
{
    const int row = blockIdx.x;
    const int t = threadIdx.x;
    float v = Y[(size_t)row * HIDs + t];

    __shared__ float red[8];
    float s = v;
    #pragma unroll
    for (int o = 32; o >= 1; o >>= 1) s += __shfl_xor(s, o, 64);
    const int w = t >> 6, lane = t & 63;
    if (lane == 0) red[w] = s;
    __syncthreads();
    float mu = (red[0] + red[1] + red[2] + red[3]) * (1.f / 256.f);
    float dl = v - mu;
    float q = dl * dl;
    #pragma unroll
    for (int o = 32; o >= 1; o >>= 1) q += __shfl_xor(q, o, 64);
    if (lane == 0) red[4 + w] = q;
    __syncthreads();
    float var = (red[4] + red[5] + red[6] + red[7]) * (1.f / 256.f);
    X[(size_t)row * HIDs + t] = dl * rsqrtf(var + 1e-5f) * g[t] + b[t];
}

// ---------------------------------------------------------------------------
// Prediction head: out[row] = dot(X[row,:], pW) + pb. Wave per row.
// ---------------------------------------------------------------------------
__global__ __launch_bounds__(256) void pred_kernel(
    const float* __restrict__ X, const float* __restrict__ pW,
    const float* __restrict__ pb, float* __restrict__ out)
{
    const int w = threadIdx.x >> 6, lane = threadIdx.x & 63;
    const int row = blockIdx.x * 4 + w;
    const float* xr = X + (size_t)row * HIDs;
    float s = 0.f;
    #pragma unroll
    for (int i = 0; i < 4; i++) s = fmaf(xr[lane + i * 64], pW[lane + i * 64], s);
    #pragma unroll
    for (int o = 32; o >= 1; o >>= 1) s += __shfl_xor(s, o, 64);
    if (lane == 0) out[row] = s + pb[0];
}

// ---------------------------------------------------------------------------
extern "C" void kernel_launch(void* const* d_in, const int* in_sizes, int n_in,
                              void* d_out, int out_size, void* d_ws, size_t ws_size,
                              hipStream_t stream)
{
    (void)in_sizes; (void)n_in; (void)out_size; (void)ws_size;

    const float* ct_t   = (const float*)d_in[0];
    const float* ts_t   = (const float*)d_in[1];
    const float* ct_emb = (const float*)d_in[2];
    const float* ts_emb = (const float*)d_in[3];
    const float* kp     = (const float*)d_in[4];
    const float* ct_W   = (const float*)d_in[5];
    const float* ct_b   = (const float*)d_in[6];
    const float* fW0    = (const float*)d_in[7];
    const float* fb0    = (const float*)d_in[8];
    const float* fW1    = (const float*)d_in[9];
    const float* fb1    = (const float*)d_in[10];
    const float* fW2    = (const float*)d_in[11];
    const float* fb2    = (const float*)d_in[12];
    const float* f_ln_g = (const float*)d_in[13];
    const float* f_ln_b = (const float*)d_in[14];
    const float* Wqkv   = (const float*)d_in[15];
    const float* bqkv   = (const float*)d_in[16];
    const float* Wo     = (const float*)d_in[17];
    const float* bo     = (const float*)d_in[18];
    const float* W1     = (const float*)d_in[19];
    const float* b1     = (const float*)d_in[20];
    const float* W2     = (const float*)d_in[21];
    const float* b2     = (const float*)d_in[22];
    const float* ln1_g  = (const float*)d_in[23];
    const float* ln1_b  = (const float*)d_in[24];
    const float* ln2_g  = (const float*)d_in[25];
    const float* ln2_b  = (const float*)d_in[26];
    const float* pred_W = (const float*)d_in[27];
    const float* pred_b = (const float*)d_in[28];

    float* ws = (float*)d_ws;
    // workspace layout (floats), with lifetime-based reuse (total 50 MB):
    float* ct_e  = ws;                 // 524288    [0, 0.5M)
    float* temp  = ws + 524288;        // 2097152   [0.5M, 2.5M)
    float* ybuf  = temp;               //   (temp dead after g1 gemm)
    float* g1    = ws + 2621440;       // 2097152   [2.5M, 4.5M)
    float* xbuf  = g1;                 //   (g1 dead after aux gemm)
    float* aux   = ws + 4718592;       // region [4.5M, 10.5M)
    float* qkv   = aux;                //   6291456 (aux dead when qkv written)
    float* ff1   = aux;                //   4194304 (qkv dead when ff1 written)
    float* obuf  = ws + 11010048;      // 2097152   [10.5M, 12.5M)

    const int NRts = Bsz * Lsz;  // 8192
    const int NRct = Bsz * Msz;  // 2048
    auto grid = [](int nr, int out) { return dim3((unsigned)((nr >> 6) * (out >> 6))); };

    // --- tokenizer ---
    gemm_kernel<<<grid(NRct, 256), 256, 0, stream>>>(ct_emb, ct_W, ct_b, nullptr,
                                                     ct_e, NRct, 256, 256, 0);
    tokenizer_kernel<<<dim3(Bsz * Lsz), 256, 0, stream>>>(ct_t, ts_t, ct_e, kp, temp);

    // --- fusion ---
    gemm_kernel<<<grid(NRts, 256), 256, 0, stream>>>(temp, fW0, fb0, nullptr,
                                                     g1, NRts, 256, 256, 0);
    gemm_kernel<<<grid(NRts, 256), 256, 0, stream>>>(ts_emb, fW1, fb1, g1,
                                                     aux, NRts, 256, 256, 1);
    gemm_kernel<<<grid(NRts, 256), 256, 0, stream>>>(aux, fW2, fb2, ts_emb,
                                                     ybuf, NRts, 256, 256, 0);
    ln_kernel<<<dim3(NRts), 256, 0, stream>>>(ybuf, f_ln_g, f_ln_b, xbuf);

    // --- transformer layers ---
    for (int l = 0; l < 2; l++) {
        gemm_kernel<<<grid(NRts, 768), 256, 0, stream>>>(
            xbuf, Wqkv + (size_t)l * 768 * 256, bqkv + l * 768, nullptr,
            qkv, NRts, 256, 768, 0);
        attn_kernel<<<dim3(2048), 256, 0, stream>>>(qkv, obuf);
        gemm_kernel<<<grid(NRts, 256), 256, 0, stream>>>(
            obuf, Wo + (size_t)l * 256 * 256, bo + l * 256, xbuf,
            ybuf, NRts, 256, 256, 0);
        ln_kernel<<<dim3(NRts), 256, 0, stream>>>(ybuf, ln1_g + l * 256, ln1_b + l * 256, xbuf);
        gemm_kernel<<<grid(NRts, 512), 256, 0, stream>>>(
            xbuf, W1 + (size_t)l * 512 * 256, b1 + l * 512, nullptr,
            ff1, NRts, 256, 512, 2);
        gemm_kernel<<<grid(NRts, 256), 256, 0, stream>>>(
            ff1, W2 + (size_t)l * 256 * 512, b2 + l * 256, xbuf,
            ybuf, NRts, 512, 256, 0);
        ln_kernel<<<dim3(NRts), 256, 0, stream>>>(ybuf, ln2_g + l * 256, ln2_b + l * 256, xbuf);
    }

    // --- prediction head ---
    pred_kernel<<<dim3(NRts / 4), 256, 0, stream>>>(xbuf, pred_W, pred_b, (float*)d_out);
}

// Round 2
// 873.667 us; speedup vs baseline: 1.5845x; 1.5845x over previous
//
#include <hip/hip_runtime.h>
#include <hip/hip_bf16.h>
#include <cstddef>

// Shapes (compile-time constants from the reference)
// B=16, M=128, L=512, HID=256, H=4, DH=64, LAYERS=2
#define Bsz 16
#define Msz 128
#define Lsz 512
#define HIDs 256
#define Hh 4
#define DHs 64

typedef __attribute__((ext_vector_type(4))) float f32x4;
typedef __attribute__((ext_vector_type(8))) __bf16 bf16x8;
typedef __attribute__((ext_vector_type(8))) unsigned short ushort8;

static __device__ inline unsigned short f2bf(float f) {
    __hip_bfloat16 h = __float2bfloat16(f);
    return *(unsigned short*)&h;
}

// ---------------------------------------------------------------------------
// Generic GEMM: Y[NR,OUT] = act(X[NR,K] @ W[OUT,K]^T + bias[OUT] + add[NR,OUT])
// act: 0=none, 1=ELU, 2=GELU(exact)
// ---------------------------------------------------------------------------
__global__ __launch_bounds__(256) void gemm_kernel(
    const float* __restrict__ X, const float* __restrict__ W,
    const float* __restrict__ bias, const float* __restrict__ add,
    float* __restrict__ Y, int NR, int K, int OUT, int act)
{
    __shared__ float Xs[16][68];
    __shared__ float Ws[16][68];
    const int nbx = OUT >> 6;
    const int bx = blockIdx.x % nbx;
    const int by = blockIdx.x / nbx;
    const int r0 = by << 6, o0 = bx << 6;
    const int tid = threadIdx.x;
    const int tx = tid & 15, ty = tid >> 4;

    float acc[4][4] = {{0.f,0.f,0.f,0.f},{0.f,0.f,0.f,0.f},
                       {0.f,0.f,0.f,0.f},{0.f,0.f,0.f,0.f}};

    for (int k0 = 0; k0 < K; k0 += 16) {
        #pragma unroll
        for (int i = 0; i < 4; i++) {
            int idx = (i << 8) + tid;
            int kk = idx & 15, rr = idx >> 4;
            Xs[kk][rr] = X[(size_t)(r0 + rr) * K + (k0 + kk)];
            Ws[kk][rr] = W[(size_t)(o0 + rr) * K + (k0 + kk)];
        }
        __syncthreads();
        #pragma unroll
        for (int kk = 0; kk < 16; kk++) {
            float a[4], b[4];
            *(float4*)a = *(const float4*)&Xs[kk][ty << 2];
            *(float4*)b = *(const float4*)&Ws[kk][tx << 2];
            #pragma unroll
            for (int i = 0; i < 4; i++)
                #pragma unroll
                for (int j = 0; j < 4; j++)
                    acc[i][j] = fmaf(a[i], b[j], acc[i][j]);
        }
        __syncthreads();
    }

    #pragma unroll
    for (int i = 0; i < 4; i++) {
        int r = r0 + (ty << 2) + i;
        #pragma unroll
        for (int j = 0; j < 4; j++) {
            int o = o0 + (tx << 2) + j;
            float v = acc[i][j] + bias[o];
            if (add) v += add[(size_t)r * OUT + o];
            if (act == 1)      v = (v > 0.f) ? v : (__expf(v) - 1.f);
            else if (act == 2) v = 0.5f * v * (1.f + erff(v * 0.70710678118654752f));
            Y[(size_t)r * OUT + o] = v;
        }
    }
}

// ---------------------------------------------------------------------------
// TN tokenizer
// ---------------------------------------------------------------------------
__global__ __launch_bounds__(256) void tokenizer_kernel(
    const float* __restrict__ ct_t, const float* __restrict__ ts_t,
    const float* __restrict__ ct_e, const float* __restrict__ kp,
    float* __restrict__ temp)
{
    const int bid = blockIdx.x;
    const int n = bid & (Lsz - 1);
    const int b = bid >> 9;
    const int t = threadIdx.x;
    const int s = t >> 6;
    const int d = t & 63;

    float p = kp[d];
    float alpha = fmaxf(p, 0.f) + log1pf(__expf(-fabsf(p)));
    const float tsn = ts_t[b * Lsz + n];

    __shared__ float cts[Msz];
    if (t < Msz) cts[t] = ct_t[b * Msz + t];
    __syncthreads();

    float acc = 0.f;
    for (int m = 0; m < Msz; m++) {
        float diff = cts[m] - tsn;
        float nrm = diff * diff;
        float e = __expf(-alpha * nrm);
        float pw;
        if (s == 0) pw = 1.f;
        else if (s == 1) pw = e;
        else if (s == 2) pw = e * e;
        else pw = e * e * e;
        float ssum = pw;
        #pragma unroll
        for (int o = 32; o >= 1; o >>= 1) ssum += __shfl_xor(ssum, o, 64);
        acc += (pw / ssum) * ct_e[(size_t)(b * Msz + m) * HIDs + t];
    }
    temp[(size_t)(b * Lsz + n) * HIDs + t] = acc;
}

// ---------------------------------------------------------------------------
// MFMA bf16 flash attention.
// Block = 256 threads = 4 waves; handles one (b,h) and 64 q-rows (16/wave).
// Grid = B*H*(L/64) = 512. qkv row layout [768]: q +0, k +256, v +512,
// head h at cols h*64..h*64+63.
// mfma_f32_16x16x32_bf16 layouts:
//   A: lane l holds A[l&15][8*(l>>4)+j], j=0..7
//   B: lane l holds B[8*(l>>4)+j][l&15]
//   C/D: lane l holds D[4*(l>>4)+p][l&15], p=0..3
// ---------------------------------------------------------------------------
__global__ __launch_bounds__(256) void attn_mfma_kernel(
    const float* __restrict__ qkv, float* __restrict__ O)
{
    const int bid = blockIdx.x;
    const int qt = bid & 7;
    const int h  = (bid >> 3) & 3;
    const int b  = bid >> 5;
    const int t  = threadIdx.x;
    const int w  = t >> 6;
    const int lane = t & 63;
    const int g = lane >> 4;      // 0..3
    const int r = lane & 15;      // 0..15

    __shared__ float Ks[64][65];
    __shared__ float Vs[64][65];
    __shared__ float Ps[4][16][65];

    const float* base = qkv + (size_t)b * Lsz * 768;
    const int q0 = qt * 64 + w * 16;

    // Q fragments (rows q0+r, d = 8g+j (+32 for frag 1)), fp32 -> bf16
    bf16x8 qf[2];
    {
        const float* qp = base + (size_t)(q0 + r) * 768 + h * 64 + 8 * g;
        #pragma unroll
        for (int f = 0; f < 2; f++) {
            ushort8 u;
            #pragma unroll
            for (int j = 0; j < 8; j++) u[j] = f2bf(qp[32 * f + j]);
            qf[f] = __builtin_bit_cast(bf16x8, u);
        }
    }

    f32x4 Ofr[4];
    #pragma unroll
    for (int dblk = 0; dblk < 4; dblk++) Ofr[dblk] = (f32x4){0.f, 0.f, 0.f, 0.f};
    float m_run[4] = {-1e30f, -1e30f, -1e30f, -1e30f};
    float l_run[4] = {0.f, 0.f, 0.f, 0.f};

    for (int c = 0; c < 8; c++) {
        __syncthreads();   // previous chunk fully consumed
        // ---- stage K and V chunk (fp32, coalesced float4) ----
        {
            const int rr = t >> 4;
            const int c4 = t & 15;
            #pragma unroll
            for (int i = 0; i < 4; i++) {
                int row = rr + 16 * i;
                const float* gp = base + (size_t)(c * 64 + row) * 768 + 256 + h * 64 + 4 * c4;
                *(float4*)&Ks[row][4 * c4] = *(const float4*)gp;
                *(float4*)&Vs[row][4 * c4] = *(const float4*)(gp + 256);
            }
        }
        __syncthreads();

        // ---- S = (Q K^T) * 0.125 for this chunk: 4 col-subtiles of 16 ----
        f32x4 sfr[4];
        #pragma unroll
        for (int s = 0; s < 4; s++) {
            f32x4 acc = (f32x4){0.f, 0.f, 0.f, 0.f};
            #pragma unroll
            for (int f = 0; f < 2; f++) {
                // B-frag of K^T == A-layout of K: row s*16+r, d = 8g+32f+j
                const float* kp = &Ks[s * 16 + r][8 * g + 32 * f];
                ushort8 u;
                #pragma unroll
                for (int j = 0; j < 8; j++) u[j] = f2bf(kp[j]);
                acc = __builtin_amdgcn_mfma_f32_16x16x32_bf16(
                    qf[f], __builtin_bit_cast(bf16x8, u), acc, 0, 0, 0);
            }
            #pragma unroll
            for (int p = 0; p < 4; p++) acc[p] *= 0.125f;
            sfr[s] = acc;
        }

        // ---- online softmax (rows = 4g+p, cols across s and 16-lane group) ----
        #pragma unroll
        for (int p = 0; p < 4; p++) {
            float rm = fmaxf(fmaxf(sfr[0][p], sfr[1][p]), fmaxf(sfr[2][p], sfr[3][p]));
            #pragma unroll
            for (int o = 1; o <= 8; o <<= 1) rm = fmaxf(rm, __shfl_xor(rm, o));
            float mnew = fmaxf(m_run[p], rm);
            float sc = __expf(m_run[p] - mnew);
            m_run[p] = mnew;
            float rs = 0.f;
            #pragma unroll
            for (int s = 0; s < 4; s++) {
                float pv = __expf(sfr[s][p] - mnew);
                Ps[w][4 * g + p][s * 16 + r] = pv;
                rs += pv;
            }
            #pragma unroll
            for (int o = 1; o <= 8; o <<= 1) rs += __shfl_xor(rs, o);
            l_run[p] = l_run[p] * sc + rs;
            #pragma unroll
            for (int dblk = 0; dblk < 4; dblk++) Ofr[dblk][p] *= sc;
        }

        // P writes are per-wave private LDS; drain before cross-lane reads
        __asm__ volatile("s_waitcnt lgkmcnt(0)" ::: "memory");

        // ---- O += P @ V ----
        #pragma unroll
        for (int f = 0; f < 2; f++) {
            // A-frag of P: row r, k = 8g+32f+j
            const float* pp = &Ps[w][r][8 * g + 32 * f];
            ushort8 ua;
            #pragma unroll
            for (int j = 0; j < 8; j++) ua[j] = f2bf(pp[j]);
            bf16x8 pa = __builtin_bit_cast(bf16x8, ua);
            #pragma unroll
            for (int dblk = 0; dblk < 4; dblk++) {
                // B-frag of V: k = 8g+32f+j, d = dblk*16+r
                ushort8 ub;
                #pragma unroll
                for (int j = 0; j < 8; j++)
                    ub[j] = f2bf(Vs[32 * f + 8 * g + j][dblk * 16 + r]);
                Ofr[dblk] = __builtin_amdgcn_mfma_f32_16x16x32_bf16(
                    pa, __builtin_bit_cast(bf16x8, ub), Ofr[dblk], 0, 0, 0);
            }
        }
    }

    // ---- epilogue: O /= l, store fp32 ----
    #pragma unroll
    for (int dblk = 0; dblk < 4; dblk++) {
        #pragma unroll
        for (int p = 0; p < 4; p++) {
            int row = q0 + 4 * g + p;
            O[(size_t)(b * Lsz + row) * HIDs + h * 64 + dblk * 16 + r] =
                Ofr[dblk][p] / l_run[p];
        }
    }
}

// ---------------------------------------------------------------------------
// LayerNorm over last dim (256)
// ---------------------------------------------------------------------------
__global__ __launch_bounds__(256) void ln_kernel(
    const float* __restrict__ Y, const float* __restrict__ g,
    const float* __restrict__ b, float* __restrict__ X)
{
    const int row = blockIdx.x;
    const int t = threadIdx.x;
    float v = Y[(size_t)row * HIDs + t];

    __shared__ float red[8];
    float s = v;
    #pragma unroll
    for (int o = 32; o >= 1; o >>= 1) s += __shfl_xor(s, o, 64);
    const int w = t >> 6, lane = t & 63;
    if (lane == 0) red[w] = s;
    __syncthreads();
    float mu = (red[0] + red[1] + red[2] + red[3]) * (1.f / 256.f);
    float dl = v - mu;
    float q = dl * dl;
    #pragma unroll
    for (int o = 32; o >= 1; o >>= 1) q += __shfl_xor(q, o, 64);
    if (lane == 0) red[4 + w] = q;
    __syncthreads();
    float var = (red[4] + red[5] + red[6] + red[7]) * (1.f / 256.f);
    X[(size_t)row * HIDs + t] = dl * rsqrtf(var + 1e-5f) * g[t] + b[t];
}

// ---------------------------------------------------------------------------
// Prediction head
// ---------------------------------------------------------------------------
__global__ __launch_bounds__(256) void pred_kernel(
    const float* __restrict__ X, const float* __restrict__ pW,
    const float* __restrict__ pb, float* __restrict__ out)
{
    const int w = threadIdx.x >> 6, lane = threadIdx.x & 63;
    const int row = blockIdx.x * 4 + w;
    const float* xr = X + (size_t)row * HIDs;
    float s = 0.f;
    #pragma unroll
    for (int i = 0; i < 4; i++) s = fmaf(xr[lane + i * 64], pW[lane + i * 64], s);
    #pragma unroll
    for (int o = 32; o >= 1; o >>= 1) s += __shfl_xor(s, o, 64);
    if (lane == 0) out[row] = s + pb[0];
}

// ---------------------------------------------------------------------------
extern "C" void kernel_launch(void* const* d_in, const int* in_sizes, int n_in,
                              void* d_out, int out_size, void* d_ws, size_t ws_size,
                              hipStream_t stream)
{
    (void)in_sizes; (void)n_in; (void)out_size; (void)ws_size;

    const float* ct_t   = (const float*)d_in[0];
    const float* ts_t   = (const float*)d_in[1];
    const float* ct_emb = (const float*)d_in[2];
    const float* ts_emb = (const float*)d_in[3];
    const float* kp     = (const float*)d_in[4];
    const float* ct_W   = (const float*)d_in[5];
    const float* ct_b   = (const float*)d_in[6];
    const float* fW0    = (const float*)d_in[7];
    const float* fb0    = (const float*)d_in[8];
    const float* fW1    = (const float*)d_in[9];
    const float* fb1    = (const float*)d_in[10];
    const float* fW2    = (const float*)d_in[11];
    const float* fb2    = (const float*)d_in[12];
    const float* f_ln_g = (const float*)d_in[13];
    const float* f_ln_b = (const float*)d_in[14];
    const float* Wqkv   = (const float*)d_in[15];
    const float* bqkv   = (const float*)d_in[16];
    const float* Wo     = (const float*)d_in[17];
    const float* bo     = (const float*)d_in[18];
    const float* W1     = (const float*)d_in[19];
    const float* b1     = (const float*)d_in[20];
    const float* W2     = (const float*)d_in[21];
    const float* b2     = (const float*)d_in[22];
    const float* ln1_g  = (const float*)d_in[23];
    const float* ln1_b  = (const float*)d_in[24];
    const float* ln2_g  = (const float*)d_in[25];
    const float* ln2_b  = (const float*)d_in[26];
    const float* pred_W = (const float*)d_in[27];
    const float* pred_b = (const float*)d_in[28];

    float* ws = (float*)d_ws;
    float* ct_e  = ws;                 // 524288
    float* temp  = ws + 524288;        // 2097152
    float* ybuf  = temp;
    float* g1    = ws + 2621440;       // 2097152
    float* xbuf  = g1;
    float* aux   = ws + 4718592;       // region
    float* qkv   = aux;
    float* ff1   = aux;
    float* obuf  = ws + 11010048;      // 2097152

    const int NRts = Bsz * Lsz;  // 8192
    const int NRct = Bsz * Msz;  // 2048
    auto grid = [](int nr, int out) { return dim3((unsigned)((nr >> 6) * (out >> 6))); };

    // --- tokenizer ---
    gemm_kernel<<<grid(NRct, 256), 256, 0, stream>>>(ct_emb, ct_W, ct_b, nullptr,
                                                     ct_e, NRct, 256, 256, 0);
    tokenizer_kernel<<<dim3(Bsz * Lsz), 256, 0, stream>>>(ct_t, ts_t, ct_e, kp, temp);

    // --- fusion ---
    gemm_kernel<<<grid(NRts, 256), 256, 0, stream>>>(temp, fW0, fb0, nullptr,
                                                     g1, NRts, 256, 256, 0);
    gemm_kernel<<<grid(NRts, 256), 256, 0, stream>>>(ts_emb, fW1, fb1, g1,
                                                     aux, NRts, 256, 256, 1);
    gemm_kernel<<<grid(NRts, 256), 256, 0, stream>>>(aux, fW2, fb2, ts_emb,
                                                     ybuf, NRts, 256, 256, 0);
    ln_kernel<<<dim3(NRts), 256, 0, stream>>>(ybuf, f_ln_g, f_ln_b, xbuf);

    // --- transformer layers ---
    for (int l = 0; l < 2; l++) {
        gemm_kernel<<<grid(NRts, 768), 256, 0, stream>>>(
            xbuf, Wqkv + (size_t)l * 768 * 256, bqkv + l * 768, nullptr,
            qkv, NRts, 256, 768, 0);
        attn_mfma_kernel<<<dim3(512), 256, 0, stream>>>(qkv, obuf);
        gemm_kernel<<<grid(NRts, 256), 256, 0, stream>>>(
            obuf, Wo + (size_t)l * 256 * 256, bo + l * 256, xbuf,
            ybuf, NRts, 256, 256, 0);
        ln_kernel<<<dim3(NRts), 256, 0, stream>>>(ybuf, ln1_g + l * 256, ln1_b + l * 256, xbuf);
        gemm_kernel<<<grid(NRts, 512), 256, 0, stream>>>(
            xbuf, W1 + (size_t)l * 512 * 256, b1 + l * 512, nullptr,
            ff1, NRts, 256, 512, 2);
        gemm_kernel<<<grid(NRts, 256), 256, 0, stream>>>(
            ff1, W2 + (size_t)l * 256 * 512, b2 + l * 256, xbuf,
            ybuf, NRts, 512, 256, 0);
        ln_kernel<<<dim3(NRts), 256, 0, stream>>>(ybuf, ln2_g + l * 256, ln2_b + l * 256, xbuf);
    }

    // --- prediction head ---
    pred_kernel<<<dim3(NRts / 4), 256, 0, stream>>>(xbuf, pred_W, pred_b, (float*)d_out);
}

// Round 3
// 660.452 us; speedup vs baseline: 2.0961x; 1.3228x over previous
//
#include <hip/hip_runtime.h>
#include <hip/hip_bf16.h>
#include <cstddef>

// Shapes (compile-time constants from the reference)
// B=16, M=128, L=512, HID=256, H=4, DH=64, LAYERS=2
#define Bsz 16
#define Msz 128
#define Lsz 512
#define HIDs 256
#define Hh 4
#define DHs 64

typedef __attribute__((ext_vector_type(4))) float f32x4;
typedef __attribute__((ext_vector_type(8))) __bf16 bf16x8;
typedef __attribute__((ext_vector_type(8))) unsigned short ushort8;

static __device__ inline unsigned short f2bf(float f) {
    __hip_bfloat16 h = __float2bfloat16(f);
    return *(unsigned short*)&h;
}

// ---------------------------------------------------------------------------
// Generic GEMM: Y[NR,OUT] = act(X[NR,K] @ W[OUT,K]^T + bias[OUT] + add[NR,OUT])
// act: 0=none, 1=ELU, 2=GELU(exact)
// ---------------------------------------------------------------------------
__global__ __launch_bounds__(256) void gemm_kernel(
    const float* __restrict__ X, const float* __restrict__ W,
    const float* __restrict__ bias, const float* __restrict__ add,
    float* __restrict__ Y, int NR, int K, int OUT, int act)
{
    __shared__ float Xs[16][68];
    __shared__ float Ws[16][68];
    const int nbx = OUT >> 6;
    const int bx = blockIdx.x % nbx;
    const int by = blockIdx.x / nbx;
    const int r0 = by << 6, o0 = bx << 6;
    const int tid = threadIdx.x;
    const int tx = tid & 15, ty = tid >> 4;

    float acc[4][4] = {{0.f,0.f,0.f,0.f},{0.f,0.f,0.f,0.f},
                       {0.f,0.f,0.f,0.f},{0.f,0.f,0.f,0.f}};

    for (int k0 = 0; k0 < K; k0 += 16) {
        #pragma unroll
        for (int i = 0; i < 4; i++) {
            int idx = (i << 8) + tid;
            int kk = idx & 15, rr = idx >> 4;
            Xs[kk][rr] = X[(size_t)(r0 + rr) * K + (k0 + kk)];
            Ws[kk][rr] = W[(size_t)(o0 + rr) * K + (k0 + kk)];
        }
        __syncthreads();
        #pragma unroll
        for (int kk = 0; kk < 16; kk++) {
            float a[4], b[4];
            *(float4*)a = *(const float4*)&Xs[kk][ty << 2];
            *(float4*)b = *(const float4*)&Ws[kk][tx << 2];
            #pragma unroll
            for (int i = 0; i < 4; i++)
                #pragma unroll
                for (int j = 0; j < 4; j++)
                    acc[i][j] = fmaf(a[i], b[j], acc[i][j]);
        }
        __syncthreads();
    }

    #pragma unroll
    for (int i = 0; i < 4; i++) {
        int r = r0 + (ty << 2) + i;
        #pragma unroll
        for (int j = 0; j < 4; j++) {
            int o = o0 + (tx << 2) + j;
            float v = acc[i][j] + bias[o];
            if (add) v += add[(size_t)r * OUT + o];
            if (act == 1)      v = (v > 0.f) ? v : (__expf(v) - 1.f);
            else if (act == 2) v = 0.5f * v * (1.f + erff(v * 0.70710678118654752f));
            Y[(size_t)r * OUT + o] = v;
        }
    }
}

// ---------------------------------------------------------------------------
// Tokenizer denominators: invW[b,s,n,m] = 1 / sum_d exp(-(s+1)*alpha_d*x),
// x = (ct_t[b,m]-ts_t[b,n])^2, s=0..2 (scales 1..3; scale 0 is uniform 1/64).
// Thread = one (b,n,m); serial in-register d-loop (no cross-lane reduce).
// Grid = B*M*L/256 = 4096.
// ---------------------------------------------------------------------------
__global__ __launch_bounds__(256) void denom_kernel(
    const float* __restrict__ ct_t, const float* __restrict__ ts_t,
    const float* __restrict__ kp, float* __restrict__ invW)
{
    __shared__ float cal[64];   // -softplus(kp[d])
    const int tid = threadIdx.x;
    if (tid < 64) {
        float p = kp[tid];
        float a = fmaxf(p, 0.f) + log1pf(__expf(-fabsf(p)));
        cal[tid] = -a;
    }
    __syncthreads();

    const unsigned G = blockIdx.x * 256u + tid;
    const int b = G >> 16;
    const int n = (G >> 7) & 511;
    const int m = G & 127;

    float x = ct_t[b * Msz + m] - ts_t[b * Lsz + n];
    x = x * x;

    float s1 = 0.f, s2 = 0.f, s3 = 0.f;
    #pragma unroll
    for (int d = 0; d < 64; d++) {
        float e = __expf(cal[d] * x);   // exp(-alpha_d * x)
        float e2 = e * e;
        s1 += e;
        s2 += e2;
        s3 = fmaf(e2, e, s3);
    }
    const size_t base = ((size_t)b * 3 * Lsz + n) * Msz + m;
    invW[base]                        = 1.f / s1;
    invW[base + (size_t)Lsz * Msz]    = 1.f / s2;
    invW[base + (size_t)2 * Lsz * Msz] = 1.f / s3;
}

// ---------------------------------------------------------------------------
// Tokenizer v2: temp[b,n,s*64+d] = sum_m exp(-s*alpha_d*x)*invW[s] * ct_e[..]
// Block = (b,n), 4 waves; wave w handles scale s=w. Wave 0: sim==1/64.
// ---------------------------------------------------------------------------
__global__ __launch_bounds__(256) void tokenizer2_kernel(
    const float* __restrict__ ct_t, const float* __restrict__ ts_t,
    const float* __restrict__ ct_e, const float* __restrict__ kp,
    const float* __restrict__ invW, float* __restrict__ temp)
{
    const int bid = blockIdx.x;
    const int n = bid & (Lsz - 1);
    const int b = bid >> 9;
    const int t = threadIdx.x;
    const int w = t >> 6;
    const int d = t & 63;

    __shared__ float xs[Msz];
    const float tsn = ts_t[b * Lsz + n];
    if (t < Msz) {
        float df = ct_t[b * Msz + t] - tsn;
        xs[t] = df * df;
    }
    __syncthreads();

    const float* ce = ct_e + (size_t)b * Msz * HIDs + w * 64 + d;  // + m*256
    float acc = 0.f;

    if (w == 0) {
        #pragma unroll 4
        for (int m = 0; m < Msz; m++) acc += ce[(size_t)m * HIDs];
        acc *= (1.f / 64.f);
    } else {
        float p = kp[d];
        float a = fmaxf(p, 0.f) + log1pf(__expf(-fabsf(p)));
        const float c = -(float)w * a;
        const float* ivp = invW + ((size_t)(b * 3 + (w - 1)) * Lsz + n) * Msz;
        for (int m = 0; m < Msz; m += 4) {
            f32x4 xv = *(const f32x4*)&xs[m];
            f32x4 iv = *(const f32x4*)&ivp[m];
            float e0 = __expf(c * xv.x);
            float e1 = __expf(c * xv.y);
            float e2 = __expf(c * xv.z);
            float e3 = __expf(c * xv.w);
            acc = fmaf(e0 * iv.x, ce[(size_t)(m + 0) * HIDs], acc);
            acc = fmaf(e1 * iv.y, ce[(size_t)(m + 1) * HIDs], acc);
            acc = fmaf(e2 * iv.z, ce[(size_t)(m + 2) * HIDs], acc);
            acc = fmaf(e3 * iv.w, ce[(size_t)(m + 3) * HIDs], acc);
        }
    }
    temp[(size_t)(b * Lsz + n) * HIDs + t] = acc;
}

// ---------------------------------------------------------------------------
// MFMA bf16 flash attention (unchanged from round 1).
// ---------------------------------------------------------------------------
__global__ __launch_bounds__(256) void attn_mfma_kernel(
    const float* __restrict__ qkv, float* __restrict__ O)
{
    const int bid = blockIdx.x;
    const int qt = bid & 7;
    const int h  = (bid >> 3) & 3;
    const int b  = bid >> 5;
    const int t  = threadIdx.x;
    const int w  = t >> 6;
    const int lane = t & 63;
    const int g = lane >> 4;
    const int r = lane & 15;

    __shared__ float Ks[64][65];
    __shared__ float Vs[64][65];
    __shared__ float Ps[4][16][65];

    const float* base = qkv + (size_t)b * Lsz * 768;
    const int q0 = qt * 64 + w * 16;

    bf16x8 qf[2];
    {
        const float* qp = base + (size_t)(q0 + r) * 768 + h * 64 + 8 * g;
        #pragma unroll
        for (int f = 0; f < 2; f++) {
            ushort8 u;
            #pragma unroll
            for (int j = 0; j < 8; j++) u[j] = f2bf(qp[32 * f + j]);
            qf[f] = __builtin_bit_cast(bf16x8, u);
        }
    }

    f32x4 Ofr[4];
    #pragma unroll
    for (int dblk = 0; dblk < 4; dblk++) Ofr[dblk] = (f32x4){0.f, 0.f, 0.f, 0.f};
    float m_run[4] = {-1e30f, -1e30f, -1e30f, -1e30f};
    float l_run[4] = {0.f, 0.f, 0.f, 0.f};

    for (int c = 0; c < 8; c++) {
        __syncthreads();
        {
            const int rr = t >> 4;
            const int c4 = t & 15;
            #pragma unroll
            for (int i = 0; i < 4; i++) {
                int row = rr + 16 * i;
                const float* gp = base + (size_t)(c * 64 + row) * 768 + 256 + h * 64 + 4 * c4;
                *(float4*)&Ks[row][4 * c4] = *(const float4*)gp;
                *(float4*)&Vs[row][4 * c4] = *(const float4*)(gp + 256);
            }
        }
        __syncthreads();

        f32x4 sfr[4];
        #pragma unroll
        for (int s = 0; s < 4; s++) {
            f32x4 acc = (f32x4){0.f, 0.f, 0.f, 0.f};
            #pragma unroll
            for (int f = 0; f < 2; f++) {
                const float* kp2 = &Ks[s * 16 + r][8 * g + 32 * f];
                ushort8 u;
                #pragma unroll
                for (int j = 0; j < 8; j++) u[j] = f2bf(kp2[j]);
                acc = __builtin_amdgcn_mfma_f32_16x16x32_bf16(
                    qf[f], __builtin_bit_cast(bf16x8, u), acc, 0, 0, 0);
            }
            #pragma unroll
            for (int p = 0; p < 4; p++) acc[p] *= 0.125f;
            sfr[s] = acc;
        }

        #pragma unroll
        for (int p = 0; p < 4; p++) {
            float rm = fmaxf(fmaxf(sfr[0][p], sfr[1][p]), fmaxf(sfr[2][p], sfr[3][p]));
            #pragma unroll
            for (int o = 1; o <= 8; o <<= 1) rm = fmaxf(rm, __shfl_xor(rm, o));
            float mnew = fmaxf(m_run[p], rm);
            float sc = __expf(m_run[p] - mnew);
            m_run[p] = mnew;
            float rs = 0.f;
            #pragma unroll
            for (int s = 0; s < 4; s++) {
                float pv = __expf(sfr[s][p] - mnew);
                Ps[w][4 * g + p][s * 16 + r] = pv;
                rs += pv;
            }
            #pragma unroll
            for (int o = 1; o <= 8; o <<= 1) rs += __shfl_xor(rs, o);
            l_run[p] = l_run[p] * sc + rs;
            #pragma unroll
            for (int dblk = 0; dblk < 4; dblk++) Ofr[dblk][p] *= sc;
        }

        __asm__ volatile("s_waitcnt lgkmcnt(0)" ::: "memory");

        #pragma unroll
        for (int f = 0; f < 2; f++) {
            const float* pp = &Ps[w][r][8 * g + 32 * f];
            ushort8 ua;
            #pragma unroll
            for (int j = 0; j < 8; j++) ua[j] = f2bf(pp[j]);
            bf16x8 pa = __builtin_bit_cast(bf16x8, ua);
            #pragma unroll
            for (int dblk = 0; dblk < 4; dblk++) {
                ushort8 ub;
                #pragma unroll
                for (int j = 0; j < 8; j++)
                    ub[j] = f2bf(Vs[32 * f + 8 * g + j][dblk * 16 + r]);
                Ofr[dblk] = __builtin_amdgcn_mfma_f32_16x16x32_bf16(
                    pa, __builtin_bit_cast(bf16x8, ub), Ofr[dblk], 0, 0, 0);
            }
        }
    }

    #pragma unroll
    for (int dblk = 0; dblk < 4; dblk++) {
        #pragma unroll
        for (int p = 0; p < 4; p++) {
            int row = q0 + 4 * g + p;
            O[(size_t)(b * Lsz + row) * HIDs + h * 64 + dblk * 16 + r] =
                Ofr[dblk][p] / l_run[p];
        }
    }
}

// ---------------------------------------------------------------------------
// LayerNorm over last dim (256)
// ---------------------------------------------------------------------------
__global__ __launch_bounds__(256) void ln_kernel(
    const float* __restrict__ Y, const float* __restrict__ g,
    const float* __restrict__ b, float* __restrict__ X)
{
    const int row = blockIdx.x;
    const int t = threadIdx.x;
    float v = Y[(size_t)row * HIDs + t];

    __shared__ float red[8];
    float s = v;
    #pragma unroll
    for (int o = 32; o >= 1; o >>= 1) s += __shfl_xor(s, o, 64);
    const int w = t >> 6, lane = t & 63;
    if (lane == 0) red[w] = s;
    __syncthreads();
    float mu = (red[0] + red[1] + red[2] + red[3]) * (1.f / 256.f);
    float dl = v - mu;
    float q = dl * dl;
    #pragma unroll
    for (int o = 32; o >= 1; o >>= 1) q += __shfl_xor(q, o, 64);
    if (lane == 0) red[4 + w] = q;
    __syncthreads();
    float var = (red[4] + red[5] + red[6] + red[7]) * (1.f / 256.f);
    X[(size_t)row * HIDs + t] = dl * rsqrtf(var + 1e-5f) * g[t] + b[t];
}

// ---------------------------------------------------------------------------
// Prediction head
// ---------------------------------------------------------------------------
__global__ __launch_bounds__(256) void pred_kernel(
    const float* __restrict__ X, const float* __restrict__ pW,
    const float* __restrict__ pb, float* __restrict__ out)
{
    const int w = threadIdx.x >> 6, lane = threadIdx.x & 63;
    const int row = blockIdx.x * 4 + w;
    const float* xr = X + (size_t)row * HIDs;
    float s = 0.f;
    #pragma unroll
    for (int i = 0; i < 4; i++) s = fmaf(xr[lane + i * 64], pW[lane + i * 64], s);
    #pragma unroll
    for (int o = 32; o >= 1; o >>= 1) s += __shfl_xor(s, o, 64);
    if (lane == 0) out[row] = s + pb[0];
}

// ---------------------------------------------------------------------------
extern "C" void kernel_launch(void* const* d_in, const int* in_sizes, int n_in,
                              void* d_out, int out_size, void* d_ws, size_t ws_size,
                              hipStream_t stream)
{
    (void)in_sizes; (void)n_in; (void)out_size; (void)ws_size;

    const float* ct_t   = (const float*)d_in[0];
    const float* ts_t   = (const float*)d_in[1];
    const float* ct_emb = (const float*)d_in[2];
    const float* ts_emb = (const float*)d_in[3];
    const float* kp     = (const float*)d_in[4];
    const float* ct_W   = (const float*)d_in[5];
    const float* ct_b   = (const float*)d_in[6];
    const float* fW0    = (const float*)d_in[7];
    const float* fb0    = (const float*)d_in[8];
    const float* fW1    = (const float*)d_in[9];
    const float* fb1    = (const float*)d_in[10];
    const float* fW2    = (const float*)d_in[11];
    const float* fb2    = (const float*)d_in[12];
    const float* f_ln_g = (const float*)d_in[13];
    const float* f_ln_b = (const float*)d_in[14];
    const float* Wqkv   = (const float*)d_in[15];
    const float* bqkv   = (const float*)d_in[16];
    const float* Wo     = (const float*)d_in[17];
    const float* bo     = (const float*)d_in[18];
    const float* W1     = (const float*)d_in[19];
    const float* b1     = (const float*)d_in[20];
    const float* W2     = (const float*)d_in[21];
    const float* b2     = (const float*)d_in[22];
    const float* ln1_g  = (const float*)d_in[23];
    const float* ln1_b  = (const float*)d_in[24];
    const float* ln2_g  = (const float*)d_in[25];
    const float* ln2_b  = (const float*)d_in[26];
    const float* pred_W = (const float*)d_in[27];
    const float* pred_b = (const float*)d_in[28];

    float* ws = (float*)d_ws;
    float* ct_e  = ws;                 // 524288
    float* temp  = ws + 524288;        // 2097152
    float* ybuf  = temp;
    float* g1    = ws + 2621440;       // 2097152
    float* xbuf  = g1;
    float* aux   = ws + 4718592;       // region (6291456 floats)
    float* invW  = aux;                //   3145728 (dead before qkv written)
    float* qkv   = aux;
    float* ff1   = aux;
    float* obuf  = ws + 11010048;      // 2097152

    const int NRts = Bsz * Lsz;  // 8192
    const int NRct = Bsz * Msz;  // 2048
    auto grid = [](int nr, int out) { return dim3((unsigned)((nr >> 6) * (out >> 6))); };

    // --- tokenizer ---
    gemm_kernel<<<grid(NRct, 256), 256, 0, stream>>>(ct_emb, ct_W, ct_b, nullptr,
                                                     ct_e, NRct, 256, 256, 0);
    denom_kernel<<<dim3(Bsz * Msz * Lsz / 256), 256, 0, stream>>>(ct_t, ts_t, kp, invW);
    tokenizer2_kernel<<<dim3(Bsz * Lsz), 256, 0, stream>>>(ct_t, ts_t, ct_e, kp, invW, temp);

    // --- fusion ---
    gemm_kernel<<<grid(NRts, 256), 256, 0, stream>>>(temp, fW0, fb0, nullptr,
                                                     g1, NRts, 256, 256, 0);
    gemm_kernel<<<grid(NRts, 256), 256, 0, stream>>>(ts_emb, fW1, fb1, g1,
                                                     aux, NRts, 256, 256, 1);
    gemm_kernel<<<grid(NRts, 256), 256, 0, stream>>>(aux, fW2, fb2, ts_emb,
                                                     ybuf, NRts, 256, 256, 0);
    ln_kernel<<<dim3(NRts), 256, 0, stream>>>(ybuf, f_ln_g, f_ln_b, xbuf);

    // --- transformer layers ---
    for (int l = 0; l < 2; l++) {
        gemm_kernel<<<grid(NRts, 768), 256, 0, stream>>>(
            xbuf, Wqkv + (size_t)l * 768 * 256, bqkv + l * 768, nullptr,
            qkv, NRts, 256, 768, 0);
        attn_mfma_kernel<<<dim3(512), 256, 0, stream>>>(qkv, obuf);
        gemm_kernel<<<grid(NRts, 256), 256, 0, stream>>>(
            obuf, Wo + (size_t)l * 256 * 256, bo + l * 256, xbuf,
            ybuf, NRts, 256, 256, 0);
        ln_kernel<<<dim3(NRts), 256, 0, stream>>>(ybuf, ln1_g + l * 256, ln1_b + l * 256, xbuf);
        gemm_kernel<<<grid(NRts, 512), 256, 0, stream>>>(
            xbuf, W1 + (size_t)l * 512 * 256, b1 + l * 512, nullptr,
            ff1, NRts, 256, 512, 2);
        gemm_kernel<<<grid(NRts, 256), 256, 0, stream>>>(
            ff1, W2 + (size_t)l * 256 * 512, b2 + l * 256, xbuf,
            ybuf, NRts, 512, 256, 0);
        ln_kernel<<<dim3(NRts), 256, 0, stream>>>(ybuf, ln2_g + l * 256, ln2_b + l * 256, xbuf);
    }

    // --- prediction head ---
    pred_kernel<<<dim3(NRts / 4), 256, 0, stream>>>(xbuf, pred_W, pred_b, (float*)d_out);
}

// Round 4
// 427.954 us; speedup vs baseline: 3.2348x; 1.5433x over previous
//
#include <hip/hip_runtime.h>
#include <hip/hip_bf16.h>
#include <cstddef>

// Shapes (compile-time constants from the reference)
// B=16, M=128, L=512, HID=256, H=4, DH=64, LAYERS=2
#define Bsz 16
#define Msz 128
#define Lsz 512
#define HIDs 256
#define Hh 4
#define DHs 64

typedef __attribute__((ext_vector_type(4))) float f32x4;
typedef __attribute__((ext_vector_type(8))) __bf16 bf16x8;
typedef __attribute__((ext_vector_type(8))) unsigned short ushort8;

static __device__ inline unsigned short f2bf(float f) {
    __hip_bfloat16 h = __float2bfloat16(f);
    return *(unsigned short*)&h;
}

static __device__ inline void gload16(const ushort* g, ushort* l) {
    __builtin_amdgcn_global_load_lds(
        (const __attribute__((address_space(1))) void*)g,
        (__attribute__((address_space(3))) void*)l, 16, 0, 0);
}

// ---------------------------------------------------------------------------
// Convert fp32 -> bf16 for ts_emb, ct_emb and all weight matrices, packed
// into one contiguous bf16 region. Each thread does 8 elements.
// Grid = 491520/256 = 1920 blocks.
// ---------------------------------------------------------------------------
__global__ __launch_bounds__(256) void cvt_all_kernel(
    const float* __restrict__ ts_emb, const float* __restrict__ ct_emb,
    const float* __restrict__ ct_W, const float* __restrict__ fW0,
    const float* __restrict__ fW1, const float* __restrict__ fW2,
    const float* __restrict__ Wqkv, const float* __restrict__ Wo,
    const float* __restrict__ W1, const float* __restrict__ W2,
    ushort* __restrict__ dst)
{
    const unsigned u = blockIdx.x * 256u + threadIdx.x;   // ushort8-unit index
    const float* src; unsigned base;
    if      (u < 262144u) { src = ts_emb; base = 0u; }
    else if (u < 327680u) { src = ct_emb; base = 262144u; }
    else if (u < 335872u) { src = ct_W;   base = 327680u; }
    else if (u < 344064u) { src = fW0;    base = 335872u; }
    else if (u < 352256u) { src = fW1;    base = 344064u; }
    else if (u < 360448u) { src = fW2;    base = 352256u; }
    else if (u < 409600u) { src = Wqkv;   base = 360448u; }
    else if (u < 425984u) { src = Wo;     base = 409600u; }
    else if (u < 458752u) { src = W1;     base = 425984u; }
    else                  { src = W2;     base = 458752u; }
    const unsigned rel = u - base;
    float4 a = ((const float4*)src)[rel * 2];
    float4 b = ((const float4*)src)[rel * 2 + 1];
    ushort8 o;
    o[0] = f2bf(a.x); o[1] = f2bf(a.y); o[2] = f2bf(a.z); o[3] = f2bf(a.w);
    o[4] = f2bf(b.x); o[5] = f2bf(b.y); o[6] = f2bf(b.z); o[7] = f2bf(b.w);
    ((ushort8*)dst)[u] = o;
}

// ---------------------------------------------------------------------------
// MFMA bf16 GEMM: Y = act(X[NR,K] @ W[OUT,K]^T + bias + add)
// X, W bf16 (K-contiguous rows). Yf (fp32) and/or Yb (bf16) outputs, nullable.
// 128x128 tile / block (4 waves, 2x2), BK=64, global_load_lds staging with
// XOR-swizzled source chunks (LDS linear) so ds_read_b128 frags are ~2-way.
// Requires NR%128==0, OUT%128==0, K%64==0.
// act: 0=none, 1=ELU, 2=GELU(exact)
// ---------------------------------------------------------------------------
__global__ __launch_bounds__(256) void gemm_mfma_kernel(
    const ushort* __restrict__ X, const ushort* __restrict__ W,
    const float* __restrict__ bias, const float* __restrict__ add,
    float* __restrict__ Yf, ushort* __restrict__ Yb,
    int NR, int K, int OUT, int act)
{
    __shared__ ushort As[128 * 64];
    __shared__ ushort Bs[128 * 64];

    const int nbx = OUT >> 7;
    const int bx = blockIdx.x % nbx;
    const int by = blockIdx.x / nbx;
    const int r0 = by << 7, o0 = bx << 7;
    const int tid = threadIdx.x;
    const int w = tid >> 6;
    const int lane = tid & 63;
    const int wr = w >> 1, wc = w & 1;
    const int lr = lane & 15, lg = lane >> 4;

    // staging lane geometry
    const int grow = lane >> 3;                 // 0..7 row within 8-row slab
    const int gchunk = (lane & 7) ^ grow;       // swizzled source 16B-chunk

    // fragment LDS byte offsets (independent of k-step)
    unsigned aoff[4][2], boff[4][2];
    #pragma unroll
    for (int m = 0; m < 4; m++)
        #pragma unroll
        for (int f = 0; f < 2; f++) {
            int rowA = wr * 64 + m * 16 + lr;
            int rowB = wc * 64 + m * 16 + lr;
            unsigned c1 = (unsigned)((lg + 4 * f) ^ (lr & 7)) * 16u;
            aoff[m][f] = (unsigned)rowA * 128u + c1;
            boff[m][f] = (unsigned)rowB * 128u + c1;
        }

    f32x4 acc[4][4];
    #pragma unroll
    for (int m = 0; m < 4; m++)
        #pragma unroll
        for (int n = 0; n < 4; n++) acc[m][n] = (f32x4){0.f, 0.f, 0.f, 0.f};

    const int nk = K >> 6;
    for (int ks = 0; ks < nk; ks++) {
        const int k0 = ks << 6;
        if (ks) __syncthreads();     // previous tile fully consumed
        // ---- stage A,B: 4+4 global_load_lds (16B/lane) per wave ----
        #pragma unroll
        for (int i = 0; i < 4; i++) {
            int row = w * 32 + i * 8 + grow;
            gload16(X + (size_t)(r0 + row) * K + k0 + gchunk * 8,
                    &As[(w * 32 + i * 8) * 64]);
            gload16(W + (size_t)(o0 + row) * K + k0 + gchunk * 8,
                    &Bs[(w * 32 + i * 8) * 64]);
        }
        __syncthreads();             // drains vmcnt, data visible

        #pragma unroll
        for (int f = 0; f < 2; f++) {
            bf16x8 av[4], bv[4];
            #pragma unroll
            for (int m = 0; m < 4; m++)
                av[m] = *(const bf16x8*)((const char*)As + aoff[m][f]);
            #pragma unroll
            for (int n = 0; n < 4; n++)
                bv[n] = *(const bf16x8*)((const char*)Bs + boff[n][f]);
            #pragma unroll
            for (int m = 0; m < 4; m++)
                #pragma unroll
                for (int n = 0; n < 4; n++)
                    acc[m][n] = __builtin_amdgcn_mfma_f32_16x16x32_bf16(
                        av[m], bv[n], acc[m][n], 0, 0, 0);
        }
    }

    // ---- epilogue ----
    const int ocol0 = o0 + wc * 64;
    float bn[4];
    #pragma unroll
    for (int n = 0; n < 4; n++) bn[n] = bias[ocol0 + n * 16 + lr];
    const bool hasAdd = (add != nullptr);

    #pragma unroll
    for (int m = 0; m < 4; m++) {
        #pragma unroll
        for (int p = 0; p < 4; p++) {
            int r = r0 + wr * 64 + m * 16 + 4 * lg + p;
            size_t rb = (size_t)r * OUT;
            #pragma unroll
            for (int n = 0; n < 4; n++) {
                int o = ocol0 + n * 16 + lr;
                float v = acc[m][n][p] + bn[n];
                if (hasAdd) v += add[rb + o];
                if (act == 1)      v = (v > 0.f) ? v : (__expf(v) - 1.f);
                else if (act == 2) v = 0.5f * v * (1.f + erff(v * 0.70710678118654752f));
                if (Yf) Yf[rb + o] = v;
                if (Yb) Yb[rb + o] = f2bf(v);
            }
        }
    }
}

// ---------------------------------------------------------------------------
// Tokenizer denominators (unchanged)
// ---------------------------------------------------------------------------
__global__ __launch_bounds__(256) void denom_kernel(
    const float* __restrict__ ct_t, const float* __restrict__ ts_t,
    const float* __restrict__ kp, float* __restrict__ invW)
{
    __shared__ float cal[64];
    const int tid = threadIdx.x;
    if (tid < 64) {
        float p = kp[tid];
        float a = fmaxf(p, 0.f) + log1pf(__expf(-fabsf(p)));
        cal[tid] = -a;
    }
    __syncthreads();

    const unsigned G = blockIdx.x * 256u + tid;
    const int b = G >> 16;
    const int n = (G >> 7) & 511;
    const int m = G & 127;

    float x = ct_t[b * Msz + m] - ts_t[b * Lsz + n];
    x = x * x;

    float s1 = 0.f, s2 = 0.f, s3 = 0.f;
    #pragma unroll
    for (int d = 0; d < 64; d++) {
        float e = __expf(cal[d] * x);
        float e2 = e * e;
        s1 += e;
        s2 += e2;
        s3 = fmaf(e2, e, s3);
    }
    const size_t base = ((size_t)b * 3 * Lsz + n) * Msz + m;
    invW[base]                         = 1.f / s1;
    invW[base + (size_t)Lsz * Msz]     = 1.f / s2;
    invW[base + (size_t)2 * Lsz * Msz] = 1.f / s3;
}

// ---------------------------------------------------------------------------
// Tokenizer v2 (bf16 output for the following GEMM)
// ---------------------------------------------------------------------------
__global__ __launch_bounds__(256) void tokenizer2_kernel(
    const float* __restrict__ ct_t, const float* __restrict__ ts_t,
    const float* __restrict__ ct_e, const float* __restrict__ kp,
    const float* __restrict__ invW, ushort* __restrict__ tempb)
{
    const int bid = blockIdx.x;
    const int n = bid & (Lsz - 1);
    const int b = bid >> 9;
    const int t = threadIdx.x;
    const int w = t >> 6;
    const int d = t & 63;

    __shared__ float xs[Msz];
    const float tsn = ts_t[b * Lsz + n];
    if (t < Msz) {
        float df = ct_t[b * Msz + t] - tsn;
        xs[t] = df * df;
    }
    __syncthreads();

    const float* ce = ct_e + (size_t)b * Msz * HIDs + w * 64 + d;
    float acc = 0.f;

    if (w == 0) {
        #pragma unroll 4
        for (int m = 0; m < Msz; m++) acc += ce[(size_t)m * HIDs];
        acc *= (1.f / 64.f);
    } else {
        float p = kp[d];
        float a = fmaxf(p, 0.f) + log1pf(__expf(-fabsf(p)));
        const float c = -(float)w * a;
        const float* ivp = invW + ((size_t)(b * 3 + (w - 1)) * Lsz + n) * Msz;
        for (int m = 0; m < Msz; m += 4) {
            f32x4 xv = *(const f32x4*)&xs[m];
            f32x4 iv = *(const f32x4*)&ivp[m];
            float e0 = __expf(c * xv.x);
            float e1 = __expf(c * xv.y);
            float e2 = __expf(c * xv.z);
            float e3 = __expf(c * xv.w);
            acc = fmaf(e0 * iv.x, ce[(size_t)(m + 0) * HIDs], acc);
            acc = fmaf(e1 * iv.y, ce[(size_t)(m + 1) * HIDs], acc);
            acc = fmaf(e2 * iv.z, ce[(size_t)(m + 2) * HIDs], acc);
            acc = fmaf(e3 * iv.w, ce[(size_t)(m + 3) * HIDs], acc);
        }
    }
    tempb[(size_t)(b * Lsz + n) * HIDs + t] = f2bf(acc);
}

// ---------------------------------------------------------------------------
// MFMA bf16 flash attention, bf16 qkv input, bf16 O output.
// Block = 4 waves, one (b,h), 64 q-rows. Grid = 512.
// K staged row-major [64][72] (pad -> 2-way b128 reads); V staged TRANSPOSED
// Vt[d][k] so the PV B-operand is a contiguous b128 read.
// ---------------------------------------------------------------------------
__global__ __launch_bounds__(256) void attn_mfma_kernel(
    const ushort* __restrict__ qkv, ushort* __restrict__ Ob)
{
    const int bid = blockIdx.x;
    const int qt = bid & 7;
    const int h  = (bid >> 3) & 3;
    const int b  = bid >> 5;
    const int t  = threadIdx.x;
    const int w  = t >> 6;
    const int lane = t & 63;
    const int g = lane >> 4;
    const int r = lane & 15;

    __shared__ ushort Ks[64][72];
    __shared__ ushort Vt[64][72];   // [d][k]
    __shared__ float  Ps[4][16][65];

    const ushort* base = qkv + (size_t)b * Lsz * 768;
    const int q0 = qt * 64 + w * 16;

    bf16x8 qf[2];
    {
        const ushort* qp = base + (size_t)(q0 + r) * 768 + h * 64 + 8 * g;
        qf[0] = __builtin_bit_cast(bf16x8, *(const ushort8*)qp);
        qf[1] = __builtin_bit_cast(bf16x8, *(const ushort8*)(qp + 32));
    }

    f32x4 Ofr[4];
    #pragma unroll
    for (int dblk = 0; dblk < 4; dblk++) Ofr[dblk] = (f32x4){0.f, 0.f, 0.f, 0.f};
    float m_run[4] = {-1e30f, -1e30f, -1e30f, -1e30f};
    float l_run[4] = {0.f, 0.f, 0.f, 0.f};

    const int srow = t >> 2;        // 0..63
    const int sseg = t & 3;         // 0..3  (16 elems each)

    for (int c = 0; c < 8; c++) {
        __syncthreads();
        {
            const ushort* kr = base + (size_t)(c * 64 + srow) * 768 + 256 + h * 64 + sseg * 16;
            ushort8 k0 = *(const ushort8*)kr;
            ushort8 k1 = *(const ushort8*)(kr + 8);
            *(ushort8*)&Ks[srow][sseg * 16]     = k0;
            *(ushort8*)&Ks[srow][sseg * 16 + 8] = k1;
            ushort8 v0 = *(const ushort8*)(kr + 256);
            ushort8 v1 = *(const ushort8*)(kr + 264);
            #pragma unroll
            for (int j = 0; j < 8; j++) {
                Vt[sseg * 16 + j][srow]     = v0[j];
                Vt[sseg * 16 + 8 + j][srow] = v1[j];
            }
        }
        __syncthreads();

        // ---- S = (Q K^T) * 0.125 ----
        f32x4 sfr[4];
        #pragma unroll
        for (int s = 0; s < 4; s++) {
            f32x4 a2 = (f32x4){0.f, 0.f, 0.f, 0.f};
            #pragma unroll
            for (int f = 0; f < 2; f++) {
                bf16x8 kf = *(const bf16x8*)&Ks[s * 16 + r][8 * g + 32 * f];
                a2 = __builtin_amdgcn_mfma_f32_16x16x32_bf16(qf[f], kf, a2, 0, 0, 0);
            }
            #pragma unroll
            for (int p = 0; p < 4; p++) a2[p] *= 0.125f;
            sfr[s] = a2;
        }

        // ---- online softmax ----
        #pragma unroll
        for (int p = 0; p < 4; p++) {
            float rm = fmaxf(fmaxf(sfr[0][p], sfr[1][p]), fmaxf(sfr[2][p], sfr[3][p]));
            #pragma unroll
            for (int o = 1; o <= 8; o <<= 1) rm = fmaxf(rm, __shfl_xor(rm, o));
            float mnew = fmaxf(m_run[p], rm);
            float sc = __expf(m_run[p] - mnew);
            m_run[p] = mnew;
            float rs = 0.f;
            #pragma unroll
            for (int s = 0; s < 4; s++) {
                float pv = __expf(sfr[s][p] - mnew);
                Ps[w][4 * g + p][s * 16 + r] = pv;
                rs += pv;
            }
            #pragma unroll
            for (int o = 1; o <= 8; o <<= 1) rs += __shfl_xor(rs, o);
            l_run[p] = l_run[p] * sc + rs;
            #pragma unroll
            for (int dblk = 0; dblk < 4; dblk++) Ofr[dblk][p] *= sc;
        }

        __asm__ volatile("s_waitcnt lgkmcnt(0)" ::: "memory");

        // ---- O += P @ V ----
        #pragma unroll
        for (int f = 0; f < 2; f++) {
            const float* pp = &Ps[w][r][8 * g + 32 * f];
            ushort8 ua;
            #pragma unroll
            for (int j = 0; j < 8; j++) ua[j] = f2bf(pp[j]);
            bf16x8 pa = __builtin_bit_cast(bf16x8, ua);
            #pragma unroll
            for (int dblk = 0; dblk < 4; dblk++) {
                bf16x8 vb = *(const bf16x8*)&Vt[dblk * 16 + r][32 * f + 8 * g];
                Ofr[dblk] = __builtin_amdgcn_mfma_f32_16x16x32_bf16(
                    pa, vb, Ofr[dblk], 0, 0, 0);
            }
        }
    }

    #pragma unroll
    for (int dblk = 0; dblk < 4; dblk++) {
        #pragma unroll
        for (int p = 0; p < 4; p++) {
            int row = q0 + 4 * g + p;
            Ob[(size_t)(b * Lsz + row) * HIDs + h * 64 + dblk * 16 + r] =
                f2bf(Ofr[dblk][p] / l_run[p]);
        }
    }
}

// ---------------------------------------------------------------------------
// LayerNorm over last dim (256), dual fp32 + bf16 output
// ---------------------------------------------------------------------------
__global__ __launch_bounds__(256) void ln_kernel(
    const float* __restrict__ Y, const float* __restrict__ g,
    const float* __restrict__ b, float* __restrict__ X, ushort* __restrict__ Xb)
{
    const int row = blockIdx.x;
    const int t = threadIdx.x;
    float v = Y[(size_t)row * HIDs + t];

    __shared__ float red[8];
    float s = v;
    #pragma unroll
    for (int o = 32; o >= 1; o >>= 1) s += __shfl_xor(s, o, 64);
    const int w = t >> 6, lane = t & 63;
    if (lane == 0) red[w] = s;
    __syncthreads();
    float mu = (red[0] + red[1] + red[2] + red[3]) * (1.f / 256.f);
    float dl = v - mu;
    float q = dl * dl;
    #pragma unroll
    for (int o = 32; o >= 1; o >>= 1) q += __shfl_xor(q, o, 64);
    if (lane == 0) red[4 + w] = q;
    __syncthreads();
    float var = (red[4] + red[5] + red[6] + red[7]) * (1.f / 256.f);
    float out = dl * rsqrtf(var + 1e-5f) * g[t] + b[t];
    X[(size_t)row * HIDs + t] = out;
    Xb[(size_t)row * HIDs + t] = f2bf(out);
}

// ---------------------------------------------------------------------------
// Prediction head
// ---------------------------------------------------------------------------
__global__ __launch_bounds__(256) void pred_kernel(
    const float* __restrict__ X, const float* __restrict__ pW,
    const float* __restrict__ pb, float* __restrict__ out)
{
    const int w = threadIdx.x >> 6, lane = threadIdx.x & 63;
    const int row = blockIdx.x * 4 + w;
    const float* xr = X + (size_t)row * HIDs;
    float s = 0.f;
    #pragma unroll
    for (int i = 0; i < 4; i++) s = fmaf(xr[lane + i * 64], pW[lane + i * 64], s);
    #pragma unroll
    for (int o = 32; o >= 1; o >>= 1) s += __shfl_xor(s, o, 64);
    if (lane == 0) out[row] = s + pb[0];
}

// ---------------------------------------------------------------------------
extern "C" void kernel_launch(void* const* d_in, const int* in_sizes, int n_in,
                              void* d_out, int out_size, void* d_ws, size_t ws_size,
                              hipStream_t stream)
{
    (void)in_sizes; (void)n_in; (void)out_size; (void)ws_size;

    const float* ct_t   = (const float*)d_in[0];
    const float* ts_t   = (const float*)d_in[1];
    const float* ct_emb = (const float*)d_in[2];
    const float* ts_emb = (const float*)d_in[3];
    const float* kp     = (const float*)d_in[4];
    const float* ct_W   = (const float*)d_in[5];
    const float* ct_b   = (const float*)d_in[6];
    const float* fW0    = (const float*)d_in[7];
    const float* fb0    = (const float*)d_in[8];
    const float* fW1    = (const float*)d_in[9];
    const float* fb1    = (const float*)d_in[10];
    const float* fW2    = (const float*)d_in[11];
    const float* fb2    = (const float*)d_in[12];
    const float* f_ln_g = (const float*)d_in[13];
    const float* f_ln_b = (const float*)d_in[14];
    const float* Wqkv   = (const float*)d_in[15];
    const float* bqkv   = (const float*)d_in[16];
    const float* Wo     = (const float*)d_in[17];
    const float* bo     = (const float*)d_in[18];
    const float* W1     = (const float*)d_in[19];
    const float* b1     = (const float*)d_in[20];
    const float* W2     = (const float*)d_in[21];
    const float* b2     = (const float*)d_in[22];
    const float* ln1_g  = (const float*)d_in[23];
    const float* ln1_b  = (const float*)d_in[24];
    const float* ln2_g  = (const float*)d_in[25];
    const float* ln2_b  = (const float*)d_in[26];
    const float* pred_W = (const float*)d_in[27];
    const float* pred_b = (const float*)d_in[28];

    // ---- workspace layout ----
    // bf16 region (ushort offsets):
    ushort* wsb = (ushort*)d_ws;
    ushort* tsb  = wsb;               // 2097152
    ushort* ceb  = wsb + 2097152;     // 524288
    ushort* wct  = wsb + 2621440;     // 65536
    ushort* wf0  = wsb + 2686976;     // 65536
    ushort* wf1  = wsb + 2752512;     // 65536
    ushort* wf2  = wsb + 2818048;     // 65536
    ushort* wqkv = wsb + 2883584;     // 393216 (2 layers)
    ushort* wo   = wsb + 3276800;     // 131072
    ushort* w1   = wsb + 3407872;     // 262144
    ushort* w2   = wsb + 3670016;     // 262144  -> ends 3932160 us

    // fp32 region (float offsets):
    float* ws = (float*)d_ws;
    float* ct_e = ws + 1966080;       // 524288 fl
    float* Rreg = ws + 2490368;       // 3145728 fl shared: invW | qkvbf | auxbf | ff1bf
    float* invW = Rreg;
    ushort* qkvbf = (ushort*)Rreg;    // 6291456 us max
    ushort* auxbf = (ushort*)Rreg;
    ushort* ff1bf = (ushort*)Rreg;
    ushort* tempb = (ushort*)(ws + 5636096);  // 2097152 us
    float* ybuf = ws + 6684672;       // 2097152 fl
    float* xbuf = ws + 8781824;       // 2097152 fl
    ushort* xbf = (ushort*)(ws + 10878976);  // 2097152 us
    ushort* obf = (ushort*)(ws + 11927552);  // 2097152 us -> ends 12976128 fl

    const int NRts = Bsz * Lsz;  // 8192
    const int NRct = Bsz * Msz;  // 2048
    auto grid = [](int nr, int out) { return dim3((unsigned)((nr >> 7) * (out >> 7))); };

    // --- convert inputs + weights to bf16 ---
    cvt_all_kernel<<<dim3(1920), 256, 0, stream>>>(
        ts_emb, ct_emb, ct_W, fW0, fW1, fW2, Wqkv, Wo, W1, W2, wsb);

    // --- tokenizer ---
    gemm_mfma_kernel<<<grid(NRct, 256), 256, 0, stream>>>(
        ceb, wct, ct_b, nullptr, ct_e, nullptr, NRct, 256, 256, 0);
    denom_kernel<<<dim3(Bsz * Msz * Lsz / 256), 256, 0, stream>>>(ct_t, ts_t, kp, invW);
    tokenizer2_kernel<<<dim3(Bsz * Lsz), 256, 0, stream>>>(ct_t, ts_t, ct_e, kp, invW, tempb);

    // --- fusion ---
    gemm_mfma_kernel<<<grid(NRts, 256), 256, 0, stream>>>(
        tempb, wf0, fb0, nullptr, ybuf /*g1*/, nullptr, NRts, 256, 256, 0);
    gemm_mfma_kernel<<<grid(NRts, 256), 256, 0, stream>>>(
        tsb, wf1, fb1, ybuf /*g1*/, nullptr, auxbf, NRts, 256, 256, 1);
    gemm_mfma_kernel<<<grid(NRts, 256), 256, 0, stream>>>(
        auxbf, wf2, fb2, ts_emb, ybuf, nullptr, NRts, 256, 256, 0);
    ln_kernel<<<dim3(NRts), 256, 0, stream>>>(ybuf, f_ln_g, f_ln_b, xbuf, xbf);

    // --- transformer layers ---
    for (int l = 0; l < 2; l++) {
        gemm_mfma_kernel<<<grid(NRts, 768), 256, 0, stream>>>(
            xbf, wqkv + (size_t)l * 196608, bqkv + l * 768, nullptr,
            nullptr, qkvbf, NRts, 256, 768, 0);
        attn_mfma_kernel<<<dim3(512), 256, 0, stream>>>(qkvbf, obf);
        gemm_mfma_kernel<<<grid(NRts, 256), 256, 0, stream>>>(
            obf, wo + (size_t)l * 65536, bo + l * 256, xbuf,
            ybuf, nullptr, NRts, 256, 256, 0);
        ln_kernel<<<dim3(NRts), 256, 0, stream>>>(ybuf, ln1_g + l * 256, ln1_b + l * 256, xbuf, xbf);
        gemm_mfma_kernel<<<grid(NRts, 512), 256, 0, stream>>>(
            xbf, w1 + (size_t)l * 131072, b1 + l * 512, nullptr,
            nullptr, ff1bf, NRts, 256, 512, 2);
        gemm_mfma_kernel<<<grid(NRts, 256), 256, 0, stream>>>(
            ff1bf, w2 + (size_t)l * 131072, b2 + l * 256, xbuf,
            ybuf, nullptr, NRts, 512, 256, 0);
        ln_kernel<<<dim3(NRts), 256, 0, stream>>>(ybuf, ln2_g + l * 256, ln2_b + l * 256, xbuf, xbf);
    }

    // --- prediction head ---
    pred_kernel<<<dim3(NRts / 4), 256, 0, stream>>>(xbuf, pred_W, pred_b, (float*)d_out);
}

// Round 5
// 289.390 us; speedup vs baseline: 4.7837x; 1.4788x over previous
//
#include <hip/hip_runtime.h>
#include <hip/hip_bf16.h>
#include <cstddef>

// Shapes: B=16, M=128, L=512, HID=256, H=4, DH=64, LAYERS=2
#define Bsz 16
#define Msz 128
#define Lsz 512
#define HIDs 256

typedef __attribute__((ext_vector_type(4))) float f32x4;
typedef __attribute__((ext_vector_type(8))) __bf16 bf16x8;
typedef __attribute__((ext_vector_type(8))) unsigned short ushort8;

#define CHEB_K 12
#define PI_F 3.14159265358979323846f

static __device__ inline unsigned short f2bf(float f) {
    __hip_bfloat16 h = __float2bfloat16(f);
    return *(unsigned short*)&h;
}
static __device__ inline float bf2f(unsigned short u) {
    return __builtin_bit_cast(float, (unsigned)u << 16);
}
static __device__ inline void gload16(const ushort* g, ushort* l) {
    __builtin_amdgcn_global_load_lds(
        (const __attribute__((address_space(1))) void*)g,
        (__attribute__((address_space(3))) void*)l, 16, 0, 0);
}

// ---------------------------------------------------------------------------
// fp32 -> bf16 conversion / repacking.
//   ts_emb -> Xcat[row][256+col]   (second half of K=512 concat input)
//   fW0    -> Wcat[o][0..255], fW1 -> Wcat[o][256..511]
//   others linear.
// ---------------------------------------------------------------------------
__global__ __launch_bounds__(256) void cvt_all_kernel(
    const float* __restrict__ ts_emb, const float* __restrict__ ct_emb,
    const float* __restrict__ ct_W, const float* __restrict__ fW0,
    const float* __restrict__ fW1, const float* __restrict__ fW2,
    const float* __restrict__ Wqkv, const float* __restrict__ Wo,
    const float* __restrict__ W1, const float* __restrict__ W2,
    ushort* __restrict__ Xcat, ushort* __restrict__ Wcat,
    ushort* __restrict__ cebin, ushort* __restrict__ wct,
    ushort* __restrict__ wf2, ushort* __restrict__ wqkv,
    ushort* __restrict__ wo, ushort* __restrict__ w1, ushort* __restrict__ w2)
{
    const unsigned u = blockIdx.x * 256u + threadIdx.x;   // ushort8-unit idx
    const float* src; ushort* dst; unsigned rel;
    if (u < 262144u) {            // ts_emb -> Xcat strided
        rel = u; src = ts_emb;
        dst = Xcat + ((size_t)(rel >> 5) * 512 + 256 + (rel & 31) * 8);
    } else if (u < 327680u) { rel = u - 262144u; src = ct_emb; dst = cebin + (size_t)rel * 8; }
    else if (u < 335872u) { rel = u - 327680u; src = ct_W; dst = wct + (size_t)rel * 8; }
    else if (u < 344064u) { rel = u - 335872u; src = fW0;
        dst = Wcat + ((size_t)(rel >> 5) * 512 + (rel & 31) * 8); }
    else if (u < 352256u) { rel = u - 344064u; src = fW1;
        dst = Wcat + ((size_t)(rel >> 5) * 512 + 256 + (rel & 31) * 8); }
    else if (u < 360448u) { rel = u - 352256u; src = fW2; dst = wf2 + (size_t)rel * 8; }
    else if (u < 409600u) { rel = u - 360448u; src = Wqkv; dst = wqkv + (size_t)rel * 8; }
    else if (u < 425984u) { rel = u - 409600u; src = Wo;  dst = wo + (size_t)rel * 8; }
    else if (u < 458752u) { rel = u - 425984u; src = W1;  dst = w1 + (size_t)rel * 8; }
    else                  { rel = u - 458752u; src = W2;  dst = w2 + (size_t)rel * 8; }
    float4 a = ((const float4*)src)[(size_t)rel * 2];
    float4 b = ((const float4*)src)[(size_t)rel * 2 + 1];
    ushort8 o;
    o[0] = f2bf(a.x); o[1] = f2bf(a.y); o[2] = f2bf(a.z); o[3] = f2bf(a.w);
    o[4] = f2bf(b.x); o[5] = f2bf(b.y); o[6] = f2bf(b.z); o[7] = f2bf(b.w);
    *(ushort8*)dst = o;
}

// ---------------------------------------------------------------------------
// MFMA bf16 GEMM: Y = act(X[NR,K] @ W[OUT,K]^T + bias (+bias2) (+add))
// 64x128 tile, 4 waves (2x2), BK=64, global_load_lds w/ XOR-swizzled source.
// Requires NR%64==0, OUT%128==0, K%64==0. act: 0=none,1=ELU,2=GELU.
// ---------------------------------------------------------------------------
__global__ __launch_bounds__(256) void gemm_mfma_kernel(
    const ushort* __restrict__ X, const ushort* __restrict__ W,
    const float* __restrict__ bias, const float* __restrict__ bias2,
    const float* __restrict__ add,
    float* __restrict__ Yf, ushort* __restrict__ Yb,
    int NR, int K, int OUT, int act)
{
    __shared__ ushort As[64 * 64];
    __shared__ ushort Bs[128 * 64];

    const int nbx = OUT >> 7;
    const int bx = blockIdx.x % nbx;
    const int by = blockIdx.x / nbx;
    const int r0 = by << 6, o0 = bx << 7;
    const int tid = threadIdx.x;
    const int w = tid >> 6;
    const int lane = tid & 63;
    const int wr = w >> 1, wc = w & 1;
    const int lr = lane & 15, lg = lane >> 4;

    const int grow = lane >> 3;
    const int gchunk = (lane & 7) ^ grow;

    unsigned aoff[2][2], boff[4][2];
    #pragma unroll
    for (int f = 0; f < 2; f++) {
        unsigned c1base = (unsigned)(lg + 4 * f);
        #pragma unroll
        for (int m = 0; m < 2; m++) {
            int rowA = wr * 32 + m * 16 + lr;
            aoff[m][f] = (unsigned)rowA * 128u + ((c1base ^ (lr & 7)) * 16u);
        }
        #pragma unroll
        for (int n = 0; n < 4; n++) {
            int rowB = wc * 64 + n * 16 + lr;
            boff[n][f] = (unsigned)rowB * 128u + ((c1base ^ (lr & 7)) * 16u);
        }
    }

    f32x4 acc[2][4];
    #pragma unroll
    for (int m = 0; m < 2; m++)
        #pragma unroll
        for (int n = 0; n < 4; n++) acc[m][n] = (f32x4){0.f, 0.f, 0.f, 0.f};

    const int nk = K >> 6;
    for (int ks = 0; ks < nk; ks++) {
        const int k0 = ks << 6;
        if (ks) __syncthreads();
        #pragma unroll
        for (int i = 0; i < 2; i++) {
            int row = w * 16 + i * 8 + grow;
            gload16(X + (size_t)(r0 + row) * K + k0 + gchunk * 8,
                    &As[(w * 16 + i * 8) * 64]);
        }
        #pragma unroll
        for (int i = 0; i < 4; i++) {
            int row = w * 32 + i * 8 + grow;
            gload16(W + (size_t)(o0 + row) * K + k0 + gchunk * 8,
                    &Bs[(w * 32 + i * 8) * 64]);
        }
        __syncthreads();

        #pragma unroll
        for (int f = 0; f < 2; f++) {
            bf16x8 av[2], bv[4];
            #pragma unroll
            for (int m = 0; m < 2; m++)
                av[m] = *(const bf16x8*)((const char*)As + aoff[m][f]);
            #pragma unroll
            for (int n = 0; n < 4; n++)
                bv[n] = *(const bf16x8*)((const char*)Bs + boff[n][f]);
            #pragma unroll
            for (int m = 0; m < 2; m++)
                #pragma unroll
                for (int n = 0; n < 4; n++)
                    acc[m][n] = __builtin_amdgcn_mfma_f32_16x16x32_bf16(
                        av[m], bv[n], acc[m][n], 0, 0, 0);
        }
    }

    const int ocol0 = o0 + wc * 64;
    float bn[4];
    #pragma unroll
    for (int n = 0; n < 4; n++) {
        int o = ocol0 + n * 16 + lr;
        bn[n] = bias[o] + (bias2 ? bias2[o] : 0.f);
    }
    const bool hasAdd = (add != nullptr);

    #pragma unroll
    for (int m = 0; m < 2; m++) {
        #pragma unroll
        for (int p = 0; p < 4; p++) {
            int r = r0 + wr * 32 + m * 16 + 4 * lg + p;
            size_t rb = (size_t)r * OUT;
            #pragma unroll
            for (int n = 0; n < 4; n++) {
                int o = ocol0 + n * 16 + lr;
                float v = acc[m][n][p] + bn[n];
                if (hasAdd) v += add[rb + o];
                if (act == 1)      v = (v > 0.f) ? v : (__expf(v) - 1.f);
                else if (act == 2) v = 0.5f * v * (1.f + erff(v * 0.70710678118654752f));
                if (Yf) Yf[rb + o] = v;
                if (Yb) Yb[rb + o] = f2bf(v);
            }
        }
    }
}

// ---------------------------------------------------------------------------
// Chebyshev coefficients: clut[s1][k][d] = c_k(u), u=(s1+1)*softplus(kp[d]),
// for e^{-u x} on x in [0,1], T_k(2x-1). Also cD[s1][k] = sum_d c_k (for the
// denominator poly). One block, 256 threads (192 active = 3 waves x 64 d).
// ---------------------------------------------------------------------------
__global__ __launch_bounds__(256) void cheb_kernel(
    const float* __restrict__ kp, float* __restrict__ clut, float* __restrict__ cD)
{
    __shared__ float costab[CHEB_K][32];
    __shared__ float xq[32];
    __shared__ float alph[64];
    const int t = threadIdx.x;
    if (t < 64) {
        float p = kp[t];
        alph[t] = fmaxf(p, 0.f) + log1pf(__expf(-fabsf(p)));
    }
    #pragma unroll
    for (int i = 0; i < 2; i++) {
        int idx = i * 256 + t;
        if (idx < CHEB_K * 32) {
            int k = idx >> 5, q = idx & 31;
            float th = (q + 0.5f) * (PI_F / 32.f);
            costab[k][q] = __cosf((float)k * th);
        }
    }
    if (t < 32) xq[t] = 0.5f * (1.f + __cosf((t + 0.5f) * (PI_F / 32.f)));
    __syncthreads();

    if (t >= 192) return;
    const int d = t & 63, s1 = t >> 6;
    const float u = (float)(s1 + 1) * alph[d];
    float f[32];
    #pragma unroll
    for (int q = 0; q < 32; q++) f[q] = __expf(-u * xq[q]);
    #pragma unroll
    for (int k = 0; k < CHEB_K; k++) {
        float sum = 0.f;
        #pragma unroll
        for (int q = 0; q < 32; q++) sum = fmaf(f[q], costab[k][q], sum);
        float c = sum * ((k == 0 ? 1.f : 2.f) / 32.f);
        clut[s1 * (CHEB_K * 64) + k * 64 + d] = c;
        float sr = c;
        #pragma unroll
        for (int o = 1; o <= 32; o <<= 1) sr += __shfl_xor(sr, o, 64);
        if (d == 0) cD[s1 * CHEB_K + k] = sr;
    }
}

// ---------------------------------------------------------------------------
// Denominators via Clenshaw-free T-recurrence: invW[b,s1,n,m] (bf16)
//   = 1 / sum_d e^{-(s1+1) a_d x},  evaluated as poly_s(x) with cD coeffs.
// Grid 4096 x 256.
// ---------------------------------------------------------------------------
__global__ __launch_bounds__(256) void denom3_kernel(
    const float* __restrict__ ct_t, const float* __restrict__ ts_t,
    const float* __restrict__ cD, ushort* __restrict__ invW)
{
    __shared__ float cd[3][CHEB_K];
    const int tid = threadIdx.x;
    if (tid < 3 * CHEB_K) cd[tid / CHEB_K][tid % CHEB_K] = cD[tid];
    __syncthreads();

    const unsigned G = blockIdx.x * 256u + tid;
    const int b = G >> 16;
    const int n = (G >> 7) & 511;
    const int m = G & 127;

    float x = ct_t[b * Msz + m] - ts_t[b * Lsz + n];
    x = x * x;
    const float xi = 2.f * x - 1.f;
    const float xi2 = 2.f * xi;

    float t0 = 1.f, t1 = xi;
    float a1 = cd[0][0] + cd[0][1] * xi;
    float a2 = cd[1][0] + cd[1][1] * xi;
    float a3 = cd[2][0] + cd[2][1] * xi;
    #pragma unroll
    for (int k = 2; k < CHEB_K; k++) {
        float tn = fmaf(xi2, t1, -t0);
        a1 = fmaf(cd[0][k], tn, a1);
        a2 = fmaf(cd[1][k], tn, a2);
        a3 = fmaf(cd[2][k], tn, a3);
        t0 = t1; t1 = tn;
    }
    const size_t base = ((size_t)b * 3 * Lsz + n) * Msz + m;
    invW[base]                         = f2bf(1.f / a1);
    invW[base + (size_t)Lsz * Msz]     = f2bf(1.f / a2);
    invW[base + (size_t)2 * Lsz * Msz] = f2bf(1.f / a3);
}

// ---------------------------------------------------------------------------
// Tokenizer as MFMA: block=(b, s1, ntile64), 4 waves = 16-row n-slices.
// out[n, d] = sum_k c_k(s,d) * sum_m (invW*T_k(xi))[n,m] * ce[m, s*64+d]
// A_k built in registers via T-recurrence directly in MFMA A-frag layout.
// Writes Xcat cols (s1+1)*64 .. +63. Grid = 16*3*8 = 384.
// ---------------------------------------------------------------------------
__global__ __launch_bounds__(256) void tok3_kernel(
    const float* __restrict__ ct_t, const float* __restrict__ ts_t,
    const ushort* __restrict__ ceb, const ushort* __restrict__ invW,
    const float* __restrict__ clut, ushort* __restrict__ Xcat)
{
    const int bid = blockIdx.x;
    const int nt = bid & 7;
    const int s1 = (bid >> 3) % 3;
    const int b  = bid / 24;
    const int tid = threadIdx.x;
    const int w = tid >> 6, lane = tid & 63, g = lane >> 4, r = lane & 15;

    __shared__ ushort ceT[64][136];   // [d][m], pitch 136 (272B)
    __shared__ float  cl[CHEB_K][64];
    __shared__ float  cts[128];

    // stage ceT (transposed ce slice for scale s = s1+1)
    #pragma unroll
    for (int i = 0; i < 8; i++) {
        int idx = i * 256 + tid;              // 2048 ushort4 units
        int m = idx >> 4, d4 = (idx & 15) << 2;
        const ushort* gp = ceb + (((size_t)b * 128 + m) << 8) + (s1 + 1) * 64 + d4;
        ushort4 v = *(const ushort4*)gp;
        ceT[d4 + 0][m] = v.x; ceT[d4 + 1][m] = v.y;
        ceT[d4 + 2][m] = v.z; ceT[d4 + 3][m] = v.w;
    }
    #pragma unroll
    for (int i = 0; i < 3; i++) {
        int idx = i * 256 + tid;              // 768
        cl[idx >> 6][idx & 63] = clut[s1 * (CHEB_K * 64) + idx];
    }
    if (tid < 128) cts[tid] = ct_t[b * 128 + tid];
    __syncthreads();

    const int nrow = nt * 64 + w * 16 + r;
    const float tsn = ts_t[b * 512 + nrow];

    float xi2v[4][8], Ta[4][8], Tb[4][8];
    #pragma unroll
    for (int t4 = 0; t4 < 4; t4++) {
        int m0 = 8 * g + 32 * t4;
        ushort8 iv = *(const ushort8*)&invW[((((size_t)b * 3 + s1) * 512 + nrow) << 7) + m0];
        #pragma unroll
        for (int j = 0; j < 8; j++) {
            float dfx = cts[m0 + j] - tsn;
            float x = dfx * dfx;
            float xi = 2.f * x - 1.f;
            float w0 = bf2f(iv[j]);
            xi2v[t4][j] = 2.f * xi;
            Ta[t4][j] = w0;            // invW * T_0
            Tb[t4][j] = w0 * xi;       // invW * T_1
        }
    }

    bf16x8 cef[4][4];                  // [dblk][mstep]
    #pragma unroll
    for (int db = 0; db < 4; db++)
        #pragma unroll
        for (int t4 = 0; t4 < 4; t4++)
            cef[db][t4] = *(const bf16x8*)&ceT[db * 16 + r][8 * g + 32 * t4];

    f32x4 acc[4];
    #pragma unroll
    for (int db = 0; db < 4; db++) acc[db] = (f32x4){0.f, 0.f, 0.f, 0.f};

    #pragma unroll
    for (int k = 0; k < CHEB_K; k++) {
        if (k >= 2) {
            #pragma unroll
            for (int t4 = 0; t4 < 4; t4++)
                #pragma unroll
                for (int j = 0; j < 8; j++) {
                    if (k & 1) Tb[t4][j] = fmaf(xi2v[t4][j], Ta[t4][j], -Tb[t4][j]);
                    else       Ta[t4][j] = fmaf(xi2v[t4][j], Tb[t4][j], -Ta[t4][j]);
                }
        }
        bf16x8 af[4];
        #pragma unroll
        for (int t4 = 0; t4 < 4; t4++) {
            ushort8 u;
            #pragma unroll
            for (int j = 0; j < 8; j++)
                u[j] = f2bf((k & 1) ? Tb[t4][j] : Ta[t4][j]);
            af[t4] = __builtin_bit_cast(bf16x8, u);
        }
        #pragma unroll
        for (int db = 0; db < 4; db++) {
            f32x4 gk = (f32x4){0.f, 0.f, 0.f, 0.f};
            #pragma unroll
            for (int t4 = 0; t4 < 4; t4++)
                gk = __builtin_amdgcn_mfma_f32_16x16x32_bf16(af[t4], cef[db][t4], gk, 0, 0, 0);
            float ck = cl[k][db * 16 + r];
            #pragma unroll
            for (int p = 0; p < 4; p++) acc[db][p] = fmaf(ck, gk[p], acc[db][p]);
        }
    }

    #pragma unroll
    for (int db = 0; db < 4; db++)
        #pragma unroll
        for (int p = 0; p < 4; p++) {
            int n_out = nt * 64 + w * 16 + 4 * g + p;
            Xcat[((size_t)b * 512 + n_out) * 512 + (s1 + 1) * 64 + db * 16 + r] =
                f2bf(acc[db][p]);
        }
}

// ---------------------------------------------------------------------------
// Scale-0 output: Xcat[b,n,0:64] = (sum_m ce[b,m,0:64]) / 64  (n-independent)
// ---------------------------------------------------------------------------
__global__ __launch_bounds__(256) void bcast0_kernel(
    const ushort* __restrict__ ceb, ushort* __restrict__ Xcat)
{
    const int b = blockIdx.x;
    const int t = threadIdx.x;
    const int d = t & 63, q = t >> 6;
    float s = 0.f;
    #pragma unroll 8
    for (int i = 0; i < 32; i++) {
        int m = q * 32 + i;
        s += bf2f(ceb[(((size_t)b * 128 + m) << 8) + d]);
    }
    __shared__ float red[4][64];
    __shared__ ushort row[64];
    red[q][d] = s;
    __syncthreads();
    if (t < 64)
        row[t] = f2bf((red[0][t] + red[1][t] + red[2][t] + red[3][t]) * (1.f / 64.f));
    __syncthreads();
    #pragma unroll
    for (int i = 0; i < 16; i++) {
        int idx = i * 256 + t;             // 4096 ushort8 chunks
        int n = idx >> 3, j = idx & 7;
        *(ushort8*)&Xcat[((size_t)b * 512 + n) * 512 + j * 8] =
            *(const ushort8*)&row[j * 8];
    }
}

// ---------------------------------------------------------------------------
// MFMA bf16 flash attention (unchanged from round 3).
// ---------------------------------------------------------------------------
__global__ __launch_bounds__(256) void attn_mfma_kernel(
    const ushort* __restrict__ qkv, ushort* __restrict__ Ob)
{
    const int bid = blockIdx.x;
    const int qt = bid & 7;
    const int h  = (bid >> 3) & 3;
    const int b  = bid >> 5;
    const int t  = threadIdx.x;
    const int w  = t >> 6;
    const int lane = t & 63;
    const int g = lane >> 4;
    const int r = lane & 15;

    __shared__ ushort Ks[64][72];
    __shared__ ushort Vt[64][72];
    __shared__ float  Ps[4][16][65];

    const ushort* base = qkv + (size_t)b * Lsz * 768;
    const int q0 = qt * 64 + w * 16;

    bf16x8 qf[2];
    {
        const ushort* qp = base + (size_t)(q0 + r) * 768 + h * 64 + 8 * g;
        qf[0] = __builtin_bit_cast(bf16x8, *(const ushort8*)qp);
        qf[1] = __builtin_bit_cast(bf16x8, *(const ushort8*)(qp + 32));
    }

    f32x4 Ofr[4];
    #pragma unroll
    for (int dblk = 0; dblk < 4; dblk++) Ofr[dblk] = (f32x4){0.f, 0.f, 0.f, 0.f};
    float m_run[4] = {-1e30f, -1e30f, -1e30f, -1e30f};
    float l_run[4] = {0.f, 0.f, 0.f, 0.f};

    const int srow = t >> 2;
    const int sseg = t & 3;

    for (int c = 0; c < 8; c++) {
        __syncthreads();
        {
            const ushort* kr = base + (size_t)(c * 64 + srow) * 768 + 256 + h * 64 + sseg * 16;
            ushort8 k0 = *(const ushort8*)kr;
            ushort8 k1 = *(const ushort8*)(kr + 8);
            *(ushort8*)&Ks[srow][sseg * 16]     = k0;
            *(ushort8*)&Ks[srow][sseg * 16 + 8] = k1;
            ushort8 v0 = *(const ushort8*)(kr + 256);
            ushort8 v1 = *(const ushort8*)(kr + 264);
            #pragma unroll
            for (int j = 0; j < 8; j++) {
                Vt[sseg * 16 + j][srow]     = v0[j];
                Vt[sseg * 16 + 8 + j][srow] = v1[j];
            }
        }
        __syncthreads();

        f32x4 sfr[4];
        #pragma unroll
        for (int s = 0; s < 4; s++) {
            f32x4 a2 = (f32x4){0.f, 0.f, 0.f, 0.f};
            #pragma unroll
            for (int f = 0; f < 2; f++) {
                bf16x8 kf = *(const bf16x8*)&Ks[s * 16 + r][8 * g + 32 * f];
                a2 = __builtin_amdgcn_mfma_f32_16x16x32_bf16(qf[f], kf, a2, 0, 0, 0);
            }
            #pragma unroll
            for (int p = 0; p < 4; p++) a2[p] *= 0.125f;
            sfr[s] = a2;
        }

        #pragma unroll
        for (int p = 0; p < 4; p++) {
            float rm = fmaxf(fmaxf(sfr[0][p], sfr[1][p]), fmaxf(sfr[2][p], sfr[3][p]));
            #pragma unroll
            for (int o = 1; o <= 8; o <<= 1) rm = fmaxf(rm, __shfl_xor(rm, o));
            float mnew = fmaxf(m_run[p], rm);
            float sc = __expf(m_run[p] - mnew);
            m_run[p] = mnew;
            float rs = 0.f;
            #pragma unroll
            for (int s = 0; s < 4; s++) {
                float pv = __expf(sfr[s][p] - mnew);
                Ps[w][4 * g + p][s * 16 + r] = pv;
                rs += pv;
            }
            #pragma unroll
            for (int o = 1; o <= 8; o <<= 1) rs += __shfl_xor(rs, o);
            l_run[p] = l_run[p] * sc + rs;
            #pragma unroll
            for (int dblk = 0; dblk < 4; dblk++) Ofr[dblk][p] *= sc;
        }

        __asm__ volatile("s_waitcnt lgkmcnt(0)" ::: "memory");

        #pragma unroll
        for (int f = 0; f < 2; f++) {
            const float* pp = &Ps[w][r][8 * g + 32 * f];
            ushort8 ua;
            #pragma unroll
            for (int j = 0; j < 8; j++) ua[j] = f2bf(pp[j]);
            bf16x8 pa = __builtin_bit_cast(bf16x8, ua);
            #pragma unroll
            for (int dblk = 0; dblk < 4; dblk++) {
                bf16x8 vb = *(const bf16x8*)&Vt[dblk * 16 + r][32 * f + 8 * g];
                Ofr[dblk] = __builtin_amdgcn_mfma_f32_16x16x32_bf16(
                    pa, vb, Ofr[dblk], 0, 0, 0);
            }
        }
    }

    #pragma unroll
    for (int dblk = 0; dblk < 4; dblk++) {
        #pragma unroll
        for (int p = 0; p < 4; p++) {
            int row = q0 + 4 * g + p;
            Ob[(size_t)(b * Lsz + row) * HIDs + h * 64 + dblk * 16 + r] =
                f2bf(Ofr[dblk][p] / l_run[p]);
        }
    }
}

// ---------------------------------------------------------------------------
// LayerNorm over last dim (256), dual fp32 + bf16 output
// ---------------------------------------------------------------------------
__global__ __launch_bounds__(256) void ln_kernel(
    const float* __restrict__ Y, const float* __restrict__ g,
    const float* __restrict__ b, float* __restrict__ X, ushort* __restrict__ Xb)
{
    const int row = blockIdx.x;
    const int t = threadIdx.x;
    float v = Y[(size_t)row * HIDs + t];

    __shared__ float red[8];
    float s = v;
    #pragma unroll
    for (int o = 32; o >= 1; o >>= 1) s += __shfl_xor(s, o, 64);
    const int w = t >> 6, lane = t & 63;
    if (lane == 0) red[w] = s;
    __syncthreads();
    float mu = (red[0] + red[1] + red[2] + red[3]) * (1.f / 256.f);
    float dl = v - mu;
    float q = dl * dl;
    #pragma unroll
    for (int o = 32; o >= 1; o >>= 1) q += __shfl_xor(q, o, 64);
    if (lane == 0) red[4 + w] = q;
    __syncthreads();
    float var = (red[4] + red[5] + red[6] + red[7]) * (1.f / 256.f);
    float out = dl * rsqrtf(var + 1e-5f) * g[t] + b[t];
    X[(size_t)row * HIDs + t] = out;
    Xb[(size_t)row * HIDs + t] = f2bf(out);
}

// ---------------------------------------------------------------------------
// Prediction head
// ---------------------------------------------------------------------------
__global__ __launch_bounds__(256) void pred_kernel(
    const float* __restrict__ X, const float* __restrict__ pW,
    const float* __restrict__ pb, float* __restrict__ out)
{
    const int w = threadIdx.x >> 6, lane = threadIdx.x & 63;
    const int row = blockIdx.x * 4 + w;
    const float* xr = X + (size_t)row * HIDs;
    float s = 0.f;
    #pragma unroll
    for (int i = 0; i < 4; i++) s = fmaf(xr[lane + i * 64], pW[lane + i * 64], s);
    #pragma unroll
    for (int o = 32; o >= 1; o >>= 1) s += __shfl_xor(s, o, 64);
    if (lane == 0) out[row] = s + pb[0];
}

// ---------------------------------------------------------------------------
extern "C" void kernel_launch(void* const* d_in, const int* in_sizes, int n_in,
                              void* d_out, int out_size, void* d_ws, size_t ws_size,
                              hipStream_t stream)
{
    (void)in_sizes; (void)n_in; (void)out_size; (void)ws_size;

    const float* ct_t   = (const float*)d_in[0];
    const float* ts_t   = (const float*)d_in[1];
    const float* ct_emb = (const float*)d_in[2];
    const float* ts_emb = (const float*)d_in[3];
    const float* kp     = (const float*)d_in[4];
    const float* ct_W   = (const float*)d_in[5];
    const float* ct_b   = (const float*)d_in[6];
    const float* fW0    = (const float*)d_in[7];
    const float* fb0    = (const float*)d_in[8];
    const float* fW1    = (const float*)d_in[9];
    const float* fb1    = (const float*)d_in[10];
    const float* fW2    = (const float*)d_in[11];
    const float* fb2    = (const float*)d_in[12];
    const float* f_ln_g = (const float*)d_in[13];
    const float* f_ln_b = (const float*)d_in[14];
    const float* Wqkv   = (const float*)d_in[15];
    const float* bqkv   = (const float*)d_in[16];
    const float* Wo     = (const float*)d_in[17];
    const float* bo     = (const float*)d_in[18];
    const float* W1     = (const float*)d_in[19];
    const float* b1     = (const float*)d_in[20];
    const float* W2     = (const float*)d_in[21];
    const float* b2     = (const float*)d_in[22];
    const float* ln1_g  = (const float*)d_in[23];
    const float* ln1_b  = (const float*)d_in[24];
    const float* ln2_g  = (const float*)d_in[25];
    const float* ln2_b  = (const float*)d_in[26];
    const float* pred_W = (const float*)d_in[27];
    const float* pred_b = (const float*)d_in[28];

    // ---- workspace layout (ushort units unless noted) ----
    ushort* wsb = (ushort*)d_ws;
    ushort* invW  = wsb;                    // [0, 12582912)  (bf16)
    ushort* auxbf = wsb;                    //   reuse after tok3: 2,097,152
    ushort* qkvbf = wsb;                    //   reuse: 6,291,456
    ushort* ff1bf = wsb;                    //   reuse: 4,194,304
    ushort* Xcat  = wsb + 12582912;         // 4,194,304  [8192][512]
    ushort* Wcat  = wsb + 16777216;         // 131,072    [256][512]
    ushort* cebin = wsb + 16908288;         // 524,288
    ushort* cebout= wsb + 17432576;         // 524,288
    ushort* wct   = wsb + 17956864;         // 65,536
    ushort* wf2   = wsb + 18022400;         // 65,536
    ushort* wqkv  = wsb + 18087936;         // 393,216
    ushort* wo    = wsb + 18481152;         // 131,072
    ushort* w1    = wsb + 18612224;         // 262,144
    ushort* w2    = wsb + 18874368;         // 262,144 -> ends 19,136,512
    ushort* xbf   = wsb + 19136512;         // 2,097,152
    ushort* obf   = wsb + 21233664;         // 2,097,152 -> ends 23,330,816
    float*  wsf   = (float*)d_ws;
    float*  ybuf  = wsf + 11665408;         // 2,097,152 fl
    float*  xbuf  = wsf + 13762560;         // 2,097,152 fl
    float*  clut  = wsf + 15859712;         // 2,304 fl
    float*  cDp   = wsf + 15862016;         // 36 fl

    const int NRts = Bsz * Lsz;  // 8192
    const int NRct = Bsz * Msz;  // 2048
    auto grid = [](int nr, int out) { return dim3((unsigned)((nr >> 6) * (out >> 7))); };

    // --- convert/pack inputs + weights to bf16 ---
    cvt_all_kernel<<<dim3(1920), 256, 0, stream>>>(
        ts_emb, ct_emb, ct_W, fW0, fW1, fW2, Wqkv, Wo, W1, W2,
        Xcat, Wcat, cebin, wct, wf2, wqkv, wo, w1, w2);

    // --- tokenizer ---
    gemm_mfma_kernel<<<grid(NRct, 256), 256, 0, stream>>>(
        cebin, wct, ct_b, nullptr, nullptr, nullptr, cebout, NRct, 256, 256, 0);
    cheb_kernel<<<dim3(1), 256, 0, stream>>>(kp, clut, cDp);
    denom3_kernel<<<dim3(Bsz * Msz * Lsz / 256), 256, 0, stream>>>(ct_t, ts_t, cDp, invW);
    tok3_kernel<<<dim3(384), 256, 0, stream>>>(ct_t, ts_t, cebout, invW, clut, Xcat);
    bcast0_kernel<<<dim3(Bsz), 256, 0, stream>>>(cebout, Xcat);

    // --- fusion ---
    gemm_mfma_kernel<<<grid(NRts, 256), 256, 0, stream>>>(
        Xcat, Wcat, fb0, fb1, nullptr, nullptr, auxbf, NRts, 512, 256, 1);
    gemm_mfma_kernel<<<grid(NRts, 256), 256, 0, stream>>>(
        auxbf, wf2, fb2, nullptr, ts_emb, ybuf, nullptr, NRts, 256, 256, 0);
    ln_kernel<<<dim3(NRts), 256, 0, stream>>>(ybuf, f_ln_g, f_ln_b, xbuf, xbf);

    // --- transformer layers ---
    for (int l = 0; l < 2; l++) {
        gemm_mfma_kernel<<<grid(NRts, 768), 256, 0, stream>>>(
            xbf, wqkv + (size_t)l * 196608, bqkv + l * 768, nullptr, nullptr,
            nullptr, qkvbf, NRts, 256, 768, 0);
        attn_mfma_kernel<<<dim3(512), 256, 0, stream>>>(qkvbf, obf);
        gemm_mfma_kernel<<<grid(NRts, 256), 256, 0, stream>>>(
            obf, wo + (size_t)l * 65536, bo + l * 256, nullptr, xbuf,
            ybuf, nullptr, NRts, 256, 256, 0);
        ln_kernel<<<dim3(NRts), 256, 0, stream>>>(ybuf, ln1_g + l * 256, ln1_b + l * 256, xbuf, xbf);
        gemm_mfma_kernel<<<grid(NRts, 512), 256, 0, stream>>>(
            xbf, w1 + (size_t)l * 131072, b1 + l * 512, nullptr, nullptr,
            nullptr, ff1bf, NRts, 256, 512, 2);
        gemm_mfma_kernel<<<grid(NRts, 256), 256, 0, stream>>>(
            ff1bf, w2 + (size_t)l * 131072, b2 + l * 256, nullptr, xbuf,
            ybuf, nullptr, NRts, 512, 256, 0);
        ln_kernel<<<dim3(NRts), 256, 0, stream>>>(ybuf, ln2_g + l * 256, ln2_b + l * 256, xbuf, xbf);
    }

    // --- prediction head ---
    pred_kernel<<<dim3(NRts / 4), 256, 0, stream>>>(xbuf, pred_W, pred_b, (float*)d_out);
}

// Round 6
// 219.741 us; speedup vs baseline: 6.3000x; 1.3170x over previous
//
#include <hip/hip_runtime.h>
#include <hip/hip_bf16.h>
#include <cstddef>

// Shapes: B=16, M=128, L=512, HID=256, H=4, DH=64, LAYERS=2
#define Bsz 16
#define Msz 128
#define Lsz 512
#define HIDs 256

typedef __attribute__((ext_vector_type(4))) float f32x4;
typedef __attribute__((ext_vector_type(8))) __bf16 bf16x8;
typedef __attribute__((ext_vector_type(8))) unsigned short ushort8;

#define CHEB_K 12
#define PI_F 3.14159265358979323846f

static __device__ inline unsigned short f2bf(float f) {
    __hip_bfloat16 h = __float2bfloat16(f);
    return *(unsigned short*)&h;
}
static __device__ inline float bf2f(unsigned short u) {
    return __builtin_bit_cast(float, (unsigned)u << 16);
}
static __device__ inline void gload16(const ushort* g, ushort* l) {
    __builtin_amdgcn_global_load_lds(
        (const __attribute__((address_space(1))) void*)g,
        (__attribute__((address_space(3))) void*)l, 16, 0, 0);
}

// ---------------------------------------------------------------------------
// fp32 -> bf16 conversion / repacking (unchanged from round 4).
// ---------------------------------------------------------------------------
__global__ __launch_bounds__(256) void cvt_all_kernel(
    const float* __restrict__ ts_emb, const float* __restrict__ ct_emb,
    const float* __restrict__ ct_W, const float* __restrict__ fW0,
    const float* __restrict__ fW1, const float* __restrict__ fW2,
    const float* __restrict__ Wqkv, const float* __restrict__ Wo,
    const float* __restrict__ W1, const float* __restrict__ W2,
    ushort* __restrict__ Xcat, ushort* __restrict__ Wcat,
    ushort* __restrict__ cebin, ushort* __restrict__ wct,
    ushort* __restrict__ wf2, ushort* __restrict__ wqkv,
    ushort* __restrict__ wo, ushort* __restrict__ w1, ushort* __restrict__ w2)
{
    const unsigned u = blockIdx.x * 256u + threadIdx.x;   // ushort8-unit idx
    const float* src; ushort* dst; unsigned rel;
    if (u < 262144u) {            // ts_emb -> Xcat strided
        rel = u; src = ts_emb;
        dst = Xcat + ((size_t)(rel >> 5) * 512 + 256 + (rel & 31) * 8);
    } else if (u < 327680u) { rel = u - 262144u; src = ct_emb; dst = cebin + (size_t)rel * 8; }
    else if (u < 335872u) { rel = u - 327680u; src = ct_W; dst = wct + (size_t)rel * 8; }
    else if (u < 344064u) { rel = u - 335872u; src = fW0;
        dst = Wcat + ((size_t)(rel >> 5) * 512 + (rel & 31) * 8); }
    else if (u < 352256u) { rel = u - 344064u; src = fW1;
        dst = Wcat + ((size_t)(rel >> 5) * 512 + 256 + (rel & 31) * 8); }
    else if (u < 360448u) { rel = u - 352256u; src = fW2; dst = wf2 + (size_t)rel * 8; }
    else if (u < 409600u) { rel = u - 360448u; src = Wqkv; dst = wqkv + (size_t)rel * 8; }
    else if (u < 425984u) { rel = u - 409600u; src = Wo;  dst = wo + (size_t)rel * 8; }
    else if (u < 458752u) { rel = u - 425984u; src = W1;  dst = w1 + (size_t)rel * 8; }
    else                  { rel = u - 458752u; src = W2;  dst = w2 + (size_t)rel * 8; }
    float4 a = ((const float4*)src)[(size_t)rel * 2];
    float4 b = ((const float4*)src)[(size_t)rel * 2 + 1];
    ushort8 o;
    o[0] = f2bf(a.x); o[1] = f2bf(a.y); o[2] = f2bf(a.z); o[3] = f2bf(a.w);
    o[4] = f2bf(b.x); o[5] = f2bf(b.y); o[6] = f2bf(b.z); o[7] = f2bf(b.w);
    *(ushort8*)dst = o;
}

// ---------------------------------------------------------------------------
// MFMA bf16 GEMM: Y = act(X[NR,K] @ W[OUT,K]^T + bias (+bias2))
// 64x128 tile, 4 waves (2x2), BK=64, global_load_lds w/ XOR-swizzled source.
// act: 0=none,1=ELU,2=GELU.
// ---------------------------------------------------------------------------
__global__ __launch_bounds__(256) void gemm_mfma_kernel(
    const ushort* __restrict__ X, const ushort* __restrict__ W,
    const float* __restrict__ bias, const float* __restrict__ bias2,
    float* __restrict__ Yf, ushort* __restrict__ Yb,
    int NR, int K, int OUT, int act)
{
    __shared__ ushort As[64 * 64];
    __shared__ ushort Bs[128 * 64];

    const int nbx = OUT >> 7;
    const int bx = blockIdx.x % nbx;
    const int by = blockIdx.x / nbx;
    const int r0 = by << 6, o0 = bx << 7;
    const int tid = threadIdx.x;
    const int w = tid >> 6;
    const int lane = tid & 63;
    const int wr = w >> 1, wc = w & 1;
    const int lr = lane & 15, lg = lane >> 4;

    const int grow = lane >> 3;
    const int gchunk = (lane & 7) ^ grow;

    unsigned aoff[2][2], boff[4][2];
    #pragma unroll
    for (int f = 0; f < 2; f++) {
        unsigned cc = (unsigned)((lg + 4 * f) ^ (lr & 7)) * 16u;
        #pragma unroll
        for (int m = 0; m < 2; m++)
            aoff[m][f] = (unsigned)(wr * 32 + m * 16 + lr) * 128u + cc;
        #pragma unroll
        for (int n = 0; n < 4; n++)
            boff[n][f] = (unsigned)(wc * 64 + n * 16 + lr) * 128u + cc;
    }

    f32x4 acc[2][4];
    #pragma unroll
    for (int m = 0; m < 2; m++)
        #pragma unroll
        for (int n = 0; n < 4; n++) acc[m][n] = (f32x4){0.f, 0.f, 0.f, 0.f};

    const int nk = K >> 6;
    for (int ks = 0; ks < nk; ks++) {
        const int k0 = ks << 6;
        if (ks) __syncthreads();
        #pragma unroll
        for (int i = 0; i < 2; i++) {
            int row = w * 16 + i * 8 + grow;
            gload16(X + (size_t)(r0 + row) * K + k0 + gchunk * 8,
                    &As[(w * 16 + i * 8) * 64]);
        }
        #pragma unroll
        for (int i = 0; i < 4; i++) {
            int row = w * 32 + i * 8 + grow;
            gload16(W + (size_t)(o0 + row) * K + k0 + gchunk * 8,
                    &Bs[(w * 32 + i * 8) * 64]);
        }
        __syncthreads();

        #pragma unroll
        for (int f = 0; f < 2; f++) {
            bf16x8 av[2], bv[4];
            #pragma unroll
            for (int m = 0; m < 2; m++)
                av[m] = *(const bf16x8*)((const char*)As + aoff[m][f]);
            #pragma unroll
            for (int n = 0; n < 4; n++)
                bv[n] = *(const bf16x8*)((const char*)Bs + boff[n][f]);
            #pragma unroll
            for (int m = 0; m < 2; m++)
                #pragma unroll
                for (int n = 0; n < 4; n++)
                    acc[m][n] = __builtin_amdgcn_mfma_f32_16x16x32_bf16(
                        av[m], bv[n], acc[m][n], 0, 0, 0);
        }
    }

    const int ocol0 = o0 + wc * 64;
    float bn[4];
    #pragma unroll
    for (int n = 0; n < 4; n++) {
        int o = ocol0 + n * 16 + lr;
        bn[n] = bias[o] + (bias2 ? bias2[o] : 0.f);
    }

    #pragma unroll
    for (int m = 0; m < 2; m++) {
        #pragma unroll
        for (int p = 0; p < 4; p++) {
            int r = r0 + wr * 32 + m * 16 + 4 * lg + p;
            size_t rb = (size_t)r * OUT;
            #pragma unroll
            for (int n = 0; n < 4; n++) {
                int o = ocol0 + n * 16 + lr;
                float v = acc[m][n][p] + bn[n];
                if (act == 1)      v = (v > 0.f) ? v : (__expf(v) - 1.f);
                else if (act == 2) v = 0.5f * v * (1.f + erff(v * 0.70710678118654752f));
                if (Yf) Yf[rb + o] = v;
                if (Yb) Yb[rb + o] = f2bf(v);
            }
        }
    }
}

// ---------------------------------------------------------------------------
// Fused GEMM + residual + LayerNorm (+ optional pred head).
// Y = LN(X[8192,K] @ W[256,K]^T + bias + add) * lng + lnb
// Tile 32 rows x 256 cols (full row per block), 4 waves = 4 column slices.
// Outputs: Xf (fp32, nullable), Xb (bf16, nullable),
//          pout[row] = dot(Y_row, predW) + predb (if predW != null).
// ---------------------------------------------------------------------------
__global__ __launch_bounds__(256) void gemm_ln_kernel(
    const ushort* __restrict__ X, const ushort* __restrict__ W,
    const float* __restrict__ bias, const float* __restrict__ add,
    const float* __restrict__ lng, const float* __restrict__ lnb,
    float* __restrict__ Xf, ushort* __restrict__ Xb,
    const float* __restrict__ predW, const float* __restrict__ predb,
    float* __restrict__ pout, int K)
{
    __shared__ ushort As[32 * 64];
    __shared__ ushort Bs[256 * 64];
    __shared__ float redA[32][4];
    __shared__ float redB[32][4];

    const int r0 = blockIdx.x << 5;
    const int tid = threadIdx.x;
    const int w = tid >> 6;          // wave = 64-col slice
    const int lane = tid & 63;
    const int lr = lane & 15, lg = lane >> 4;
    const int grow = lane >> 3;
    const int gchunk = (lane & 7) ^ grow;

    unsigned aoff[2][2], boff[4][2];
    #pragma unroll
    for (int f = 0; f < 2; f++) {
        unsigned cc = (unsigned)((lg + 4 * f) ^ (lr & 7)) * 16u;
        #pragma unroll
        for (int m = 0; m < 2; m++)
            aoff[m][f] = (unsigned)(m * 16 + lr) * 128u + cc;
        #pragma unroll
        for (int n = 0; n < 4; n++)
            boff[n][f] = (unsigned)(w * 64 + n * 16 + lr) * 128u + cc;
    }

    f32x4 acc[2][4];
    #pragma unroll
    for (int m = 0; m < 2; m++)
        #pragma unroll
        for (int n = 0; n < 4; n++) acc[m][n] = (f32x4){0.f, 0.f, 0.f, 0.f};

    const int nk = K >> 6;
    for (int ks = 0; ks < nk; ks++) {
        const int k0 = ks << 6;
        if (ks) __syncthreads();
        gload16(X + (size_t)(r0 + w * 8 + grow) * K + k0 + gchunk * 8,
                &As[(w * 8) * 64]);
        #pragma unroll
        for (int i = 0; i < 8; i++) {
            gload16(W + (size_t)(w * 64 + i * 8 + grow) * K + k0 + gchunk * 8,
                    &Bs[(w * 64 + i * 8) * 64]);
        }
        __syncthreads();

        #pragma unroll
        for (int f = 0; f < 2; f++) {
            bf16x8 av[2], bv[4];
            #pragma unroll
            for (int m = 0; m < 2; m++)
                av[m] = *(const bf16x8*)((const char*)As + aoff[m][f]);
            #pragma unroll
            for (int n = 0; n < 4; n++)
                bv[n] = *(const bf16x8*)((const char*)Bs + boff[n][f]);
            #pragma unroll
            for (int m = 0; m < 2; m++)
                #pragma unroll
                for (int n = 0; n < 4; n++)
                    acc[m][n] = __builtin_amdgcn_mfma_f32_16x16x32_bf16(
                        av[m], bv[n], acc[m][n], 0, 0, 0);
        }
    }

    // ---- epilogue: v = acc + bias + add ----
    const int col0 = w * 64;
    float bn[4], gv[4], bv2[4], pwv[4];
    #pragma unroll
    for (int n = 0; n < 4; n++) {
        int o = col0 + n * 16 + lr;
        bn[n] = bias[o];
        gv[n] = lng[o];
        bv2[n] = lnb[o];
        pwv[n] = predW ? predW[o] : 0.f;
    }
    #pragma unroll
    for (int m = 0; m < 2; m++)
        #pragma unroll
        for (int p = 0; p < 4; p++) {
            int r = r0 + m * 16 + 4 * lg + p;
            size_t rb = (size_t)r * 256;
            #pragma unroll
            for (int n = 0; n < 4; n++)
                acc[m][n][p] += bn[n] + add[rb + col0 + n * 16 + lr];
        }

    // ---- pass 1: row sums -> mean ----
    #pragma unroll
    for (int m = 0; m < 2; m++)
        #pragma unroll
        for (int p = 0; p < 4; p++) {
            float s = acc[m][0][p] + acc[m][1][p] + acc[m][2][p] + acc[m][3][p];
            #pragma unroll
            for (int o = 1; o <= 8; o <<= 1) s += __shfl_xor(s, o);
            if (lr == 0) redA[m * 16 + 4 * lg + p][w] = s;
        }
    __syncthreads();
    float mu[2][4];
    #pragma unroll
    for (int m = 0; m < 2; m++)
        #pragma unroll
        for (int p = 0; p < 4; p++) {
            int row = m * 16 + 4 * lg + p;
            mu[m][p] = (redA[row][0] + redA[row][1] + redA[row][2] + redA[row][3])
                       * (1.f / 256.f);
        }

    // ---- pass 2: sum of squared deviations -> var ----
    #pragma unroll
    for (int m = 0; m < 2; m++)
        #pragma unroll
        for (int p = 0; p < 4; p++) {
            float q = 0.f;
            #pragma unroll
            for (int n = 0; n < 4; n++) {
                float dl = acc[m][n][p] - mu[m][p];
                q = fmaf(dl, dl, q);
            }
            #pragma unroll
            for (int o = 1; o <= 8; o <<= 1) q += __shfl_xor(q, o);
            if (lr == 0) redB[m * 16 + 4 * lg + p][w] = q;
        }
    __syncthreads();

    // ---- normalize, write, optional pred dot ----
    #pragma unroll
    for (int m = 0; m < 2; m++)
        #pragma unroll
        for (int p = 0; p < 4; p++) {
            int row = m * 16 + 4 * lg + p;
            float var = (redB[row][0] + redB[row][1] + redB[row][2] + redB[row][3])
                        * (1.f / 256.f);
            float rsig = rsqrtf(var + 1e-5f);
            int r = r0 + row;
            size_t rb = (size_t)r * 256;
            float pd = 0.f;
            #pragma unroll
            for (int n = 0; n < 4; n++) {
                int o = col0 + n * 16 + lr;
                float xn = (acc[m][n][p] - mu[m][p]) * rsig * gv[n] + bv2[n];
                if (Xf) Xf[rb + o] = xn;
                if (Xb) Xb[rb + o] = f2bf(xn);
                pd = fmaf(xn, pwv[n], pd);
            }
            if (predW) {
                #pragma unroll
                for (int o = 1; o <= 8; o <<= 1) pd += __shfl_xor(pd, o);
                if (lr == 0) redA[row][w] = pd;   // redA reads all done pre-sync2
            }
        }
    if (predW) {
        __syncthreads();
        if (tid < 32)
            pout[r0 + tid] = redA[tid][0] + redA[tid][1] + redA[tid][2]
                           + redA[tid][3] + predb[0];
    }
}

// ---------------------------------------------------------------------------
// Chebyshev coefficients (unchanged).
// ---------------------------------------------------------------------------
__global__ __launch_bounds__(256) void cheb_kernel(
    const float* __restrict__ kp, float* __restrict__ clut, float* __restrict__ cD)
{
    __shared__ float costab[CHEB_K][32];
    __shared__ float xq[32];
    __shared__ float alph[64];
    const int t = threadIdx.x;
    if (t < 64) {
        float p = kp[t];
        alph[t] = fmaxf(p, 0.f) + log1pf(__expf(-fabsf(p)));
    }
    #pragma unroll
    for (int i = 0; i < 2; i++) {
        int idx = i * 256 + t;
        if (idx < CHEB_K * 32) {
            int k = idx >> 5, q = idx & 31;
            float th = (q + 0.5f) * (PI_F / 32.f);
            costab[k][q] = __cosf((float)k * th);
        }
    }
    if (t < 32) xq[t] = 0.5f * (1.f + __cosf((t + 0.5f) * (PI_F / 32.f)));
    __syncthreads();

    if (t >= 192) return;
    const int d = t & 63, s1 = t >> 6;
    const float u = (float)(s1 + 1) * alph[d];
    float f[32];
    #pragma unroll
    for (int q = 0; q < 32; q++) f[q] = __expf(-u * xq[q]);
    #pragma unroll
    for (int k = 0; k < CHEB_K; k++) {
        float sum = 0.f;
        #pragma unroll
        for (int q = 0; q < 32; q++) sum = fmaf(f[q], costab[k][q], sum);
        float c = sum * ((k == 0 ? 1.f : 2.f) / 32.f);
        clut[s1 * (CHEB_K * 64) + k * 64 + d] = c;
        float sr = c;
        #pragma unroll
        for (int o = 1; o <= 32; o <<= 1) sr += __shfl_xor(sr, o, 64);
        if (d == 0) cD[s1 * CHEB_K + k] = sr;
    }
}

// ---------------------------------------------------------------------------
// Denominators (unchanged).
// ---------------------------------------------------------------------------
__global__ __launch_bounds__(256) void denom3_kernel(
    const float* __restrict__ ct_t, const float* __restrict__ ts_t,
    const float* __restrict__ cD, ushort* __restrict__ invW)
{
    __shared__ float cd[3][CHEB_K];
    const int tid = threadIdx.x;
    if (tid < 3 * CHEB_K) cd[tid / CHEB_K][tid % CHEB_K] = cD[tid];
    __syncthreads();

    const unsigned G = blockIdx.x * 256u + tid;
    const int b = G >> 16;
    const int n = (G >> 7) & 511;
    const int m = G & 127;

    float x = ct_t[b * Msz + m] - ts_t[b * Lsz + n];
    x = x * x;
    const float xi = 2.f * x - 1.f;
    const float xi2 = 2.f * xi;

    float t0 = 1.f, t1 = xi;
    float a1 = cd[0][0] + cd[0][1] * xi;
    float a2 = cd[1][0] + cd[1][1] * xi;
    float a3 = cd[2][0] + cd[2][1] * xi;
    #pragma unroll
    for (int k = 2; k < CHEB_K; k++) {
        float tn = fmaf(xi2, t1, -t0);
        a1 = fmaf(cd[0][k], tn, a1);
        a2 = fmaf(cd[1][k], tn, a2);
        a3 = fmaf(cd[2][k], tn, a3);
        t0 = t1; t1 = tn;
    }
    const size_t base = ((size_t)b * 3 * Lsz + n) * Msz + m;
    invW[base]                         = f2bf(1.f / a1);
    invW[base + (size_t)Lsz * Msz]     = f2bf(1.f / a2);
    invW[base + (size_t)2 * Lsz * Msz] = f2bf(1.f / a3);
}

// ---------------------------------------------------------------------------
// Tokenizer as MFMA (unchanged).
// ---------------------------------------------------------------------------
__global__ __launch_bounds__(256) void tok3_kernel(
    const float* __restrict__ ct_t, const float* __restrict__ ts_t,
    const ushort* __restrict__ ceb, const ushort* __restrict__ invW,
    const float* __restrict__ clut, ushort* __restrict__ Xcat)
{
    const int bid = blockIdx.x;
    const int nt = bid & 7;
    const int s1 = (bid >> 3) % 3;
    const int b  = bid / 24;
    const int tid = threadIdx.x;
    const int w = tid >> 6, lane = tid & 63, g = lane >> 4, r = lane & 15;

    __shared__ ushort ceT[64][136];
    __shared__ float  cl[CHEB_K][64];
    __shared__ float  cts[128];

    #pragma unroll
    for (int i = 0; i < 8; i++) {
        int idx = i * 256 + tid;
        int m = idx >> 4, d4 = (idx & 15) << 2;
        const ushort* gp = ceb + (((size_t)b * 128 + m) << 8) + (s1 + 1) * 64 + d4;
        ushort4 v = *(const ushort4*)gp;
        ceT[d4 + 0][m] = v.x; ceT[d4 + 1][m] = v.y;
        ceT[d4 + 2][m] = v.z; ceT[d4 + 3][m] = v.w;
    }
    #pragma unroll
    for (int i = 0; i < 3; i++) {
        int idx = i * 256 + tid;
        cl[idx >> 6][idx & 63] = clut[s1 * (CHEB_K * 64) + idx];
    }
    if (tid < 128) cts[tid] = ct_t[b * 128 + tid];
    __syncthreads();

    const int nrow = nt * 64 + w * 16 + r;
    const float tsn = ts_t[b * 512 + nrow];

    float xi2v[4][8], Ta[4][8], Tb[4][8];
    #pragma unroll
    for (int t4 = 0; t4 < 4; t4++) {
        int m0 = 8 * g + 32 * t4;
        ushort8 iv = *(const ushort8*)&invW[((((size_t)b * 3 + s1) * 512 + nrow) << 7) + m0];
        #pragma unroll
        for (int j = 0; j < 8; j++) {
            float dfx = cts[m0 + j] - tsn;
            float x = dfx * dfx;
            float xi = 2.f * x - 1.f;
            float w0 = bf2f(iv[j]);
            xi2v[t4][j] = 2.f * xi;
            Ta[t4][j] = w0;
            Tb[t4][j] = w0 * xi;
        }
    }

    bf16x8 cef[4][4];
    #pragma unroll
    for (int db = 0; db < 4; db++)
        #pragma unroll
        for (int t4 = 0; t4 < 4; t4++)
            cef[db][t4] = *(const bf16x8*)&ceT[db * 16 + r][8 * g + 32 * t4];

    f32x4 acc[4];
    #pragma unroll
    for (int db = 0; db < 4; db++) acc[db] = (f32x4){0.f, 0.f, 0.f, 0.f};

    #pragma unroll
    for (int k = 0; k < CHEB_K; k++) {
        if (k >= 2) {
            #pragma unroll
            for (int t4 = 0; t4 < 4; t4++)
                #pragma unroll
                for (int j = 0; j < 8; j++) {
                    if (k & 1) Tb[t4][j] = fmaf(xi2v[t4][j], Ta[t4][j], -Tb[t4][j]);
                    else       Ta[t4][j] = fmaf(xi2v[t4][j], Tb[t4][j], -Ta[t4][j]);
                }
        }
        bf16x8 af[4];
        #pragma unroll
        for (int t4 = 0; t4 < 4; t4++) {
            ushort8 u;
            #pragma unroll
            for (int j = 0; j < 8; j++)
                u[j] = f2bf((k & 1) ? Tb[t4][j] : Ta[t4][j]);
            af[t4] = __builtin_bit_cast(bf16x8, u);
        }
        #pragma unroll
        for (int db = 0; db < 4; db++) {
            f32x4 gk = (f32x4){0.f, 0.f, 0.f, 0.f};
            #pragma unroll
            for (int t4 = 0; t4 < 4; t4++)
                gk = __builtin_amdgcn_mfma_f32_16x16x32_bf16(af[t4], cef[db][t4], gk, 0, 0, 0);
            float ck = cl[k][db * 16 + r];
            #pragma unroll
            for (int p = 0; p < 4; p++) acc[db][p] = fmaf(ck, gk[p], acc[db][p]);
        }
    }

    #pragma unroll
    for (int db = 0; db < 4; db++)
        #pragma unroll
        for (int p = 0; p < 4; p++) {
            int n_out = nt * 64 + w * 16 + 4 * g + p;
            Xcat[((size_t)b * 512 + n_out) * 512 + (s1 + 1) * 64 + db * 16 + r] =
                f2bf(acc[db][p]);
        }
}

// ---------------------------------------------------------------------------
// Scale-0 broadcast (unchanged).
// ---------------------------------------------------------------------------
__global__ __launch_bounds__(256) void bcast0_kernel(
    const ushort* __restrict__ ceb, ushort* __restrict__ Xcat)
{
    const int b = blockIdx.x;
    const int t = threadIdx.x;
    const int d = t & 63, q = t >> 6;
    float s = 0.f;
    #pragma unroll 8
    for (int i = 0; i < 32; i++) {
        int m = q * 32 + i;
        s += bf2f(ceb[(((size_t)b * 128 + m) << 8) + d]);
    }
    __shared__ float red[4][64];
    __shared__ ushort row[64];
    red[q][d] = s;
    __syncthreads();
    if (t < 64)
        row[t] = f2bf((red[0][t] + red[1][t] + red[2][t] + red[3][t]) * (1.f / 64.f));
    __syncthreads();
    #pragma unroll
    for (int i = 0; i < 16; i++) {
        int idx = i * 256 + t;
        int n = idx >> 3, j = idx & 7;
        *(ushort8*)&Xcat[((size_t)b * 512 + n) * 512 + j * 8] =
            *(const ushort8*)&row[j * 8];
    }
}

// ---------------------------------------------------------------------------
// MFMA bf16 flash attention (unchanged).
// ---------------------------------------------------------------------------
__global__ __launch_bounds__(256) void attn_mfma_kernel(
    const ushort* __restrict__ qkv, ushort* __restrict__ Ob)
{
    const int bid = blockIdx.x;
    const int qt = bid & 7;
    const int h  = (bid >> 3) & 3;
    const int b  = bid >> 5;
    const int t  = threadIdx.x;
    const int w  = t >> 6;
    const int lane = t & 63;
    const int g = lane >> 4;
    const int r = lane & 15;

    __shared__ ushort Ks[64][72];
    __shared__ ushort Vt[64][72];
    __shared__ float  Ps[4][16][65];

    const ushort* base = qkv + (size_t)b * Lsz * 768;
    const int q0 = qt * 64 + w * 16;

    bf16x8 qf[2];
    {
        const ushort* qp = base + (size_t)(q0 + r) * 768 + h * 64 + 8 * g;
        qf[0] = __builtin_bit_cast(bf16x8, *(const ushort8*)qp);
        qf[1] = __builtin_bit_cast(bf16x8, *(const ushort8*)(qp + 32));
    }

    f32x4 Ofr[4];
    #pragma unroll
    for (int dblk = 0; dblk < 4; dblk++) Ofr[dblk] = (f32x4){0.f, 0.f, 0.f, 0.f};
    float m_run[4] = {-1e30f, -1e30f, -1e30f, -1e30f};
    float l_run[4] = {0.f, 0.f, 0.f, 0.f};

    const int srow = t >> 2;
    const int sseg = t & 3;

    for (int c = 0; c < 8; c++) {
        __syncthreads();
        {
            const ushort* kr = base + (size_t)(c * 64 + srow) * 768 + 256 + h * 64 + sseg * 16;
            ushort8 k0 = *(const ushort8*)kr;
            ushort8 k1 = *(const ushort8*)(kr + 8);
            *(ushort8*)&Ks[srow][sseg * 16]     = k0;
            *(ushort8*)&Ks[srow][sseg * 16 + 8] = k1;
            ushort8 v0 = *(const ushort8*)(kr + 256);
            ushort8 v1 = *(const ushort8*)(kr + 264);
            #pragma unroll
            for (int j = 0; j < 8; j++) {
                Vt[sseg * 16 + j][srow]     = v0[j];
                Vt[sseg * 16 + 8 + j][srow] = v1[j];
            }
        }
        __syncthreads();

        f32x4 sfr[4];
        #pragma unroll
        for (int s = 0; s < 4; s++) {
            f32x4 a2 = (f32x4){0.f, 0.f, 0.f, 0.f};
            #pragma unroll
            for (int f = 0; f < 2; f++) {
                bf16x8 kf = *(const bf16x8*)&Ks[s * 16 + r][8 * g + 32 * f];
                a2 = __builtin_amdgcn_mfma_f32_16x16x32_bf16(qf[f], kf, a2, 0, 0, 0);
            }
            #pragma unroll
            for (int p = 0; p < 4; p++) a2[p] *= 0.125f;
            sfr[s] = a2;
        }

        #pragma unroll
        for (int p = 0; p < 4; p++) {
            float rm = fmaxf(fmaxf(sfr[0][p], sfr[1][p]), fmaxf(sfr[2][p], sfr[3][p]));
            #pragma unroll
            for (int o = 1; o <= 8; o <<= 1) rm = fmaxf(rm, __shfl_xor(rm, o));
            float mnew = fmaxf(m_run[p], rm);
            float sc = __expf(m_run[p] - mnew);
            m_run[p] = mnew;
            float rs = 0.f;
            #pragma unroll
            for (int s = 0; s < 4; s++) {
                float pv = __expf(sfr[s][p] - mnew);
                Ps[w][4 * g + p][s * 16 + r] = pv;
                rs += pv;
            }
            #pragma unroll
            for (int o = 1; o <= 8; o <<= 1) rs += __shfl_xor(rs, o);
            l_run[p] = l_run[p] * sc + rs;
            #pragma unroll
            for (int dblk = 0; dblk < 4; dblk++) Ofr[dblk][p] *= sc;
        }

        __asm__ volatile("s_waitcnt lgkmcnt(0)" ::: "memory");

        #pragma unroll
        for (int f = 0; f < 2; f++) {
            const float* pp = &Ps[w][r][8 * g + 32 * f];
            ushort8 ua;
            #pragma unroll
            for (int j = 0; j < 8; j++) ua[j] = f2bf(pp[j]);
            bf16x8 pa = __builtin_bit_cast(bf16x8, ua);
            #pragma unroll
            for (int dblk = 0; dblk < 4; dblk++) {
                bf16x8 vb = *(const bf16x8*)&Vt[dblk * 16 + r][32 * f + 8 * g];
                Ofr[dblk] = __builtin_amdgcn_mfma_f32_16x16x32_bf16(
                    pa, vb, Ofr[dblk], 0, 0, 0);
            }
        }
    }

    #pragma unroll
    for (int dblk = 0; dblk < 4; dblk++) {
        #pragma unroll
        for (int p = 0; p < 4; p++) {
            int row = q0 + 4 * g + p;
            Ob[(size_t)(b * Lsz + row) * HIDs + h * 64 + dblk * 16 + r] =
                f2bf(Ofr[dblk][p] / l_run[p]);
        }
    }
}

// ---------------------------------------------------------------------------
extern "C" void kernel_launch(void* const* d_in, const int* in_sizes, int n_in,
                              void* d_out, int out_size, void* d_ws, size_t ws_size,
                              hipStream_t stream)
{
    (void)in_sizes; (void)n_in; (void)out_size; (void)ws_size;

    const float* ct_t   = (const float*)d_in[0];
    const float* ts_t   = (const float*)d_in[1];
    const float* ct_emb = (const float*)d_in[2];
    const float* ts_emb = (const float*)d_in[3];
    const float* kp     = (const float*)d_in[4];
    const float* ct_W   = (const float*)d_in[5];
    const float* ct_b   = (const float*)d_in[6];
    const float* fW0    = (const float*)d_in[7];
    const float* fb0    = (const float*)d_in[8];
    const float* fW1    = (const float*)d_in[9];
    const float* fb1    = (const float*)d_in[10];
    const float* fW2    = (const float*)d_in[11];
    const float* fb2    = (const float*)d_in[12];
    const float* f_ln_g = (const float*)d_in[13];
    const float* f_ln_b = (const float*)d_in[14];
    const float* Wqkv   = (const float*)d_in[15];
    const float* bqkv   = (const float*)d_in[16];
    const float* Wo     = (const float*)d_in[17];
    const float* bo     = (const float*)d_in[18];
    const float* W1     = (const float*)d_in[19];
    const float* b1     = (const float*)d_in[20];
    const float* W2     = (const float*)d_in[21];
    const float* b2     = (const float*)d_in[22];
    const float* ln1_g  = (const float*)d_in[23];
    const float* ln1_b  = (const float*)d_in[24];
    const float* ln2_g  = (const float*)d_in[25];
    const float* ln2_b  = (const float*)d_in[26];
    const float* pred_W = (const float*)d_in[27];
    const float* pred_b = (const float*)d_in[28];

    // ---- workspace layout (ushort units unless noted) ----
    ushort* wsb = (ushort*)d_ws;
    ushort* invW  = wsb;                    // [0, 12582912)
    ushort* auxbf = wsb;                    //   reuse after tok3
    ushort* qkvbf = wsb;                    //   reuse
    ushort* ff1bf = wsb;                    //   reuse
    ushort* Xcat  = wsb + 12582912;         // 4,194,304  [8192][512]
    ushort* Wcat  = wsb + 16777216;         // 131,072
    ushort* cebin = wsb + 16908288;         // 524,288
    ushort* cebout= wsb + 17432576;         // 524,288
    ushort* wct   = wsb + 17956864;         // 65,536
    ushort* wf2   = wsb + 18022400;         // 65,536
    ushort* wqkv  = wsb + 18087936;         // 393,216
    ushort* wo    = wsb + 18481152;         // 131,072
    ushort* w1    = wsb + 18612224;         // 262,144
    ushort* w2    = wsb + 18874368;         // 262,144 -> ends 19,136,512
    ushort* xbf   = wsb + 19136512;         // 2,097,152
    ushort* obf   = wsb + 21233664;         // 2,097,152 -> ends 23,330,816
    float*  wsf   = (float*)d_ws;
    float*  xbuf  = wsf + 11665408;         // 2,097,152 fl
    float*  clut  = wsf + 13762560;         // 2,304 fl
    float*  cDp   = wsf + 13764864;         // 36 fl

    const int NRts = Bsz * Lsz;  // 8192
    const int NRct = Bsz * Msz;  // 2048
    auto grid = [](int nr, int out) { return dim3((unsigned)((nr >> 6) * (out >> 7))); };

    // --- convert/pack inputs + weights to bf16 ---
    cvt_all_kernel<<<dim3(1920), 256, 0, stream>>>(
        ts_emb, ct_emb, ct_W, fW0, fW1, fW2, Wqkv, Wo, W1, W2,
        Xcat, Wcat, cebin, wct, wf2, wqkv, wo, w1, w2);

    // --- tokenizer ---
    gemm_mfma_kernel<<<grid(NRct, 256), 256, 0, stream>>>(
        cebin, wct, ct_b, nullptr, nullptr, cebout, NRct, 256, 256, 0);
    cheb_kernel<<<dim3(1), 256, 0, stream>>>(kp, clut, cDp);
    denom3_kernel<<<dim3(Bsz * Msz * Lsz / 256), 256, 0, stream>>>(ct_t, ts_t, cDp, invW);
    tok3_kernel<<<dim3(384), 256, 0, stream>>>(ct_t, ts_t, cebout, invW, clut, Xcat);
    bcast0_kernel<<<dim3(Bsz), 256, 0, stream>>>(cebout, Xcat);

    // --- fusion ---
    gemm_mfma_kernel<<<grid(NRts, 256), 256, 0, stream>>>(
        Xcat, Wcat, fb0, fb1, nullptr, auxbf, NRts, 512, 256, 1);
    gemm_ln_kernel<<<dim3(NRts / 32), 256, 0, stream>>>(
        auxbf, wf2, fb2, ts_emb, f_ln_g, f_ln_b, xbuf, xbf,
        nullptr, nullptr, nullptr, 256);

    // --- transformer layers ---
    for (int l = 0; l < 2; l++) {
        gemm_mfma_kernel<<<grid(NRts, 768), 256, 0, stream>>>(
            xbf, wqkv + (size_t)l * 196608, bqkv + l * 768, nullptr,
            nullptr, qkvbf, NRts, 256, 768, 0);
        attn_mfma_kernel<<<dim3(512), 256, 0, stream>>>(qkvbf, obf);
        gemm_ln_kernel<<<dim3(NRts / 32), 256, 0, stream>>>(
            obf, wo + (size_t)l * 65536, bo + l * 256, xbuf,
            ln1_g + l * 256, ln1_b + l * 256, xbuf, xbf,
            nullptr, nullptr, nullptr, 256);
        gemm_mfma_kernel<<<grid(NRts, 512), 256, 0, stream>>>(
            xbf, w1 + (size_t)l * 131072, b1 + l * 512, nullptr,
            nullptr, ff1bf, NRts, 256, 512, 2);
        if (l == 0) {
            gemm_ln_kernel<<<dim3(NRts / 32), 256, 0, stream>>>(
                ff1bf, w2 + (size_t)l * 131072, b2 + l * 256, xbuf,
                ln2_g + l * 256, ln2_b + l * 256, xbuf, xbf,
                nullptr, nullptr, nullptr, 512);
        } else {
            gemm_ln_kernel<<<dim3(NRts / 32), 256, 0, stream>>>(
                ff1bf, w2 + (size_t)l * 131072, b2 + l * 256, xbuf,
                ln2_g + l * 256, ln2_b + l * 256, nullptr, nullptr,
                pred_W, pred_b, (float*)d_out, 512);
        }
    }
}

// Round 7
// 218.426 us; speedup vs baseline: 6.3379x; 1.0060x over previous
//
#include <hip/hip_runtime.h>
#include <hip/hip_bf16.h>
#include <cstddef>

// Shapes: B=16, M=128, L=512, HID=256, H=4, DH=64, LAYERS=2
#define Bsz 16
#define Msz 128
#define Lsz 512
#define HIDs 256

typedef __attribute__((ext_vector_type(4))) float f32x4;
typedef __attribute__((ext_vector_type(8))) __bf16 bf16x8;
typedef __attribute__((ext_vector_type(8))) unsigned short ushort8;

#define CHEB_K 12
#define PI_F 3.14159265358979323846f

static __device__ inline unsigned short f2bf(float f) {
    __hip_bfloat16 h = __float2bfloat16(f);
    return *(unsigned short*)&h;
}
static __device__ inline float bf2f(unsigned short u) {
    return __builtin_bit_cast(float, (unsigned)u << 16);
}
static __device__ inline void gload16(const ushort* g, ushort* l) {
    __builtin_amdgcn_global_load_lds(
        (const __attribute__((address_space(1))) void*)g,
        (__attribute__((address_space(3))) void*)l, 16, 0, 0);
}

// ---------------------------------------------------------------------------
// fp32 -> bf16 conversion / repacking (unchanged).
// ---------------------------------------------------------------------------
__global__ __launch_bounds__(256) void cvt_all_kernel(
    const float* __restrict__ ts_emb, const float* __restrict__ ct_emb,
    const float* __restrict__ ct_W, const float* __restrict__ fW0,
    const float* __restrict__ fW1, const float* __restrict__ fW2,
    const float* __restrict__ Wqkv, const float* __restrict__ Wo,
    const float* __restrict__ W1, const float* __restrict__ W2,
    ushort* __restrict__ Xcat, ushort* __restrict__ Wcat,
    ushort* __restrict__ cebin, ushort* __restrict__ wct,
    ushort* __restrict__ wf2, ushort* __restrict__ wqkv,
    ushort* __restrict__ wo, ushort* __restrict__ w1, ushort* __restrict__ w2)
{
    const unsigned u = blockIdx.x * 256u + threadIdx.x;   // ushort8-unit idx
    const float* src; ushort* dst; unsigned rel;
    if (u < 262144u) {            // ts_emb -> Xcat strided
        rel = u; src = ts_emb;
        dst = Xcat + ((size_t)(rel >> 5) * 512 + 256 + (rel & 31) * 8);
    } else if (u < 327680u) { rel = u - 262144u; src = ct_emb; dst = cebin + (size_t)rel * 8; }
    else if (u < 335872u) { rel = u - 327680u; src = ct_W; dst = wct + (size_t)rel * 8; }
    else if (u < 344064u) { rel = u - 335872u; src = fW0;
        dst = Wcat + ((size_t)(rel >> 5) * 512 + (rel & 31) * 8); }
    else if (u < 352256u) { rel = u - 344064u; src = fW1;
        dst = Wcat + ((size_t)(rel >> 5) * 512 + 256 + (rel & 31) * 8); }
    else if (u < 360448u) { rel = u - 352256u; src = fW2; dst = wf2 + (size_t)rel * 8; }
    else if (u < 409600u) { rel = u - 360448u; src = Wqkv; dst = wqkv + (size_t)rel * 8; }
    else if (u < 425984u) { rel = u - 409600u; src = Wo;  dst = wo + (size_t)rel * 8; }
    else if (u < 458752u) { rel = u - 425984u; src = W1;  dst = w1 + (size_t)rel * 8; }
    else                  { rel = u - 458752u; src = W2;  dst = w2 + (size_t)rel * 8; }
    float4 a = ((const float4*)src)[(size_t)rel * 2];
    float4 b = ((const float4*)src)[(size_t)rel * 2 + 1];
    ushort8 o;
    o[0] = f2bf(a.x); o[1] = f2bf(a.y); o[2] = f2bf(a.z); o[3] = f2bf(a.w);
    o[4] = f2bf(b.x); o[5] = f2bf(b.y); o[6] = f2bf(b.z); o[7] = f2bf(b.w);
    *(ushort8*)dst = o;
}

// ---------------------------------------------------------------------------
// MFMA bf16 GEMM with double-buffered prefetch (T3 minimum 2-phase):
// Y = act(X[NR,K] @ W[OUT,K]^T + bias (+bias2)); 64x128 tile, 4 waves.
// stage(next) is issued BEFORE compute(cur); one barrier per K-step.
// ---------------------------------------------------------------------------
__global__ __launch_bounds__(256) void gemm_mfma_kernel(
    const ushort* __restrict__ X, const ushort* __restrict__ W,
    const float* __restrict__ bias, const float* __restrict__ bias2,
    float* __restrict__ Yf, ushort* __restrict__ Yb,
    int NR, int K, int OUT, int act)
{
    __shared__ ushort As[2][64 * 64];
    __shared__ ushort Bs[2][128 * 64];

    const int nbx = OUT >> 7;
    const int bx = blockIdx.x % nbx;
    const int by = blockIdx.x / nbx;
    const int r0 = by << 6, o0 = bx << 7;
    const int tid = threadIdx.x;
    const int w = tid >> 6;
    const int lane = tid & 63;
    const int wr = w >> 1, wc = w & 1;
    const int lr = lane & 15, lg = lane >> 4;

    const int grow = lane >> 3;
    const int gchunk = (lane & 7) ^ grow;

    unsigned aoff[2][2], boff[4][2];
    #pragma unroll
    for (int f = 0; f < 2; f++) {
        unsigned cc = (unsigned)((lg + 4 * f) ^ (lr & 7)) * 16u;
        #pragma unroll
        for (int m = 0; m < 2; m++)
            aoff[m][f] = (unsigned)(wr * 32 + m * 16 + lr) * 128u + cc;
        #pragma unroll
        for (int n = 0; n < 4; n++)
            boff[n][f] = (unsigned)(wc * 64 + n * 16 + lr) * 128u + cc;
    }

    f32x4 acc[2][4];
    #pragma unroll
    for (int m = 0; m < 2; m++)
        #pragma unroll
        for (int n = 0; n < 4; n++) acc[m][n] = (f32x4){0.f, 0.f, 0.f, 0.f};

    const int nk = K >> 6;

    auto stage = [&](int buf, int ks) {
        const int k0 = ks << 6;
        #pragma unroll
        for (int i = 0; i < 2; i++) {
            int row = w * 16 + i * 8 + grow;
            gload16(X + (size_t)(r0 + row) * K + k0 + gchunk * 8,
                    &As[buf][(w * 16 + i * 8) * 64]);
        }
        #pragma unroll
        for (int i = 0; i < 4; i++) {
            int row = w * 32 + i * 8 + grow;
            gload16(W + (size_t)(o0 + row) * K + k0 + gchunk * 8,
                    &Bs[buf][(w * 32 + i * 8) * 64]);
        }
    };

    stage(0, 0);
    __syncthreads();                 // drains vmcnt: buf0 ready
    int cur = 0;
    for (int ks = 0; ks < nk; ks++) {
        if (ks + 1 < nk) stage(cur ^ 1, ks + 1);   // prefetch, no wait
        const char* Ab = (const char*)As[cur];
        const char* Bb = (const char*)Bs[cur];
        #pragma unroll
        for (int f = 0; f < 2; f++) {
            bf16x8 av[2], bv[4];
            #pragma unroll
            for (int m = 0; m < 2; m++)
                av[m] = *(const bf16x8*)(Ab + aoff[m][f]);
            #pragma unroll
            for (int n = 0; n < 4; n++)
                bv[n] = *(const bf16x8*)(Bb + boff[n][f]);
            #pragma unroll
            for (int m = 0; m < 2; m++)
                #pragma unroll
                for (int n = 0; n < 4; n++)
                    acc[m][n] = __builtin_amdgcn_mfma_f32_16x16x32_bf16(
                        av[m], bv[n], acc[m][n], 0, 0, 0);
        }
        __syncthreads();             // waits vmcnt(0): next buf ready, cur consumed
        cur ^= 1;
    }

    const int ocol0 = o0 + wc * 64;
    float bn[4];
    #pragma unroll
    for (int n = 0; n < 4; n++) {
        int o = ocol0 + n * 16 + lr;
        bn[n] = bias[o] + (bias2 ? bias2[o] : 0.f);
    }

    #pragma unroll
    for (int m = 0; m < 2; m++) {
        #pragma unroll
        for (int p = 0; p < 4; p++) {
            int r = r0 + wr * 32 + m * 16 + 4 * lg + p;
            size_t rb = (size_t)r * OUT;
            #pragma unroll
            for (int n = 0; n < 4; n++) {
                int o = ocol0 + n * 16 + lr;
                float v = acc[m][n][p] + bn[n];
                if (act == 1)      v = (v > 0.f) ? v : (__expf(v) - 1.f);
                else if (act == 2) v = 0.5f * v * (1.f + erff(v * 0.70710678118654752f));
                if (Yf) Yf[rb + o] = v;
                if (Yb) Yb[rb + o] = f2bf(v);
            }
        }
    }
}

// ---------------------------------------------------------------------------
// Fused GEMM + residual + LayerNorm (+ optional pred head), double-buffered.
// Tile 32 rows x 256 cols (full row per block), 4 waves = 4 column slices.
// ---------------------------------------------------------------------------
__global__ __launch_bounds__(256) void gemm_ln_kernel(
    const ushort* __restrict__ X, const ushort* __restrict__ W,
    const float* __restrict__ bias, const float* __restrict__ add,
    const float* __restrict__ lng, const float* __restrict__ lnb,
    float* __restrict__ Xf, ushort* __restrict__ Xb,
    const float* __restrict__ predW, const float* __restrict__ predb,
    float* __restrict__ pout, int K)
{
    __shared__ ushort As[2][32 * 64];
    __shared__ ushort Bs[2][256 * 64];
    __shared__ float redA[32][4];
    __shared__ float redB[32][4];

    const int r0 = blockIdx.x << 5;
    const int tid = threadIdx.x;
    const int w = tid >> 6;          // wave = 64-col slice
    const int lane = tid & 63;
    const int lr = lane & 15, lg = lane >> 4;
    const int grow = lane >> 3;
    const int gchunk = (lane & 7) ^ grow;

    unsigned aoff[2][2], boff[4][2];
    #pragma unroll
    for (int f = 0; f < 2; f++) {
        unsigned cc = (unsigned)((lg + 4 * f) ^ (lr & 7)) * 16u;
        #pragma unroll
        for (int m = 0; m < 2; m++)
            aoff[m][f] = (unsigned)(m * 16 + lr) * 128u + cc;
        #pragma unroll
        for (int n = 0; n < 4; n++)
            boff[n][f] = (unsigned)(w * 64 + n * 16 + lr) * 128u + cc;
    }

    f32x4 acc[2][4];
    #pragma unroll
    for (int m = 0; m < 2; m++)
        #pragma unroll
        for (int n = 0; n < 4; n++) acc[m][n] = (f32x4){0.f, 0.f, 0.f, 0.f};

    const int nk = K >> 6;

    auto stage = [&](int buf, int ks) {
        const int k0 = ks << 6;
        gload16(X + (size_t)(r0 + w * 8 + grow) * K + k0 + gchunk * 8,
                &As[buf][(w * 8) * 64]);
        #pragma unroll
        for (int i = 0; i < 8; i++) {
            gload16(W + (size_t)(w * 64 + i * 8 + grow) * K + k0 + gchunk * 8,
                    &Bs[buf][(w * 64 + i * 8) * 64]);
        }
    };

    stage(0, 0);
    __syncthreads();
    int cur = 0;
    for (int ks = 0; ks < nk; ks++) {
        if (ks + 1 < nk) stage(cur ^ 1, ks + 1);
        const char* Ab = (const char*)As[cur];
        const char* Bb = (const char*)Bs[cur];
        #pragma unroll
        for (int f = 0; f < 2; f++) {
            bf16x8 av[2], bv[4];
            #pragma unroll
            for (int m = 0; m < 2; m++)
                av[m] = *(const bf16x8*)(Ab + aoff[m][f]);
            #pragma unroll
            for (int n = 0; n < 4; n++)
                bv[n] = *(const bf16x8*)(Bb + boff[n][f]);
            #pragma unroll
            for (int m = 0; m < 2; m++)
                #pragma unroll
                for (int n = 0; n < 4; n++)
                    acc[m][n] = __builtin_amdgcn_mfma_f32_16x16x32_bf16(
                        av[m], bv[n], acc[m][n], 0, 0, 0);
        }
        __syncthreads();
        cur ^= 1;
    }

    // ---- epilogue: v = acc + bias + add ----
    const int col0 = w * 64;
    float bn[4], gv[4], bv2[4], pwv[4];
    #pragma unroll
    for (int n = 0; n < 4; n++) {
        int o = col0 + n * 16 + lr;
        bn[n] = bias[o];
        gv[n] = lng[o];
        bv2[n] = lnb[o];
        pwv[n] = predW ? predW[o] : 0.f;
    }
    #pragma unroll
    for (int m = 0; m < 2; m++)
        #pragma unroll
        for (int p = 0; p < 4; p++) {
            int r = r0 + m * 16 + 4 * lg + p;
            size_t rb = (size_t)r * 256;
            #pragma unroll
            for (int n = 0; n < 4; n++)
                acc[m][n][p] += bn[n] + add[rb + col0 + n * 16 + lr];
        }

    // ---- pass 1: row sums -> mean ----
    #pragma unroll
    for (int m = 0; m < 2; m++)
        #pragma unroll
        for (int p = 0; p < 4; p++) {
            float s = acc[m][0][p] + acc[m][1][p] + acc[m][2][p] + acc[m][3][p];
            #pragma unroll
            for (int o = 1; o <= 8; o <<= 1) s += __shfl_xor(s, o);
            if (lr == 0) redA[m * 16 + 4 * lg + p][w] = s;
        }
    __syncthreads();
    float mu[2][4];
    #pragma unroll
    for (int m = 0; m < 2; m++)
        #pragma unroll
        for (int p = 0; p < 4; p++) {
            int row = m * 16 + 4 * lg + p;
            mu[m][p] = (redA[row][0] + redA[row][1] + redA[row][2] + redA[row][3])
                       * (1.f / 256.f);
        }

    // ---- pass 2: sum of squared deviations -> var ----
    #pragma unroll
    for (int m = 0; m < 2; m++)
        #pragma unroll
        for (int p = 0; p < 4; p++) {
            float q = 0.f;
            #pragma unroll
            for (int n = 0; n < 4; n++) {
                float dl = acc[m][n][p] - mu[m][p];
                q = fmaf(dl, dl, q);
            }
            #pragma unroll
            for (int o = 1; o <= 8; o <<= 1) q += __shfl_xor(q, o);
            if (lr == 0) redB[m * 16 + 4 * lg + p][w] = q;
        }
    __syncthreads();

    // ---- normalize, write, optional pred dot ----
    #pragma unroll
    for (int m = 0; m < 2; m++)
        #pragma unroll
        for (int p = 0; p < 4; p++) {
            int row = m * 16 + 4 * lg + p;
            float var = (redB[row][0] + redB[row][1] + redB[row][2] + redB[row][3])
                        * (1.f / 256.f);
            float rsig = rsqrtf(var + 1e-5f);
            int r = r0 + row;
            size_t rb = (size_t)r * 256;
            float pd = 0.f;
            #pragma unroll
            for (int n = 0; n < 4; n++) {
                int o = col0 + n * 16 + lr;
                float xn = (acc[m][n][p] - mu[m][p]) * rsig * gv[n] + bv2[n];
                if (Xf) Xf[rb + o] = xn;
                if (Xb) Xb[rb + o] = f2bf(xn);
                pd = fmaf(xn, pwv[n], pd);
            }
            if (predW) {
                #pragma unroll
                for (int o = 1; o <= 8; o <<= 1) pd += __shfl_xor(pd, o);
                if (lr == 0) redA[row][w] = pd;
            }
        }
    if (predW) {
        __syncthreads();
        if (tid < 32)
            pout[r0 + tid] = redA[tid][0] + redA[tid][1] + redA[tid][2]
                           + redA[tid][3] + predb[0];
    }
}

// ---------------------------------------------------------------------------
// Chebyshev coefficients (unchanged).
// ---------------------------------------------------------------------------
__global__ __launch_bounds__(256) void cheb_kernel(
    const float* __restrict__ kp, float* __restrict__ clut, float* __restrict__ cD)
{
    __shared__ float costab[CHEB_K][32];
    __shared__ float xq[32];
    __shared__ float alph[64];
    const int t = threadIdx.x;
    if (t < 64) {
        float p = kp[t];
        alph[t] = fmaxf(p, 0.f) + log1pf(__expf(-fabsf(p)));
    }
    #pragma unroll
    for (int i = 0; i < 2; i++) {
        int idx = i * 256 + t;
        if (idx < CHEB_K * 32) {
            int k = idx >> 5, q = idx & 31;
            float th = (q + 0.5f) * (PI_F / 32.f);
            costab[k][q] = __cosf((float)k * th);
        }
    }
    if (t < 32) xq[t] = 0.5f * (1.f + __cosf((t + 0.5f) * (PI_F / 32.f)));
    __syncthreads();

    if (t >= 192) return;
    const int d = t & 63, s1 = t >> 6;
    const float u = (float)(s1 + 1) * alph[d];
    float f[32];
    #pragma unroll
    for (int q = 0; q < 32; q++) f[q] = __expf(-u * xq[q]);
    #pragma unroll
    for (int k = 0; k < CHEB_K; k++) {
        float sum = 0.f;
        #pragma unroll
        for (int q = 0; q < 32; q++) sum = fmaf(f[q], costab[k][q], sum);
        float c = sum * ((k == 0 ? 1.f : 2.f) / 32.f);
        clut[s1 * (CHEB_K * 64) + k * 64 + d] = c;
        float sr = c;
        #pragma unroll
        for (int o = 1; o <= 32; o <<= 1) sr += __shfl_xor(sr, o, 64);
        if (d == 0) cD[s1 * CHEB_K + k] = sr;
    }
}

// ---------------------------------------------------------------------------
// Denominators (unchanged).
// ---------------------------------------------------------------------------
__global__ __launch_bounds__(256) void denom3_kernel(
    const float* __restrict__ ct_t, const float* __restrict__ ts_t,
    const float* __restrict__ cD, ushort* __restrict__ invW)
{
    __shared__ float cd[3][CHEB_K];
    const int tid = threadIdx.x;
    if (tid < 3 * CHEB_K) cd[tid / CHEB_K][tid % CHEB_K] = cD[tid];
    __syncthreads();

    const unsigned G = blockIdx.x * 256u + tid;
    const int b = G >> 16;
    const int n = (G >> 7) & 511;
    const int m = G & 127;

    float x = ct_t[b * Msz + m] - ts_t[b * Lsz + n];
    x = x * x;
    const float xi = 2.f * x - 1.f;
    const float xi2 = 2.f * xi;

    float t0 = 1.f, t1 = xi;
    float a1 = cd[0][0] + cd[0][1] * xi;
    float a2 = cd[1][0] + cd[1][1] * xi;
    float a3 = cd[2][0] + cd[2][1] * xi;
    #pragma unroll
    for (int k = 2; k < CHEB_K; k++) {
        float tn = fmaf(xi2, t1, -t0);
        a1 = fmaf(cd[0][k], tn, a1);
        a2 = fmaf(cd[1][k], tn, a2);
        a3 = fmaf(cd[2][k], tn, a3);
        t0 = t1; t1 = tn;
    }
    const size_t base = ((size_t)b * 3 * Lsz + n) * Msz + m;
    invW[base]                         = f2bf(1.f / a1);
    invW[base + (size_t)Lsz * Msz]     = f2bf(1.f / a2);
    invW[base + (size_t)2 * Lsz * Msz] = f2bf(1.f / a3);
}

// ---------------------------------------------------------------------------
// Tokenizer as MFMA (unchanged).
// ---------------------------------------------------------------------------
__global__ __launch_bounds__(256) void tok3_kernel(
    const float* __restrict__ ct_t, const float* __restrict__ ts_t,
    const ushort* __restrict__ ceb, const ushort* __restrict__ invW,
    const float* __restrict__ clut, ushort* __restrict__ Xcat)
{
    const int bid = blockIdx.x;
    const int nt = bid & 7;
    const int s1 = (bid >> 3) % 3;
    const int b  = bid / 24;
    const int tid = threadIdx.x;
    const int w = tid >> 6, lane = tid & 63, g = lane >> 4, r = lane & 15;

    __shared__ ushort ceT[64][136];
    __shared__ float  cl[CHEB_K][64];
    __shared__ float  cts[128];

    #pragma unroll
    for (int i = 0; i < 8; i++) {
        int idx = i * 256 + tid;
        int m = idx >> 4, d4 = (idx & 15) << 2;
        const ushort* gp = ceb + (((size_t)b * 128 + m) << 8) + (s1 + 1) * 64 + d4;
        ushort4 v = *(const ushort4*)gp;
        ceT[d4 + 0][m] = v.x; ceT[d4 + 1][m] = v.y;
        ceT[d4 + 2][m] = v.z; ceT[d4 + 3][m] = v.w;
    }
    #pragma unroll
    for (int i = 0; i < 3; i++) {
        int idx = i * 256 + tid;
        cl[idx >> 6][idx & 63] = clut[s1 * (CHEB_K * 64) + idx];
    }
    if (tid < 128) cts[tid] = ct_t[b * 128 + tid];
    __syncthreads();

    const int nrow = nt * 64 + w * 16 + r;
    const float tsn = ts_t[b * 512 + nrow];

    float xi2v[4][8], Ta[4][8], Tb[4][8];
    #pragma unroll
    for (int t4 = 0; t4 < 4; t4++) {
        int m0 = 8 * g + 32 * t4;
        ushort8 iv = *(const ushort8*)&invW[((((size_t)b * 3 + s1) * 512 + nrow) << 7) + m0];
        #pragma unroll
        for (int j = 0; j < 8; j++) {
            float dfx = cts[m0 + j] - tsn;
            float x = dfx * dfx;
            float xi = 2.f * x - 1.f;
            float w0 = bf2f(iv[j]);
            xi2v[t4][j] = 2.f * xi;
            Ta[t4][j] = w0;
            Tb[t4][j] = w0 * xi;
        }
    }

    bf16x8 cef[4][4];
    #pragma unroll
    for (int db = 0; db < 4; db++)
        #pragma unroll
        for (int t4 = 0; t4 < 4; t4++)
            cef[db][t4] = *(const bf16x8*)&ceT[db * 16 + r][8 * g + 32 * t4];

    f32x4 acc[4];
    #pragma unroll
    for (int db = 0; db < 4; db++) acc[db] = (f32x4){0.f, 0.f, 0.f, 0.f};

    #pragma unroll
    for (int k = 0; k < CHEB_K; k++) {
        if (k >= 2) {
            #pragma unroll
            for (int t4 = 0; t4 < 4; t4++)
                #pragma unroll
                for (int j = 0; j < 8; j++) {
                    if (k & 1) Tb[t4][j] = fmaf(xi2v[t4][j], Ta[t4][j], -Tb[t4][j]);
                    else       Ta[t4][j] = fmaf(xi2v[t4][j], Tb[t4][j], -Ta[t4][j]);
                }
        }
        bf16x8 af[4];
        #pragma unroll
        for (int t4 = 0; t4 < 4; t4++) {
            ushort8 u;
            #pragma unroll
            for (int j = 0; j < 8; j++)
                u[j] = f2bf((k & 1) ? Tb[t4][j] : Ta[t4][j]);
            af[t4] = __builtin_bit_cast(bf16x8, u);
        }
        #pragma unroll
        for (int db = 0; db < 4; db++) {
            f32x4 gk = (f32x4){0.f, 0.f, 0.f, 0.f};
            #pragma unroll
            for (int t4 = 0; t4 < 4; t4++)
                gk = __builtin_amdgcn_mfma_f32_16x16x32_bf16(af[t4], cef[db][t4], gk, 0, 0, 0);
            float ck = cl[k][db * 16 + r];
            #pragma unroll
            for (int p = 0; p < 4; p++) acc[db][p] = fmaf(ck, gk[p], acc[db][p]);
        }
    }

    #pragma unroll
    for (int db = 0; db < 4; db++)
        #pragma unroll
        for (int p = 0; p < 4; p++) {
            int n_out = nt * 64 + w * 16 + 4 * g + p;
            Xcat[((size_t)b * 512 + n_out) * 512 + (s1 + 1) * 64 + db * 16 + r] =
                f2bf(acc[db][p]);
        }
}

// ---------------------------------------------------------------------------
// Scale-0 broadcast (unchanged).
// ---------------------------------------------------------------------------
__global__ __launch_bounds__(256) void bcast0_kernel(
    const ushort* __restrict__ ceb, ushort* __restrict__ Xcat)
{
    const int b = blockIdx.x;
    const int t = threadIdx.x;
    const int d = t & 63, q = t >> 6;
    float s = 0.f;
    #pragma unroll 8
    for (int i = 0; i < 32; i++) {
        int m = q * 32 + i;
        s += bf2f(ceb[(((size_t)b * 128 + m) << 8) + d]);
    }
    __shared__ float red[4][64];
    __shared__ ushort row[64];
    red[q][d] = s;
    __syncthreads();
    if (t < 64)
        row[t] = f2bf((red[0][t] + red[1][t] + red[2][t] + red[3][t]) * (1.f / 64.f));
    __syncthreads();
    #pragma unroll
    for (int i = 0; i < 16; i++) {
        int idx = i * 256 + t;
        int n = idx >> 3, j = idx & 7;
        *(ushort8*)&Xcat[((size_t)b * 512 + n) * 512 + j * 8] =
            *(const ushort8*)&row[j * 8];
    }
}

// ---------------------------------------------------------------------------
// MFMA bf16 flash attention, double-buffered K/V prefetch (issue-early /
// write-late): chunk c+1's K/V loaded to regs during compute of chunk c,
// written to the alternate LDS buffer after compute; 1 barrier per chunk.
// ---------------------------------------------------------------------------
__global__ __launch_bounds__(256) void attn_mfma_kernel(
    const ushort* __restrict__ qkv, ushort* __restrict__ Ob)
{
    const int bid = blockIdx.x;
    const int qt = bid & 7;
    const int h  = (bid >> 3) & 3;
    const int b  = bid >> 5;
    const int t  = threadIdx.x;
    const int w  = t >> 6;
    const int lane = t & 63;
    const int g = lane >> 4;
    const int r = lane & 15;

    __shared__ ushort Ks[2][64][72];
    __shared__ ushort Vt[2][64][72];
    __shared__ float  Ps[4][16][65];

    const ushort* base = qkv + (size_t)b * Lsz * 768;
    const int q0 = qt * 64 + w * 16;

    bf16x8 qf[2];
    {
        const ushort* qp = base + (size_t)(q0 + r) * 768 + h * 64 + 8 * g;
        qf[0] = __builtin_bit_cast(bf16x8, *(const ushort8*)qp);
        qf[1] = __builtin_bit_cast(bf16x8, *(const ushort8*)(qp + 32));
    }

    f32x4 Ofr[4];
    #pragma unroll
    for (int dblk = 0; dblk < 4; dblk++) Ofr[dblk] = (f32x4){0.f, 0.f, 0.f, 0.f};
    float m_run[4] = {-1e30f, -1e30f, -1e30f, -1e30f};
    float l_run[4] = {0.f, 0.f, 0.f, 0.f};

    const int srow = t >> 2;
    const int sseg = t & 3;

    ushort8 pk0, pk1, pv0, pv1;
    auto gload_chunk = [&](int c) {
        const ushort* kr = base + (size_t)(c * 64 + srow) * 768 + 256 + h * 64 + sseg * 16;
        pk0 = *(const ushort8*)kr;
        pk1 = *(const ushort8*)(kr + 8);
        pv0 = *(const ushort8*)(kr + 256);
        pv1 = *(const ushort8*)(kr + 264);
    };
    auto write_chunk = [&](int buf) {
        *(ushort8*)&Ks[buf][srow][sseg * 16]     = pk0;
        *(ushort8*)&Ks[buf][srow][sseg * 16 + 8] = pk1;
        #pragma unroll
        for (int j = 0; j < 8; j++) {
            Vt[buf][sseg * 16 + j][srow]     = pv0[j];
            Vt[buf][sseg * 16 + 8 + j][srow] = pv1[j];
        }
    };

    gload_chunk(0);
    write_chunk(0);
    __syncthreads();
    int cur = 0;

    for (int c = 0; c < 8; c++) {
        if (c < 7) gload_chunk(c + 1);     // prefetch: loads in flight over compute

        // ---- S = (Q K^T) * 0.125 ----
        f32x4 sfr[4];
        #pragma unroll
        for (int s = 0; s < 4; s++) {
            f32x4 a2 = (f32x4){0.f, 0.f, 0.f, 0.f};
            #pragma unroll
            for (int f = 0; f < 2; f++) {
                bf16x8 kf = *(const bf16x8*)&Ks[cur][s * 16 + r][8 * g + 32 * f];
                a2 = __builtin_amdgcn_mfma_f32_16x16x32_bf16(qf[f], kf, a2, 0, 0, 0);
            }
            #pragma unroll
            for (int p = 0; p < 4; p++) a2[p] *= 0.125f;
            sfr[s] = a2;
        }

        // ---- online softmax ----
        #pragma unroll
        for (int p = 0; p < 4; p++) {
            float rm = fmaxf(fmaxf(sfr[0][p], sfr[1][p]), fmaxf(sfr[2][p], sfr[3][p]));
            #pragma unroll
            for (int o = 1; o <= 8; o <<= 1) rm = fmaxf(rm, __shfl_xor(rm, o));
            float mnew = fmaxf(m_run[p], rm);
            float sc = __expf(m_run[p] - mnew);
            m_run[p] = mnew;
            float rs = 0.f;
            #pragma unroll
            for (int s = 0; s < 4; s++) {
                float pv = __expf(sfr[s][p] - mnew);
                Ps[w][4 * g + p][s * 16 + r] = pv;
                rs += pv;
            }
            #pragma unroll
            for (int o = 1; o <= 8; o <<= 1) rs += __shfl_xor(rs, o);
            l_run[p] = l_run[p] * sc + rs;
            #pragma unroll
            for (int dblk = 0; dblk < 4; dblk++) Ofr[dblk][p] *= sc;
        }

        __asm__ volatile("s_waitcnt lgkmcnt(0)" ::: "memory");

        // ---- O += P @ V ----
        #pragma unroll
        for (int f = 0; f < 2; f++) {
            const float* pp = &Ps[w][r][8 * g + 32 * f];
            ushort8 ua;
            #pragma unroll
            for (int j = 0; j < 8; j++) ua[j] = f2bf(pp[j]);
            bf16x8 pa = __builtin_bit_cast(bf16x8, ua);
            #pragma unroll
            for (int dblk = 0; dblk < 4; dblk++) {
                bf16x8 vb = *(const bf16x8*)&Vt[cur][dblk * 16 + r][32 * f + 8 * g];
                Ofr[dblk] = __builtin_amdgcn_mfma_f32_16x16x32_bf16(
                    pa, vb, Ofr[dblk], 0, 0, 0);
            }
        }

        if (c < 7) write_chunk(cur ^ 1);   // buf cur^1 free since last barrier
        __syncthreads();
        cur ^= 1;
    }

    #pragma unroll
    for (int dblk = 0; dblk < 4; dblk++) {
        #pragma unroll
        for (int p = 0; p < 4; p++) {
            int row = q0 + 4 * g + p;
            Ob[(size_t)(b * Lsz + row) * HIDs + h * 64 + dblk * 16 + r] =
                f2bf(Ofr[dblk][p] / l_run[p]);
        }
    }
}

// ---------------------------------------------------------------------------
extern "C" void kernel_launch(void* const* d_in, const int* in_sizes, int n_in,
                              void* d_out, int out_size, void* d_ws, size_t ws_size,
                              hipStream_t stream)
{
    (void)in_sizes; (void)n_in; (void)out_size; (void)ws_size;

    const float* ct_t   = (const float*)d_in[0];
    const float* ts_t   = (const float*)d_in[1];
    const float* ct_emb = (const float*)d_in[2];
    const float* ts_emb = (const float*)d_in[3];
    const float* kp     = (const float*)d_in[4];
    const float* ct_W   = (const float*)d_in[5];
    const float* ct_b   = (const float*)d_in[6];
    const float* fW0    = (const float*)d_in[7];
    const float* fb0    = (const float*)d_in[8];
    const float* fW1    = (const float*)d_in[9];
    const float* fb1    = (const float*)d_in[10];
    const float* fW2    = (const float*)d_in[11];
    const float* fb2    = (const float*)d_in[12];
    const float* f_ln_g = (const float*)d_in[13];
    const float* f_ln_b = (const float*)d_in[14];
    const float* Wqkv   = (const float*)d_in[15];
    const float* bqkv   = (const float*)d_in[16];
    const float* Wo     = (const float*)d_in[17];
    const float* bo     = (const float*)d_in[18];
    const float* W1     = (const float*)d_in[19];
    const float* b1     = (const float*)d_in[20];
    const float* W2     = (const float*)d_in[21];
    const float* b2     = (const float*)d_in[22];
    const float* ln1_g  = (const float*)d_in[23];
    const float* ln1_b  = (const float*)d_in[24];
    const float* ln2_g  = (const float*)d_in[25];
    const float* ln2_b  = (const float*)d_in[26];
    const float* pred_W = (const float*)d_in[27];
    const float* pred_b = (const float*)d_in[28];

    // ---- workspace layout (ushort units unless noted) ----
    ushort* wsb = (ushort*)d_ws;
    ushort* invW  = wsb;                    // [0, 12582912)
    ushort* auxbf = wsb;                    //   reuse after tok3
    ushort* qkvbf = wsb;                    //   reuse
    ushort* ff1bf = wsb;                    //   reuse
    ushort* Xcat  = wsb + 12582912;         // 4,194,304  [8192][512]
    ushort* Wcat  = wsb + 16777216;         // 131,072
    ushort* cebin = wsb + 16908288;         // 524,288
    ushort* cebout= wsb + 17432576;         // 524,288
    ushort* wct   = wsb + 17956864;         // 65,536
    ushort* wf2   = wsb + 18022400;         // 65,536
    ushort* wqkv  = wsb + 18087936;         // 393,216
    ushort* wo    = wsb + 18481152;         // 131,072
    ushort* w1    = wsb + 18612224;         // 262,144
    ushort* w2    = wsb + 18874368;         // 262,144 -> ends 19,136,512
    ushort* xbf   = wsb + 19136512;         // 2,097,152
    ushort* obf   = wsb + 21233664;         // 2,097,152 -> ends 23,330,816
    float*  wsf   = (float*)d_ws;
    float*  xbuf  = wsf + 11665408;         // 2,097,152 fl
    float*  clut  = wsf + 13762560;         // 2,304 fl
    float*  cDp   = wsf + 13764864;         // 36 fl

    const int NRts = Bsz * Lsz;  // 8192
    const int NRct = Bsz * Msz;  // 2048
    auto grid = [](int nr, int out) { return dim3((unsigned)((nr >> 6) * (out >> 7))); };

    // --- convert/pack inputs + weights to bf16 ---
    cvt_all_kernel<<<dim3(1920), 256, 0, stream>>>(
        ts_emb, ct_emb, ct_W, fW0, fW1, fW2, Wqkv, Wo, W1, W2,
        Xcat, Wcat, cebin, wct, wf2, wqkv, wo, w1, w2);

    // --- tokenizer ---
    gemm_mfma_kernel<<<grid(NRct, 256), 256, 0, stream>>>(
        cebin, wct, ct_b, nullptr, nullptr, cebout, NRct, 256, 256, 0);
    cheb_kernel<<<dim3(1), 256, 0, stream>>>(kp, clut, cDp);
    denom3_kernel<<<dim3(Bsz * Msz * Lsz / 256), 256, 0, stream>>>(ct_t, ts_t, cDp, invW);
    tok3_kernel<<<dim3(384), 256, 0, stream>>>(ct_t, ts_t, cebout, invW, clut, Xcat);
    bcast0_kernel<<<dim3(Bsz), 256, 0, stream>>>(cebout, Xcat);

    // --- fusion ---
    gemm_mfma_kernel<<<grid(NRts, 256), 256, 0, stream>>>(
        Xcat, Wcat, fb0, fb1, nullptr, auxbf, NRts, 512, 256, 1);
    gemm_ln_kernel<<<dim3(NRts / 32), 256, 0, stream>>>(
        auxbf, wf2, fb2, ts_emb, f_ln_g, f_ln_b, xbuf, xbf,
        nullptr, nullptr, nullptr, 256);

    // --- transformer layers ---
    for (int l = 0; l < 2; l++) {
        gemm_mfma_kernel<<<grid(NRts, 768), 256, 0, stream>>>(
            xbf, wqkv + (size_t)l * 196608, bqkv + l * 768, nullptr,
            nullptr, qkvbf, NRts, 256, 768, 0);
        attn_mfma_kernel<<<dim3(512), 256, 0, stream>>>(qkvbf, obf);
        gemm_ln_kernel<<<dim3(NRts / 32), 256, 0, stream>>>(
            obf, wo + (size_t)l * 65536, bo + l * 256, xbuf,
            ln1_g + l * 256, ln1_b + l * 256, xbuf, xbf,
            nullptr, nullptr, nullptr, 256);
        gemm_mfma_kernel<<<grid(NRts, 512), 256, 0, stream>>>(
            xbf, w1 + (size_t)l * 131072, b1 + l * 512, nullptr,
            nullptr, ff1bf, NRts, 256, 512, 2);
        if (l == 0) {
            gemm_ln_kernel<<<dim3(NRts / 32), 256, 0, stream>>>(
                ff1bf, w2 + (size_t)l * 131072, b2 + l * 256, xbuf,
                ln2_g + l * 256, ln2_b + l * 256, xbuf, xbf,
                nullptr, nullptr, nullptr, 512);
        } else {
            gemm_ln_kernel<<<dim3(NRts / 32), 256, 0, stream>>>(
                ff1bf, w2 + (size_t)l * 131072, b2 + l * 256, xbuf,
                ln2_g + l * 256, ln2_b + l * 256, nullptr, nullptr,
                pred_W, pred_b, (float*)d_out, 512);
        }
    }
}

// Round 8
// 206.976 us; speedup vs baseline: 6.6885x; 1.0553x over previous
//
#include <hip/hip_runtime.h>
#include <hip/hip_bf16.h>
#include <cstddef>

// Shapes: B=16, M=128, L=512, HID=256, H=4, DH=64, LAYERS=2
#define Bsz 16
#define Msz 128
#define Lsz 512
#define HIDs 256

typedef __attribute__((ext_vector_type(4))) float f32x4;
typedef __attribute__((ext_vector_type(8))) __bf16 bf16x8;
typedef __attribute__((ext_vector_type(8))) unsigned short ushort8;

#define CHEB_K 12
#define PI_F 3.14159265358979323846f

static __device__ inline unsigned short f2bf(float f) {
    __hip_bfloat16 h = __float2bfloat16(f);
    return *(unsigned short*)&h;
}
static __device__ inline float bf2f(unsigned short u) {
    return __builtin_bit_cast(float, (unsigned)u << 16);
}
static __device__ inline void gload16(const ushort* g, ushort* l) {
    __builtin_amdgcn_global_load_lds(
        (const __attribute__((address_space(1))) void*)g,
        (__attribute__((address_space(3))) void*)l, 16, 0, 0);
}

// ---------------------------------------------------------------------------
// Chebyshev coefficients (1 block).
// ---------------------------------------------------------------------------
__global__ __launch_bounds__(256) void cheb_kernel(
    const float* __restrict__ kp, float* __restrict__ clut, float* __restrict__ cD)
{
    __shared__ float costab[CHEB_K][32];
    __shared__ float xq[32];
    __shared__ float alph[64];
    const int t = threadIdx.x;
    if (t < 64) {
        float p = kp[t];
        alph[t] = fmaxf(p, 0.f) + log1pf(__expf(-fabsf(p)));
    }
    #pragma unroll
    for (int i = 0; i < 2; i++) {
        int idx = i * 256 + t;
        if (idx < CHEB_K * 32) {
            int k = idx >> 5, q = idx & 31;
            float th = (q + 0.5f) * (PI_F / 32.f);
            costab[k][q] = __cosf((float)k * th);
        }
    }
    if (t < 32) xq[t] = 0.5f * (1.f + __cosf((t + 0.5f) * (PI_F / 32.f)));
    __syncthreads();

    if (t >= 192) return;
    const int d = t & 63, s1 = t >> 6;
    const float u = (float)(s1 + 1) * alph[d];
    float f[32];
    #pragma unroll
    for (int q = 0; q < 32; q++) f[q] = __expf(-u * xq[q]);
    #pragma unroll
    for (int k = 0; k < CHEB_K; k++) {
        float sum = 0.f;
        #pragma unroll
        for (int q = 0; q < 32; q++) sum = fmaf(f[q], costab[k][q], sum);
        float c = sum * ((k == 0 ? 1.f : 2.f) / 32.f);
        clut[s1 * (CHEB_K * 64) + k * 64 + d] = c;
        float sr = c;
        #pragma unroll
        for (int o = 1; o <= 32; o <<= 1) sr += __shfl_xor(sr, o, 64);
        if (d == 0) cD[s1 * CHEB_K + k] = sr;
    }
}

// ---------------------------------------------------------------------------
// Grid-fused prep: blocks [0,1920) = fp32->bf16 cvt/repack;
// blocks [1920, 6016) = tokenizer denominators (needs cD from cheb_kernel).
// ---------------------------------------------------------------------------
__global__ __launch_bounds__(256) void prep_kernel(
    const float* __restrict__ ts_emb, const float* __restrict__ ct_emb,
    const float* __restrict__ ct_W, const float* __restrict__ fW0,
    const float* __restrict__ fW1, const float* __restrict__ fW2,
    const float* __restrict__ Wqkv, const float* __restrict__ Wo,
    const float* __restrict__ W1, const float* __restrict__ W2,
    ushort* __restrict__ Xcat, ushort* __restrict__ Wcat,
    ushort* __restrict__ cebin, ushort* __restrict__ wct,
    ushort* __restrict__ wf2, ushort* __restrict__ wqkv,
    ushort* __restrict__ wo, ushort* __restrict__ w1, ushort* __restrict__ w2,
    const float* __restrict__ ct_t, const float* __restrict__ ts_t,
    const float* __restrict__ cD, ushort* __restrict__ invW)
{
    const int bid = blockIdx.x;
    const int tid = threadIdx.x;

    if (bid < 1920) {
        // ---- cvt/repack ----
        const unsigned u = bid * 256u + tid;
        const float* src; ushort* dst; unsigned rel;
        if (u < 262144u) {
            rel = u; src = ts_emb;
            dst = Xcat + ((size_t)(rel >> 5) * 512 + 256 + (rel & 31) * 8);
        } else if (u < 327680u) { rel = u - 262144u; src = ct_emb; dst = cebin + (size_t)rel * 8; }
        else if (u < 335872u) { rel = u - 327680u; src = ct_W; dst = wct + (size_t)rel * 8; }
        else if (u < 344064u) { rel = u - 335872u; src = fW0;
            dst = Wcat + ((size_t)(rel >> 5) * 512 + (rel & 31) * 8); }
        else if (u < 352256u) { rel = u - 344064u; src = fW1;
            dst = Wcat + ((size_t)(rel >> 5) * 512 + 256 + (rel & 31) * 8); }
        else if (u < 360448u) { rel = u - 352256u; src = fW2; dst = wf2 + (size_t)rel * 8; }
        else if (u < 409600u) { rel = u - 360448u; src = Wqkv; dst = wqkv + (size_t)rel * 8; }
        else if (u < 425984u) { rel = u - 409600u; src = Wo;  dst = wo + (size_t)rel * 8; }
        else if (u < 458752u) { rel = u - 425984u; src = W1;  dst = w1 + (size_t)rel * 8; }
        else                  { rel = u - 458752u; src = W2;  dst = w2 + (size_t)rel * 8; }
        float4 a = ((const float4*)src)[(size_t)rel * 2];
        float4 b = ((const float4*)src)[(size_t)rel * 2 + 1];
        ushort8 o;
        o[0] = f2bf(a.x); o[1] = f2bf(a.y); o[2] = f2bf(a.z); o[3] = f2bf(a.w);
        o[4] = f2bf(b.x); o[5] = f2bf(b.y); o[6] = f2bf(b.z); o[7] = f2bf(b.w);
        *(ushort8*)dst = o;
    } else {
        // ---- denominators ----
        __shared__ float cd[3][CHEB_K];
        if (tid < 3 * CHEB_K) cd[tid / CHEB_K][tid % CHEB_K] = cD[tid];
        __syncthreads();

        const unsigned G = (bid - 1920) * 256u + tid;
        const int b = G >> 16;
        const int n = (G >> 7) & 511;
        const int m = G & 127;

        float x = ct_t[b * Msz + m] - ts_t[b * Lsz + n];
        x = x * x;
        const float xi = 2.f * x - 1.f;
        const float xi2 = 2.f * xi;

        float t0 = 1.f, t1 = xi;
        float a1 = cd[0][0] + cd[0][1] * xi;
        float a2 = cd[1][0] + cd[1][1] * xi;
        float a3 = cd[2][0] + cd[2][1] * xi;
        #pragma unroll
        for (int k = 2; k < CHEB_K; k++) {
            float tn = fmaf(xi2, t1, -t0);
            a1 = fmaf(cd[0][k], tn, a1);
            a2 = fmaf(cd[1][k], tn, a2);
            a3 = fmaf(cd[2][k], tn, a3);
            t0 = t1; t1 = tn;
        }
        const size_t base = ((size_t)b * 3 * Lsz + n) * Msz + m;
        invW[base]                         = f2bf(1.f / a1);
        invW[base + (size_t)Lsz * Msz]     = f2bf(1.f / a2);
        invW[base + (size_t)2 * Lsz * Msz] = f2bf(1.f / a3);
    }
}

// ---------------------------------------------------------------------------
// MFMA bf16 GEMM, double-buffered prefetch (unchanged from round 6).
// Y = act(X[NR,K] @ W[OUT,K]^T + bias (+bias2)); 64x128 tile, 4 waves.
// ---------------------------------------------------------------------------
__global__ __launch_bounds__(256) void gemm_mfma_kernel(
    const ushort* __restrict__ X, const ushort* __restrict__ W,
    const float* __restrict__ bias, const float* __restrict__ bias2,
    float* __restrict__ Yf, ushort* __restrict__ Yb,
    int NR, int K, int OUT, int act)
{
    __shared__ ushort As[2][64 * 64];
    __shared__ ushort Bs[2][128 * 64];

    const int nbx = OUT >> 7;
    const int bx = blockIdx.x % nbx;
    const int by = blockIdx.x / nbx;
    const int r0 = by << 6, o0 = bx << 7;
    const int tid = threadIdx.x;
    const int w = tid >> 6;
    const int lane = tid & 63;
    const int wr = w >> 1, wc = w & 1;
    const int lr = lane & 15, lg = lane >> 4;

    const int grow = lane >> 3;
    const int gchunk = (lane & 7) ^ grow;

    unsigned aoff[2][2], boff[4][2];
    #pragma unroll
    for (int f = 0; f < 2; f++) {
        unsigned cc = (unsigned)((lg + 4 * f) ^ (lr & 7)) * 16u;
        #pragma unroll
        for (int m = 0; m < 2; m++)
            aoff[m][f] = (unsigned)(wr * 32 + m * 16 + lr) * 128u + cc;
        #pragma unroll
        for (int n = 0; n < 4; n++)
            boff[n][f] = (unsigned)(wc * 64 + n * 16 + lr) * 128u + cc;
    }

    f32x4 acc[2][4];
    #pragma unroll
    for (int m = 0; m < 2; m++)
        #pragma unroll
        for (int n = 0; n < 4; n++) acc[m][n] = (f32x4){0.f, 0.f, 0.f, 0.f};

    const int nk = K >> 6;

    auto stage = [&](int buf, int ks) {
        const int k0 = ks << 6;
        #pragma unroll
        for (int i = 0; i < 2; i++) {
            int row = w * 16 + i * 8 + grow;
            gload16(X + (size_t)(r0 + row) * K + k0 + gchunk * 8,
                    &As[buf][(w * 16 + i * 8) * 64]);
        }
        #pragma unroll
        for (int i = 0; i < 4; i++) {
            int row = w * 32 + i * 8 + grow;
            gload16(W + (size_t)(o0 + row) * K + k0 + gchunk * 8,
                    &Bs[buf][(w * 32 + i * 8) * 64]);
        }
    };

    stage(0, 0);
    __syncthreads();
    int cur = 0;
    for (int ks = 0; ks < nk; ks++) {
        if (ks + 1 < nk) stage(cur ^ 1, ks + 1);
        const char* Ab = (const char*)As[cur];
        const char* Bb = (const char*)Bs[cur];
        #pragma unroll
        for (int f = 0; f < 2; f++) {
            bf16x8 av[2], bv[4];
            #pragma unroll
            for (int m = 0; m < 2; m++)
                av[m] = *(const bf16x8*)(Ab + aoff[m][f]);
            #pragma unroll
            for (int n = 0; n < 4; n++)
                bv[n] = *(const bf16x8*)(Bb + boff[n][f]);
            #pragma unroll
            for (int m = 0; m < 2; m++)
                #pragma unroll
                for (int n = 0; n < 4; n++)
                    acc[m][n] = __builtin_amdgcn_mfma_f32_16x16x32_bf16(
                        av[m], bv[n], acc[m][n], 0, 0, 0);
        }
        __syncthreads();
        cur ^= 1;
    }

    const int ocol0 = o0 + wc * 64;
    float bn[4];
    #pragma unroll
    for (int n = 0; n < 4; n++) {
        int o = ocol0 + n * 16 + lr;
        bn[n] = bias[o] + (bias2 ? bias2[o] : 0.f);
    }

    #pragma unroll
    for (int m = 0; m < 2; m++) {
        #pragma unroll
        for (int p = 0; p < 4; p++) {
            int r = r0 + wr * 32 + m * 16 + 4 * lg + p;
            size_t rb = (size_t)r * OUT;
            #pragma unroll
            for (int n = 0; n < 4; n++) {
                int o = ocol0 + n * 16 + lr;
                float v = acc[m][n][p] + bn[n];
                if (act == 1)      v = (v > 0.f) ? v : (__expf(v) - 1.f);
                else if (act == 2) v = 0.5f * v * (1.f + erff(v * 0.70710678118654752f));
                if (Yf) Yf[rb + o] = v;
                if (Yb) Yb[rb + o] = f2bf(v);
            }
        }
    }
}

// ---------------------------------------------------------------------------
// Fused GEMM + residual + LayerNorm (+ optional pred head).
// 16 rows x 256 cols per block (512 blocks = 2/CU), 4 waves = col slices,
// double-buffered staging.
// ---------------------------------------------------------------------------
__global__ __launch_bounds__(256) void gemm_ln_kernel(
    const ushort* __restrict__ X, const ushort* __restrict__ W,
    const float* __restrict__ bias, const float* __restrict__ add,
    const float* __restrict__ lng, const float* __restrict__ lnb,
    float* __restrict__ Xf, ushort* __restrict__ Xb,
    const float* __restrict__ predW, const float* __restrict__ predb,
    float* __restrict__ pout, int K)
{
    __shared__ ushort As[2][16 * 64];
    __shared__ ushort Bs[2][256 * 64];
    __shared__ float redA[16][4];
    __shared__ float redB[16][4];

    const int r0 = blockIdx.x << 4;
    const int tid = threadIdx.x;
    const int w = tid >> 6;          // wave = 64-col slice
    const int lane = tid & 63;
    const int lr = lane & 15, lg = lane >> 4;
    const int grow = lane >> 3;
    const int gchunk = (lane & 7) ^ grow;

    unsigned aoff[2], boff[4][2];
    #pragma unroll
    for (int f = 0; f < 2; f++) {
        unsigned cc = (unsigned)((lg + 4 * f) ^ (lr & 7)) * 16u;
        aoff[f] = (unsigned)lr * 128u + cc;
        #pragma unroll
        for (int n = 0; n < 4; n++)
            boff[n][f] = (unsigned)(w * 64 + n * 16 + lr) * 128u + cc;
    }

    f32x4 acc[4];
    #pragma unroll
    for (int n = 0; n < 4; n++) acc[n] = (f32x4){0.f, 0.f, 0.f, 0.f};

    const int nk = K >> 6;

    auto stage = [&](int buf, int ks) {
        const int k0 = ks << 6;
        if (w < 2)
            gload16(X + (size_t)(r0 + w * 8 + grow) * K + k0 + gchunk * 8,
                    &As[buf][(w * 8) * 64]);
        #pragma unroll
        for (int i = 0; i < 8; i++) {
            gload16(W + (size_t)(w * 64 + i * 8 + grow) * K + k0 + gchunk * 8,
                    &Bs[buf][(w * 64 + i * 8) * 64]);
        }
    };

    stage(0, 0);
    __syncthreads();
    int cur = 0;
    for (int ks = 0; ks < nk; ks++) {
        if (ks + 1 < nk) stage(cur ^ 1, ks + 1);
        const char* Ab = (const char*)As[cur];
        const char* Bb = (const char*)Bs[cur];
        #pragma unroll
        for (int f = 0; f < 2; f++) {
            bf16x8 av = *(const bf16x8*)(Ab + aoff[f]);
            #pragma unroll
            for (int n = 0; n < 4; n++) {
                bf16x8 bv = *(const bf16x8*)(Bb + boff[n][f]);
                acc[n] = __builtin_amdgcn_mfma_f32_16x16x32_bf16(
                    av, bv, acc[n], 0, 0, 0);
            }
        }
        __syncthreads();
        cur ^= 1;
    }

    // ---- epilogue: v = acc + bias + add ----
    const int col0 = w * 64;
    float bn[4], gv[4], bv2[4], pwv[4];
    #pragma unroll
    for (int n = 0; n < 4; n++) {
        int o = col0 + n * 16 + lr;
        bn[n] = bias[o];
        gv[n] = lng[o];
        bv2[n] = lnb[o];
        pwv[n] = predW ? predW[o] : 0.f;
    }
    #pragma unroll
    for (int p = 0; p < 4; p++) {
        int r = r0 + 4 * lg + p;
        size_t rb = (size_t)r * 256;
        #pragma unroll
        for (int n = 0; n < 4; n++)
            acc[n][p] += bn[n] + add[rb + col0 + n * 16 + lr];
    }

    // ---- pass 1: row sums -> mean ----
    #pragma unroll
    for (int p = 0; p < 4; p++) {
        float s = acc[0][p] + acc[1][p] + acc[2][p] + acc[3][p];
        #pragma unroll
        for (int o = 1; o <= 8; o <<= 1) s += __shfl_xor(s, o);
        if (lr == 0) redA[4 * lg + p][w] = s;
    }
    __syncthreads();
    float mu[4];
    #pragma unroll
    for (int p = 0; p < 4; p++) {
        int row = 4 * lg + p;
        mu[p] = (redA[row][0] + redA[row][1] + redA[row][2] + redA[row][3])
                * (1.f / 256.f);
    }

    // ---- pass 2: sum of squared deviations -> var ----
    #pragma unroll
    for (int p = 0; p < 4; p++) {
        float q = 0.f;
        #pragma unroll
        for (int n = 0; n < 4; n++) {
            float dl = acc[n][p] - mu[p];
            q = fmaf(dl, dl, q);
        }
        #pragma unroll
        for (int o = 1; o <= 8; o <<= 1) q += __shfl_xor(q, o);
        if (lr == 0) redB[4 * lg + p][w] = q;
    }
    __syncthreads();

    // ---- normalize, write, optional pred dot ----
    #pragma unroll
    for (int p = 0; p < 4; p++) {
        int row = 4 * lg + p;
        float var = (redB[row][0] + redB[row][1] + redB[row][2] + redB[row][3])
                    * (1.f / 256.f);
        float rsig = rsqrtf(var + 1e-5f);
        int r = r0 + row;
        size_t rb = (size_t)r * 256;
        float pd = 0.f;
        #pragma unroll
        for (int n = 0; n < 4; n++) {
            int o = col0 + n * 16 + lr;
            float xn = (acc[n][p] - mu[p]) * rsig * gv[n] + bv2[n];
            if (Xf) Xf[rb + o] = xn;
            if (Xb) Xb[rb + o] = f2bf(xn);
            pd = fmaf(xn, pwv[n], pd);
        }
        if (predW) {
            #pragma unroll
            for (int o = 1; o <= 8; o <<= 1) pd += __shfl_xor(pd, o);
            if (lr == 0) redA[row][w] = pd;
        }
    }
    if (predW) {
        __syncthreads();
        if (tid < 16)
            pout[r0 + tid] = redA[tid][0] + redA[tid][1] + redA[tid][2]
                           + redA[tid][3] + predb[0];
    }
}

// ---------------------------------------------------------------------------
// Grid-fused tokenizer: blocks [0,384) = tok3 MFMA; [384,400) = scale-0 bcast.
// ---------------------------------------------------------------------------
__global__ __launch_bounds__(256) void tokmix_kernel(
    const float* __restrict__ ct_t, const float* __restrict__ ts_t,
    const ushort* __restrict__ ceb, const ushort* __restrict__ invW,
    const float* __restrict__ clut, ushort* __restrict__ Xcat)
{
    const int bid = blockIdx.x;
    const int tid = threadIdx.x;

    if (bid < 384) {
        const int nt = bid & 7;
        const int s1 = (bid >> 3) % 3;
        const int b  = bid / 24;
        const int w = tid >> 6, lane = tid & 63, g = lane >> 4, r = lane & 15;

        __shared__ ushort ceT[64][136];
        __shared__ float  cl[CHEB_K][64];
        __shared__ float  cts[128];

        #pragma unroll
        for (int i = 0; i < 8; i++) {
            int idx = i * 256 + tid;
            int m = idx >> 4, d4 = (idx & 15) << 2;
            const ushort* gp = ceb + (((size_t)b * 128 + m) << 8) + (s1 + 1) * 64 + d4;
            ushort4 v = *(const ushort4*)gp;
            ceT[d4 + 0][m] = v.x; ceT[d4 + 1][m] = v.y;
            ceT[d4 + 2][m] = v.z; ceT[d4 + 3][m] = v.w;
        }
        #pragma unroll
        for (int i = 0; i < 3; i++) {
            int idx = i * 256 + tid;
            cl[idx >> 6][idx & 63] = clut[s1 * (CHEB_K * 64) + idx];
        }
        if (tid < 128) cts[tid] = ct_t[b * 128 + tid];
        __syncthreads();

        const int nrow = nt * 64 + w * 16 + r;
        const float tsn = ts_t[b * 512 + nrow];

        float xi2v[4][8], Ta[4][8], Tb[4][8];
        #pragma unroll
        for (int t4 = 0; t4 < 4; t4++) {
            int m0 = 8 * g + 32 * t4;
            ushort8 iv = *(const ushort8*)&invW[((((size_t)b * 3 + s1) * 512 + nrow) << 7) + m0];
            #pragma unroll
            for (int j = 0; j < 8; j++) {
                float dfx = cts[m0 + j] - tsn;
                float x = dfx * dfx;
                float xi = 2.f * x - 1.f;
                float w0 = bf2f(iv[j]);
                xi2v[t4][j] = 2.f * xi;
                Ta[t4][j] = w0;
                Tb[t4][j] = w0 * xi;
            }
        }

        bf16x8 cef[4][4];
        #pragma unroll
        for (int db = 0; db < 4; db++)
            #pragma unroll
            for (int t4 = 0; t4 < 4; t4++)
                cef[db][t4] = *(const bf16x8*)&ceT[db * 16 + r][8 * g + 32 * t4];

        f32x4 acc[4];
        #pragma unroll
        for (int db = 0; db < 4; db++) acc[db] = (f32x4){0.f, 0.f, 0.f, 0.f};

        #pragma unroll
        for (int k = 0; k < CHEB_K; k++) {
            if (k >= 2) {
                #pragma unroll
                for (int t4 = 0; t4 < 4; t4++)
                    #pragma unroll
                    for (int j = 0; j < 8; j++) {
                        if (k & 1) Tb[t4][j] = fmaf(xi2v[t4][j], Ta[t4][j], -Tb[t4][j]);
                        else       Ta[t4][j] = fmaf(xi2v[t4][j], Tb[t4][j], -Ta[t4][j]);
                    }
            }
            bf16x8 af[4];
            #pragma unroll
            for (int t4 = 0; t4 < 4; t4++) {
                ushort8 u;
                #pragma unroll
                for (int j = 0; j < 8; j++)
                    u[j] = f2bf((k & 1) ? Tb[t4][j] : Ta[t4][j]);
                af[t4] = __builtin_bit_cast(bf16x8, u);
            }
            #pragma unroll
            for (int db = 0; db < 4; db++) {
                f32x4 gk = (f32x4){0.f, 0.f, 0.f, 0.f};
                #pragma unroll
                for (int t4 = 0; t4 < 4; t4++)
                    gk = __builtin_amdgcn_mfma_f32_16x16x32_bf16(af[t4], cef[db][t4], gk, 0, 0, 0);
                float ck = cl[k][db * 16 + r];
                #pragma unroll
                for (int p = 0; p < 4; p++) acc[db][p] = fmaf(ck, gk[p], acc[db][p]);
            }
        }

        #pragma unroll
        for (int db = 0; db < 4; db++)
            #pragma unroll
            for (int p = 0; p < 4; p++) {
                int n_out = nt * 64 + w * 16 + 4 * g + p;
                Xcat[((size_t)b * 512 + n_out) * 512 + (s1 + 1) * 64 + db * 16 + r] =
                    f2bf(acc[db][p]);
            }
    } else {
        // ---- scale-0 broadcast ----
        const int b = bid - 384;
        const int d = tid & 63, q = tid >> 6;
        float s = 0.f;
        #pragma unroll 8
        for (int i = 0; i < 32; i++) {
            int m = q * 32 + i;
            s += bf2f(ceb[(((size_t)b * 128 + m) << 8) + d]);
        }
        __shared__ float red0[4][64];
        __shared__ ushort row0[64];
        red0[q][d] = s;
        __syncthreads();
        if (tid < 64)
            row0[tid] = f2bf((red0[0][tid] + red0[1][tid] + red0[2][tid] + red0[3][tid])
                             * (1.f / 64.f));
        __syncthreads();
        #pragma unroll
        for (int i = 0; i < 16; i++) {
            int idx = i * 256 + tid;
            int n = idx >> 3, j = idx & 7;
            *(ushort8*)&Xcat[((size_t)b * 512 + n) * 512 + j * 8] =
                *(const ushort8*)&row0[j * 8];
        }
    }
}

// ---------------------------------------------------------------------------
// MFMA bf16 flash attention: single LDS buffer (35 KB -> 2 blocks/CU by grid)
// + register prefetch (issue-early / write-late).
// ---------------------------------------------------------------------------
__global__ __launch_bounds__(256) void attn_mfma_kernel(
    const ushort* __restrict__ qkv, ushort* __restrict__ Ob)
{
    const int bid = blockIdx.x;
    const int qt = bid & 7;
    const int h  = (bid >> 3) & 3;
    const int b  = bid >> 5;
    const int t  = threadIdx.x;
    const int w  = t >> 6;
    const int lane = t & 63;
    const int g = lane >> 4;
    const int r = lane & 15;

    __shared__ ushort Ks[64][72];
    __shared__ ushort Vt[64][72];
    __shared__ float  Ps[4][16][65];

    const ushort* base = qkv + (size_t)b * Lsz * 768;
    const int q0 = qt * 64 + w * 16;

    bf16x8 qf[2];
    {
        const ushort* qp = base + (size_t)(q0 + r) * 768 + h * 64 + 8 * g;
        qf[0] = __builtin_bit_cast(bf16x8, *(const ushort8*)qp);
        qf[1] = __builtin_bit_cast(bf16x8, *(const ushort8*)(qp + 32));
    }

    f32x4 Ofr[4];
    #pragma unroll
    for (int dblk = 0; dblk < 4; dblk++) Ofr[dblk] = (f32x4){0.f, 0.f, 0.f, 0.f};
    float m_run[4] = {-1e30f, -1e30f, -1e30f, -1e30f};
    float l_run[4] = {0.f, 0.f, 0.f, 0.f};

    const int srow = t >> 2;
    const int sseg = t & 3;

    ushort8 pk0, pk1, pv0, pv1;
    auto gload_chunk = [&](int c) {
        const ushort* kr = base + (size_t)(c * 64 + srow) * 768 + 256 + h * 64 + sseg * 16;
        pk0 = *(const ushort8*)kr;
        pk1 = *(const ushort8*)(kr + 8);
        pv0 = *(const ushort8*)(kr + 256);
        pv1 = *(const ushort8*)(kr + 264);
    };
    auto write_chunk = [&]() {
        *(ushort8*)&Ks[srow][sseg * 16]     = pk0;
        *(ushort8*)&Ks[srow][sseg * 16 + 8] = pk1;
        #pragma unroll
        for (int j = 0; j < 8; j++) {
            Vt[sseg * 16 + j][srow]     = pv0[j];
            Vt[sseg * 16 + 8 + j][srow] = pv1[j];
        }
    };

    gload_chunk(0);
    write_chunk();
    __syncthreads();

    for (int c = 0; c < 8; c++) {
        if (c < 7) gload_chunk(c + 1);     // loads in flight over compute

        // ---- S = (Q K^T) * 0.125 ----
        f32x4 sfr[4];
        #pragma unroll
        for (int s = 0; s < 4; s++) {
            f32x4 a2 = (f32x4){0.f, 0.f, 0.f, 0.f};
            #pragma unroll
            for (int f = 0; f < 2; f++) {
                bf16x8 kf = *(const bf16x8*)&Ks[s * 16 + r][8 * g + 32 * f];
                a2 = __builtin_amdgcn_mfma_f32_16x16x32_bf16(qf[f], kf, a2, 0, 0, 0);
            }
            #pragma unroll
            for (int p = 0; p < 4; p++) a2[p] *= 0.125f;
            sfr[s] = a2;
        }

        // ---- online softmax ----
        #pragma unroll
        for (int p = 0; p < 4; p++) {
            float rm = fmaxf(fmaxf(sfr[0][p], sfr[1][p]), fmaxf(sfr[2][p], sfr[3][p]));
            #pragma unroll
            for (int o = 1; o <= 8; o <<= 1) rm = fmaxf(rm, __shfl_xor(rm, o));
            float mnew = fmaxf(m_run[p], rm);
            float sc = __expf(m_run[p] - mnew);
            m_run[p] = mnew;
            float rs = 0.f;
            #pragma unroll
            for (int s = 0; s < 4; s++) {
                float pv = __expf(sfr[s][p] - mnew);
                Ps[w][4 * g + p][s * 16 + r] = pv;
                rs += pv;
            }
            #pragma unroll
            for (int o = 1; o <= 8; o <<= 1) rs += __shfl_xor(rs, o);
            l_run[p] = l_run[p] * sc + rs;
            #pragma unroll
            for (int dblk = 0; dblk < 4; dblk++) Ofr[dblk][p] *= sc;
        }

        __asm__ volatile("s_waitcnt lgkmcnt(0)" ::: "memory");

        // ---- O += P @ V ----
        #pragma unroll
        for (int f = 0; f < 2; f++) {
            const float* pp = &Ps[w][r][8 * g + 32 * f];
            ushort8 ua;
            #pragma unroll
            for (int j = 0; j < 8; j++) ua[j] = f2bf(pp[j]);
            bf16x8 pa = __builtin_bit_cast(bf16x8, ua);
            #pragma unroll
            for (int dblk = 0; dblk < 4; dblk++) {
                bf16x8 vb = *(const bf16x8*)&Vt[dblk * 16 + r][32 * f + 8 * g];
                Ofr[dblk] = __builtin_amdgcn_mfma_f32_16x16x32_bf16(
                    pa, vb, Ofr[dblk], 0, 0, 0);
            }
        }

        __syncthreads();                   // all waves done reading Ks/Vt
        if (c < 7) {
            write_chunk();                 // s_waitcnt vmcnt here (late)
            __syncthreads();               // writes visible
        }
    }

    #pragma unroll
    for (int dblk = 0; dblk < 4; dblk++) {
        #pragma unroll
        for (int p = 0; p < 4; p++) {
            int row = q0 + 4 * g + p;
            Ob[(size_t)(b * Lsz + row) * HIDs + h * 64 + dblk * 16 + r] =
                f2bf(Ofr[dblk][p] / l_run[p]);
        }
    }
}

// ---------------------------------------------------------------------------
extern "C" void kernel_launch(void* const* d_in, const int* in_sizes, int n_in,
                              void* d_out, int out_size, void* d_ws, size_t ws_size,
                              hipStream_t stream)
{
    (void)in_sizes; (void)n_in; (void)out_size; (void)ws_size;

    const float* ct_t   = (const float*)d_in[0];
    const float* ts_t   = (const float*)d_in[1];
    const float* ct_emb = (const float*)d_in[2];
    const float* ts_emb = (const float*)d_in[3];
    const float* kp     = (const float*)d_in[4];
    const float* ct_W   = (const float*)d_in[5];
    const float* ct_b   = (const float*)d_in[6];
    const float* fW0    = (const float*)d_in[7];
    const float* fb0    = (const float*)d_in[8];
    const float* fW1    = (const float*)d_in[9];
    const float* fb1    = (const float*)d_in[10];
    const float* fW2    = (const float*)d_in[11];
    const float* fb2    = (const float*)d_in[12];
    const float* f_ln_g = (const float*)d_in[13];
    const float* f_ln_b = (const float*)d_in[14];
    const float* Wqkv   = (const float*)d_in[15];
    const float* bqkv   = (const float*)d_in[16];
    const float* Wo     = (const float*)d_in[17];
    const float* bo     = (const float*)d_in[18];
    const float* W1     = (const float*)d_in[19];
    const float* b1     = (const float*)d_in[20];
    const float* W2     = (const float*)d_in[21];
    const float* b2     = (const float*)d_in[22];
    const float* ln1_g  = (const float*)d_in[23];
    const float* ln1_b  = (const float*)d_in[24];
    const float* ln2_g  = (const float*)d_in[25];
    const float* ln2_b  = (const float*)d_in[26];
    const float* pred_W = (const float*)d_in[27];
    const float* pred_b = (const float*)d_in[28];

    // ---- workspace layout (ushort units unless noted) ----
    ushort* wsb = (ushort*)d_ws;
    ushort* invW  = wsb;                    // [0, 12582912)
    ushort* auxbf = wsb;                    //   reuse after tokmix
    ushort* qkvbf = wsb;                    //   reuse
    ushort* ff1bf = wsb;                    //   reuse
    ushort* Xcat  = wsb + 12582912;         // 4,194,304  [8192][512]
    ushort* Wcat  = wsb + 16777216;         // 131,072
    ushort* cebin = wsb + 16908288;         // 524,288
    ushort* cebout= wsb + 17432576;         // 524,288
    ushort* wct   = wsb + 17956864;         // 65,536
    ushort* wf2   = wsb + 18022400;         // 65,536
    ushort* wqkv  = wsb + 18087936;         // 393,216
    ushort* wo    = wsb + 18481152;         // 131,072
    ushort* w1    = wsb + 18612224;         // 262,144
    ushort* w2    = wsb + 18874368;         // 262,144 -> ends 19,136,512
    ushort* xbf   = wsb + 19136512;         // 2,097,152
    ushort* obf   = wsb + 21233664;         // 2,097,152 -> ends 23,330,816
    float*  wsf   = (float*)d_ws;
    float*  xbuf  = wsf + 11665408;         // 2,097,152 fl
    float*  clut  = wsf + 13762560;         // 2,304 fl
    float*  cDp   = wsf + 13764864;         // 36 fl

    const int NRts = Bsz * Lsz;  // 8192
    const int NRct = Bsz * Msz;  // 2048
    auto grid = [](int nr, int out) { return dim3((unsigned)((nr >> 6) * (out >> 7))); };

    // --- prep: cheb (1 blk), then cvt + denom3 grid-fused ---
    cheb_kernel<<<dim3(1), 256, 0, stream>>>(kp, clut, cDp);
    prep_kernel<<<dim3(1920 + 4096), 256, 0, stream>>>(
        ts_emb, ct_emb, ct_W, fW0, fW1, fW2, Wqkv, Wo, W1, W2,
        Xcat, Wcat, cebin, wct, wf2, wqkv, wo, w1, w2,
        ct_t, ts_t, cDp, invW);

    // --- tokenizer ---
    gemm_mfma_kernel<<<grid(NRct, 256), 256, 0, stream>>>(
        cebin, wct, ct_b, nullptr, nullptr, cebout, NRct, 256, 256, 0);
    tokmix_kernel<<<dim3(400), 256, 0, stream>>>(ct_t, ts_t, cebout, invW, clut, Xcat);

    // --- fusion ---
    gemm_mfma_kernel<<<grid(NRts, 256), 256, 0, stream>>>(
        Xcat, Wcat, fb0, fb1, nullptr, auxbf, NRts, 512, 256, 1);
    gemm_ln_kernel<<<dim3(NRts / 16), 256, 0, stream>>>(
        auxbf, wf2, fb2, ts_emb, f_ln_g, f_ln_b, xbuf, xbf,
        nullptr, nullptr, nullptr, 256);

    // --- transformer layers ---
    for (int l = 0; l < 2; l++) {
        gemm_mfma_kernel<<<grid(NRts, 768), 256, 0, stream>>>(
            xbf, wqkv + (size_t)l * 196608, bqkv + l * 768, nullptr,
            nullptr, qkvbf, NRts, 256, 768, 0);
        attn_mfma_kernel<<<dim3(512), 256, 0, stream>>>(qkvbf, obf);
        gemm_ln_kernel<<<dim3(NRts / 16), 256, 0, stream>>>(
            obf, wo + (size_t)l * 65536, bo + l * 256, xbuf,
            ln1_g + l * 256, ln1_b + l * 256, xbuf, xbf,
            nullptr, nullptr, nullptr, 256);
        gemm_mfma_kernel<<<grid(NRts, 512), 256, 0, stream>>>(
            xbf, w1 + (size_t)l * 131072, b1 + l * 512, nullptr,
            nullptr, ff1bf, NRts, 256, 512, 2);
        if (l == 0) {
            gemm_ln_kernel<<<dim3(NRts / 16), 256, 0, stream>>>(
                ff1bf, w2 + (size_t)l * 131072, b2 + l * 256, xbuf,
                ln2_g + l * 256, ln2_b + l * 256, xbuf, xbf,
                nullptr, nullptr, nullptr, 512);
        } else {
            gemm_ln_kernel<<<dim3(NRts / 16), 256, 0, stream>>>(
                ff1bf, w2 + (size_t)l * 131072, b2 + l * 256, xbuf,
                ln2_g + l * 256, ln2_b + l * 256, nullptr, nullptr,
                pred_W, pred_b, (float*)d_out, 512);
        }
    }
}